// Round 6
// baseline (331.374 us; speedup 1.0000x reference)
//
#include <hip/hip_runtime.h>
#include <hip/hip_bf16.h>
#include <math.h>

#define BB 2
#define NN 2048
#define QD 1024
#define CTX_LEN 77
#define TCD 768
#define NUM_PROMPT 64
#define PD 1024
#define HEADS 8
#define DIM_HEAD 64
#define INNER 512
#define JTOT (CTX_LEN + NUM_PROMPT + NN)   // 2189
#define SCALE 0.125f
#define MTOT (BB * NN)                     // 4096
#define JPAD 2240                          // 35 * 64, padded j extent
#define JPADA (JPAD + 64)                  // +1 prefetch tile of K rows
#define NT_J (JPAD / 64)                   // 35 j-tiles

typedef unsigned short u16;
typedef unsigned int u32;
typedef __attribute__((ext_vector_type(8))) short bf16x8;
typedef __attribute__((ext_vector_type(4))) float f32x4;

__device__ __forceinline__ u32 pack_split(float f) {   // interleaved: low16=hi, high16=lo
  u32 u = __builtin_bit_cast(u32, f);
  u32 hi = u & 0xffff0000u;
  float lo = f - __builtin_bit_cast(float, hi);
  u32 ul = __builtin_bit_cast(u32, lo);
  return __builtin_amdgcn_perm(ul, u, 0x07060302u);
}
__device__ __forceinline__ void split2(float f, u16& h, u16& l) {
  u32 u = __builtin_bit_cast(u32, f);
  u32 hm = u & 0xffff0000u;
  float lo = f - __builtin_bit_cast(float, hm);
  h = (u16)(u >> 16);
  l = (u16)(__builtin_bit_cast(u32, lo) >> 16);
}

// DPP lane move within 16-lane rows (ctrl must be ICE -> template)
template <int CTRL>
__device__ __forceinline__ float dpp_f(float x) {
  int i = __builtin_bit_cast(int, x);
  i = __builtin_amdgcn_update_dpp(0, i, CTRL, 0xF, 0xF, false);
  return __builtin_bit_cast(float, i);
}

// async global->LDS, 16B per lane; lds dest = base + lane*16
__device__ __forceinline__ void gload16(const u16* g, u32* l) {
  __builtin_amdgcn_global_load_lds(
      (const __attribute__((address_space(1))) u32*)(const void*)g,
      (__attribute__((address_space(3))) u32*)(void*)l, 16, 0, 0);
}

// ---------------- merged f32 -> hi/lo plane pack (x and prompt in one launch) ----------------
__global__ __launch_bounds__(256) void pack_planes2(
    const float* __restrict__ s0, u16* __restrict__ d0h, u16* __restrict__ d0l, int n0,
    const float* __restrict__ s1, u16* __restrict__ d1h, u16* __restrict__ d1l, int n1) {
  int i = blockIdx.x * 256 + threadIdx.x;
  const float* s;
  u16 *dh, *dl;
  if (i < n0) { s = s0; dh = d0h; dl = d0l; }
  else {
    i -= n0;
    if (i >= n1) return;
    s = s1; dh = d1h; dl = d1l;
  }
  float4 f = ((const float4*)s)[i];
  ushort4 hh, ll;
  split2(f.x, hh.x, ll.x); split2(f.y, hh.y, ll.y);
  split2(f.z, hh.z, ll.z); split2(f.w, hh.w, ll.w);
  ((ushort4*)dh)[i] = hh;
  ((ushort4*)dl)[i] = ll;
}

// ---------------- merged weight transpose+pack: 6 sources, one launch ----------------
struct TP6 {
  const float* src[6];
  u16* dh[6];
  u16* dl[6];
  int K[6], N[6];
  int blk0[7];   // cumulative block offsets, blk0[6] = total blocks
};

__global__ __launch_bounds__(256) void transpose_pack6(TP6 P) {
  __shared__ u32 T[32][33];
  const int bid = blockIdx.x;
  int s = 0;
#pragma unroll
  for (int k = 1; k < 6; ++k) s += (bid >= P.blk0[k]);
  const int rel = bid - P.blk0[s];
  const int N = P.N[s], K = P.K[s];
  const int nbx = N >> 5;
  const int bx = rel % nbx, by = rel / nbx;
  const float* __restrict__ src = P.src[s];
  u16* __restrict__ dh = P.dh[s];
  u16* __restrict__ dl = P.dl[s];
  const int t = threadIdx.x;
  const int k0 = by * 32, n0 = bx * 32;
#pragma unroll
  for (int i = 0; i < 4; ++i) {
    int e = t + i * 256;
    int kr = e >> 5, nc = e & 31;
    T[kr][nc] = pack_split(src[(size_t)(k0 + kr) * N + n0 + nc]);
  }
  __syncthreads();
#pragma unroll
  for (int i = 0; i < 4; ++i) {
    int e = t + i * 256;
    int nr = e >> 5, kc = e & 31;
    u32 w = T[kc][nr];
    size_t idx = (size_t)(n0 + nr) * K + k0 + kc;
    dh[idx] = (u16)(w & 0xffff);
    dl[idx] = (u16)(w >> 16);
  }
}

// ---------------- split-bf16 MFMA GEMM, 128x64 tiles, BK=64 (two 32-col sub-buffers) ----------------
// MODE 0: plane output -> O1h/O1l [gm*Ntot+gn]
// MODE 1: gn<TCD -> ctx planes (row remap); else q planes (x SCALE) -> O2h/O2l
// MODE 2: gn<INNER -> K planes with JPADA row remap -> O1h/O1l; else V planes -> O2h/O2l
// MODE 3: f32 out + bias
template <int MODE>
__global__ __launch_bounds__(256) void gemm_mfma(
    const u16* __restrict__ Agh, const u16* __restrict__ Agl,
    const u16* __restrict__ Bgh, const u16* __restrict__ Bgl,
    u16* __restrict__ O1h, u16* __restrict__ O1l,
    u16* __restrict__ O2h, u16* __restrict__ O2l,
    float* __restrict__ Of, const float* __restrict__ bias,
    int M, int K, int Ntot) {
  __shared__ __align__(16) u32 Ah_s[2][128 * 16];
  __shared__ __align__(16) u32 Al_s[2][128 * 16];
  __shared__ __align__(16) u32 Bh_s[2][64 * 16];
  __shared__ __align__(16) u32 Bl_s[2][64 * 16];

  const int t = threadIdx.x;
  const int w = t >> 6, lane = t & 63;
  const int m16 = lane & 15, quad = lane >> 4;
  const int wm = w >> 1, wn = w & 1;
  const int bm = blockIdx.y * 128, bn = blockIdx.x * 64;

  // DMA staging geometry: 4 lanes per 64B row, lane's 16B slot = (lane&3)*8 u16.
  // Wave w: A rows 32w..32w+31 (2 calls of 16 rows), B rows 16w..16w+15 (1 call).
  const int acol = (lane & 3) * 8;
  const int ar0 = 32 * w + (lane >> 2);
  const int ar1 = ar0 + 16;
  const int ag0 = min(bm + ar0, M - 1);   // clamp: OOB rows read valid garbage,
  const int ag1 = min(bm + ar1, M - 1);   // results guarded out in epilogue
  const u16* a0h = Agh + (size_t)ag0 * K + acol;
  const u16* a1h = Agh + (size_t)ag1 * K + acol;
  const u16* a0l = Agl + (size_t)ag0 * K + acol;
  const u16* a1l = Agl + (size_t)ag1 * K + acol;
  const int br = 16 * w + (lane >> 2);
  const u16* b0h = Bgh + (size_t)(bn + br) * K + acol;
  const u16* b0l = Bgl + (size_t)(bn + br) * K + acol;

  f32x4 acc[4][2];
#pragma unroll
  for (int i = 0; i < 4; ++i)
#pragma unroll
    for (int j = 0; j < 2; ++j) acc[i][j] = (f32x4){0.f, 0.f, 0.f, 0.f};

  for (int k0 = 0; k0 < K; k0 += 64) {
    // ---- async stage both 32-col sub-tiles ----
#pragma unroll
    for (int s = 0; s < 2; ++s) {
      const int kc = k0 + s * 32;
      gload16(a0h + kc, &Ah_s[s][(2 * w) * 256]);
      gload16(a1h + kc, &Ah_s[s][(2 * w + 1) * 256]);
      gload16(a0l + kc, &Al_s[s][(2 * w) * 256]);
      gload16(a1l + kc, &Al_s[s][(2 * w + 1) * 256]);
      gload16(b0h + kc, &Bh_s[s][w * 256]);
      gload16(b0l + kc, &Bl_s[s][w * 256]);
    }
    __syncthreads();   // drains DMA (compiler emits vmcnt(0) before barrier)

#pragma unroll
    for (int s = 0; s < 2; ++s) {
      bf16x8 ah[4], al[4], bh[2], bl[2];
#pragma unroll
      for (int mt = 0; mt < 4; ++mt) {
        int off = (wm * 64 + mt * 16 + m16) * 16 + quad * 4;
        ah[mt] = *(const bf16x8*)&Ah_s[s][off];
        al[mt] = *(const bf16x8*)&Al_s[s][off];
      }
#pragma unroll
      for (int nt = 0; nt < 2; ++nt) {
        int off = (wn * 32 + nt * 16 + m16) * 16 + quad * 4;
        bh[nt] = *(const bf16x8*)&Bh_s[s][off];
        bl[nt] = *(const bf16x8*)&Bl_s[s][off];
      }
#pragma unroll
      for (int mt = 0; mt < 4; ++mt)
#pragma unroll
        for (int nt = 0; nt < 2; ++nt) {
          acc[mt][nt] = __builtin_amdgcn_mfma_f32_16x16x32_bf16(ah[mt], bh[nt], acc[mt][nt], 0, 0, 0);
          acc[mt][nt] = __builtin_amdgcn_mfma_f32_16x16x32_bf16(ah[mt], bl[nt], acc[mt][nt], 0, 0, 0);
          acc[mt][nt] = __builtin_amdgcn_mfma_f32_16x16x32_bf16(al[mt], bh[nt], acc[mt][nt], 0, 0, 0);
        }
    }
    __syncthreads();   // frag reads done before next DMA overwrites
  }

#pragma unroll
  for (int mt = 0; mt < 4; ++mt)
#pragma unroll
    for (int nt = 0; nt < 2; ++nt)
#pragma unroll
      for (int r = 0; r < 4; ++r) {
        int gm = bm + wm * 64 + mt * 16 + quad * 4 + r;
        int gn = bn + wn * 32 + nt * 16 + m16;
        float v = acc[mt][nt][r];
        u16 sh, sl;
        if (MODE == 0) {
          if (gm < M) {
            split2(v, sh, sl);
            size_t idx = (size_t)gm * Ntot + gn;
            O1h[idx] = sh; O1l[idx] = sl;
          }
        } else if (MODE == 1) {
          if (gn < TCD) {
            split2(v, sh, sl);
            size_t row = (size_t)(gm >> 11) * JTOT + 141 + (gm & 2047);
            O1h[row * TCD + gn] = sh; O1l[row * TCD + gn] = sl;
          } else {
            split2(v * SCALE, sh, sl);
            size_t idx = (size_t)gm * INNER + (gn - TCD);
            O2h[idx] = sh; O2l[idx] = sl;
          }
        } else if (MODE == 2) {
          if (gm < M) {
            split2(v, sh, sl);
            if (gn < INNER) {
              // K: remap to [B][JPADA][INNER]; pad rows hold garbage, masked in attn
              int row = (gm < JTOT) ? gm : (gm + (JPADA - JTOT));
              size_t idx = (size_t)row * INNER + gn;
              O1h[idx] = sh; O1l[idx] = sl;
            } else {
              size_t idx = (size_t)gm * INNER + (gn - INNER);
              O2h[idx] = sh; O2l[idx] = sl;
            }
          }
        } else {
          Of[(size_t)gm * QD + gn] = v + bias[gn];
        }
      }
}

__global__ __launch_bounds__(256) void copy_ctx_kernel(
    const float* __restrict__ context, const u16* __restrict__ pch,
    const u16* __restrict__ pcl, u16* __restrict__ ch, u16* __restrict__ cl) {
  int idx = blockIdx.x * 256 + threadIdx.x;
  const int total = BB * 141 * TCD;
  if (idx >= total) return;
  int c = idx % TCD;
  int r = (idx / TCD) % 141;
  int b = idx / (141 * TCD);
  size_t dst = ((size_t)b * JTOT + r) * TCD + c;
  if (r < CTX_LEN) {
    u16 sh, sl;
    split2(context[((size_t)b * CTX_LEN + r) * TCD + c], sh, sl);
    ch[dst] = sh; cl[dst] = sl;
  } else {
    size_t s = (size_t)(r - CTX_LEN) * TCD + c;
    ch[dst] = pch[s]; cl[dst] = pcl[s];
  }
}

// ---------------- V planes [MJ][INNER] -> V^T planes [B][INNER][JPAD], zero-padded ----------------
__global__ __launch_bounds__(256) void vtrans(
    const u16* __restrict__ vh, const u16* __restrict__ vl,
    u16* __restrict__ vth, u16* __restrict__ vtl) {
  __shared__ u16 T[64][65];
  const int j0 = blockIdx.x * 64;
  const int d0 = blockIdx.y * 64;
  const int bz = blockIdx.z;
  const int b = bz >> 1;
  const u16* src = (bz & 1) ? vl : vh;
  u16* dst = (bz & 1) ? vtl : vth;
  const int t = threadIdx.x;
#pragma unroll
  for (int i = 0; i < 16; ++i) {
    int e = i * 256 + t;
    int r = e >> 6, c = e & 63;           // r = j row, c = d col
    int jg = j0 + r;
    T[r][c] = (jg < JTOT) ? src[((size_t)b * JTOT + jg) * INNER + d0 + c] : (u16)0;
  }
  __syncthreads();
#pragma unroll
  for (int i = 0; i < 16; ++i) {
    int e = i * 256 + t;
    int r = e >> 6, c = e & 63;           // r = d row, c = j col
    dst[((size_t)b * INNER + d0 + r) * JPAD + j0 + c] = T[c][r];
  }
}

// ---------------- plane-format MFMA flash attention, K double-buffered + counted vmcnt ----------------
// K planes [B][JPADA][INNER], V^T planes [B][INNER][JPAD]; each wave stages 2 chunks of
// EVERY plane (K chunks issued first, V second) so per-wave counted vmcnt splits
// K-wait from V-wait (in-order vmem retirement: <=4 outstanding after issuing 4 newer
// loads => the older group completed). K[t+1] prefetch lands during softmax/PV.
__global__ __launch_bounds__(256) void attn_mfma2(
    const u16* __restrict__ qhg, const u16* __restrict__ qlg,
    const u16* __restrict__ khg, const u16* __restrict__ klg,
    const u16* __restrict__ vtg_h, const u16* __restrict__ vtg_l,
    u16* __restrict__ aoh, u16* __restrict__ aol) {
  __shared__ __align__(16) u16 Kh_s[2][64 * 64];
  __shared__ __align__(16) u16 Kl_s[2][64 * 64];
  __shared__ __align__(16) u16 Vh_s[64 * 64];
  __shared__ __align__(16) u16 Vl_s[64 * 64];
  __shared__ __align__(16) u16 Ph_s[64 * 72];
  __shared__ __align__(16) u16 Pl_s[64 * 72];

  const int t = threadIdx.x;
  const int w = t >> 6, lane = t & 63;
  const int m16 = lane & 15, quad = lane >> 4;

  // XCD swizzle: 512 blocks = 8 * 64; each XCD gets 2 contiguous (b,h) groups
  const int id = blockIdx.x;
  const int swz = (id & 7) * 64 + (id >> 3);
  const int qt = swz & 31, bh = swz >> 5;
  const int b = bh >> 3, h = bh & 7;
  const int qrow0 = qt * 64;

  // Q fragments direct from global planes (A-frag: row=m16, k=ks*32+quad*8)
  bf16x8 qh[2], ql[2];
  {
    size_t qoff = ((size_t)(b * NN + qrow0 + w * 16 + m16)) * INNER + h * 64 + quad * 8;
#pragma unroll
    for (int ks = 0; ks < 2; ++ks) {
      qh[ks] = *(const bf16x8*)(qhg + qoff + ks * 32);
      ql[ks] = *(const bf16x8*)(qlg + qoff + ks * 32);
    }
  }

  // Staging geometry: chunk = 1KB = 8 rows of 128B; plane = 8 chunks.
  // Wave w stages chunks {2w, 2w+1} of each plane. Source chunk-slot XOR swizzle
  // (lane&7)^(lane>>3), dest linear -> LDS (row, cc) holds logical chunk cc^(row&7).
  const int sr = lane >> 3;
  const int sc = (lane & 7) ^ sr;
  const int c0 = 2 * w;
  const size_t kcs = (size_t)8 * INNER;      // K chunk row stride
  const size_t vcs = (size_t)8 * JPAD;       // V^T chunk row stride
  const u16* gKh = khg + ((size_t)b * JPADA + c0 * 8 + sr) * INNER + h * 64 + sc * 8;
  const u16* gKl = klg + ((size_t)b * JPADA + c0 * 8 + sr) * INNER + h * 64 + sc * 8;
  const u16* gVh = vtg_h + ((size_t)b * INNER + h * 64 + c0 * 8 + sr) * JPAD + sc * 8;
  const u16* gVl = vtg_l + ((size_t)b * INNER + h * 64 + c0 * 8 + sr) * JPAD + sc * 8;
  u32* lKh = (u32*)Kh_s + c0 * 256;          // + kb*2048 selects the 8KB buffer
  u32* lKl = (u32*)Kl_s + c0 * 256;
  u32* lVh = (u32*)Vh_s + c0 * 256;
  u32* lVl = (u32*)Vl_s + c0 * 256;

  f32x4 O[4] = {{0.f,0.f,0.f,0.f},{0.f,0.f,0.f,0.f},{0.f,0.f,0.f,0.f},{0.f,0.f,0.f,0.f}};
  float mrow[4], lrow[4];
#pragma unroll
  for (int r = 0; r < 4; ++r) { mrow[r] = -INFINITY; lrow[r] = 0.f; }

  // prologue: issue K[0] into buffer 0 (4 loads/wave)
  gload16(gKh, lKh);            gload16(gKh + kcs, lKh + 256);
  gload16(gKl, lKl);            gload16(gKl + kcs, lKl + 256);
  gKh += (size_t)64 * INNER;    gKl += (size_t)64 * INNER;

  for (int tile = 0; tile < NT_J; ++tile) {
    const int j0 = tile * 64;
    const int kb = tile & 1;
    __builtin_amdgcn_s_barrier();            // A: prior tile fully consumed
    __builtin_amdgcn_sched_barrier(0);
    // issue V[tile] (4 loads/wave; V buffer free since prior PV done everywhere)
    gload16(gVh, lVh);          gload16(gVh + vcs, lVh + 256);
    gload16(gVl, lVl);          gload16(gVl + vcs, lVl + 256);
    gVh += 64; gVl += 64;
    // wait own K[tile] loads (the 4 issued before V[tile])
    asm volatile("s_waitcnt vmcnt(4)" ::: "memory");
    __builtin_amdgcn_sched_barrier(0);
    __builtin_amdgcn_s_barrier();            // B: K[tile] visible to all waves
    __builtin_amdgcn_sched_barrier(0);

    // issue K[tile+1] into other buffer (lands during softmax/PV; padded tail)
    {
      u32* dKh = lKh + (kb ^ 1) * 2048;      // 2048 u32 = 8KB = one K buffer
      u32* dKl = lKl + (kb ^ 1) * 2048;
      gload16(gKh, dKh);        gload16(gKh + kcs, dKh + 256);
      gload16(gKl, dKl);        gload16(gKl + kcs, dKl + 256);
      gKh += (size_t)64 * INNER; gKl += (size_t)64 * INNER;
    }

    // ---- QK^T from K buffer kb ----
    const u16* Khb = Kh_s[kb];
    const u16* Klb = Kl_s[kb];
    f32x4 S[4];
    __builtin_amdgcn_s_setprio(1);
#pragma unroll
    for (int jt = 0; jt < 4; ++jt) {
      const int row = jt * 16 + m16;
      f32x4 acc = {0.f, 0.f, 0.f, 0.f};
#pragma unroll
      for (int ks = 0; ks < 2; ++ks) {
        const int cc = row * 64 + (((ks * 4 + quad) ^ (row & 7)) << 3);
        bf16x8 kh = *(const bf16x8*)&Khb[cc];
        bf16x8 kl = *(const bf16x8*)&Klb[cc];
        acc = __builtin_amdgcn_mfma_f32_16x16x32_bf16(qh[ks], kh, acc, 0, 0, 0);
        acc = __builtin_amdgcn_mfma_f32_16x16x32_bf16(qh[ks], kl, acc, 0, 0, 0);
        acc = __builtin_amdgcn_mfma_f32_16x16x32_bf16(ql[ks], kh, acc, 0, 0, 0);
      }
      S[jt] = acc;
    }
    __builtin_amdgcn_s_setprio(0);

    // mask tail columns (also covers K pad-row garbage)
#pragma unroll
    for (int jt = 0; jt < 4; ++jt) {
      int jc = j0 + jt * 16 + m16;
      if (jc >= JTOT)
#pragma unroll
        for (int r = 0; r < 4; ++r) S[jt][r] = -INFINITY;
    }

    // ---- online softmax: DPP reductions over 16-lane rows (off the LDS pipe) ----
    float pj[4][4];
#pragma unroll
    for (int r = 0; r < 4; ++r) {
      float mx = fmaxf(fmaxf(S[0][r], S[1][r]), fmaxf(S[2][r], S[3][r]));
      mx = fmaxf(mx, dpp_f<0xB1>(mx));     // quad_perm [1,0,3,2] = xor1
      mx = fmaxf(mx, dpp_f<0x4E>(mx));     // quad_perm [2,3,0,1] = xor2
      mx = fmaxf(mx, dpp_f<0x124>(mx));    // row_ror:4
      mx = fmaxf(mx, dpp_f<0x128>(mx));    // row_ror:8
      float mnew = fmaxf(mrow[r], mx);
      float alpha = __expf(mrow[r] - mnew);
      mrow[r] = mnew;
      float rs = 0.f;
#pragma unroll
      for (int jt = 0; jt < 4; ++jt) {
        float pv = __expf(S[jt][r] - mnew);
        pj[jt][r] = pv;
        rs += pv;
      }
      rs += dpp_f<0xB1>(rs);
      rs += dpp_f<0x4E>(rs);
      rs += dpp_f<0x124>(rs);
      rs += dpp_f<0x128>(rs);
      lrow[r] = lrow[r] * alpha + rs;
#pragma unroll
      for (int nt = 0; nt < 4; ++nt) O[nt][r] *= alpha;
    }

    // ---- P -> LDS planes (rows are wave-private: no barrier needed) ----
#pragma unroll
    for (int jt = 0; jt < 4; ++jt)
#pragma unroll
      for (int r = 0; r < 4; ++r) {
        u16 sh, sl;
        split2(pj[jt][r], sh, sl);
        int pq = (w * 16 + quad * 4 + r) * 72 + jt * 16 + m16;
        Ph_s[pq] = sh;
        Pl_s[pq] = sl;
      }

    bf16x8 ph[2], pl[2];
#pragma unroll
    for (int ks = 0; ks < 2; ++ks) {
      int po = (w * 16 + m16) * 72 + ks * 32 + quad * 8;
      ph[ks] = *(const bf16x8*)&Ph_s[po];
      pl[ks] = *(const bf16x8*)&Pl_s[po];
    }

    // wait own V[tile] loads (the 4 issued before K[tile+1])
    asm volatile("s_waitcnt vmcnt(4)" ::: "memory");
    __builtin_amdgcn_sched_barrier(0);
    __builtin_amdgcn_s_barrier();            // C: V[tile] visible to all waves
    __builtin_amdgcn_sched_barrier(0);

    // ---- PV (B-frag = V^T rows d) ----
    __builtin_amdgcn_s_setprio(1);
#pragma unroll
    for (int nt = 0; nt < 4; ++nt) {
      const int row = nt * 16 + m16;
#pragma unroll
      for (int ks = 0; ks < 2; ++ks) {
        const int cc = row * 64 + (((ks * 4 + quad) ^ (row & 7)) << 3);
        bf16x8 vh = *(const bf16x8*)&Vh_s[cc];
        bf16x8 vl = *(const bf16x8*)&Vl_s[cc];
        O[nt] = __builtin_amdgcn_mfma_f32_16x16x32_bf16(ph[ks], vh, O[nt], 0, 0, 0);
        O[nt] = __builtin_amdgcn_mfma_f32_16x16x32_bf16(ph[ks], vl, O[nt], 0, 0, 0);
        O[nt] = __builtin_amdgcn_mfma_f32_16x16x32_bf16(pl[ks], vh, O[nt], 0, 0, 0);
      }
    }
    __builtin_amdgcn_s_setprio(0);
  }

  // drain the dangling K-prefetch DMA before the block can retire
  asm volatile("s_waitcnt vmcnt(0)" ::: "memory");

  float inv[4];
#pragma unroll
  for (int r = 0; r < 4; ++r) inv[r] = 1.f / lrow[r];
#pragma unroll
  for (int nt = 0; nt < 4; ++nt)
#pragma unroll
    for (int r = 0; r < 4; ++r) {
      size_t idx = ((size_t)(b * NN + qrow0 + w * 16 + quad * 4 + r)) * INNER +
                   h * 64 + nt * 16 + m16;
      u16 sh, sl;
      split2(O[nt][r] * inv[r], sh, sl);
      aoh[idx] = sh; aol[idx] = sl;
    }
}

// ---------------- launch ----------------
extern "C" void kernel_launch(void* const* d_in, const int* in_sizes, int n_in,
                              void* d_out, int out_size, void* d_ws, size_t ws_size,
                              hipStream_t stream) {
  const float* x        = (const float*)d_in[0];
  const float* context  = (const float*)d_in[1];
  const float* prompt   = (const float*)d_in[2];
  const float* w_prompt = (const float*)d_in[3];
  const float* w_img    = (const float*)d_in[4];
  const float* w_q      = (const float*)d_in[5];
  const float* w_k      = (const float*)d_in[6];
  const float* w_v      = (const float*)d_in[7];
  const float* w_out    = (const float*)d_in[8];
  const float* b_out    = (const float*)d_in[9];
  float* out = (float*)d_out;

  const int M = MTOT;             // 4096
  const int MJ = BB * JTOT;       // 4378

  u16* p = (u16*)d_ws;
  const size_t qN = (size_t)M * INNER;
  const size_t ctxN = (size_t)MJ * TCD;
  const size_t kN = (size_t)BB * JPADA * INNER;  // padded K planes (+ prefetch tile)
  const size_t vN = (size_t)MJ * INNER;
  u16* pch = p; p += (size_t)NUM_PROMPT * TCD;
  u16* pcl = p; p += (size_t)NUM_PROMPT * TCD;
  u16* cth = p; p += ctxN; u16* ctl = p; p += ctxN;
  u16* aoh = p; p += qN;   u16* aol = p; p += qN;
  u16* xh  = p; p += (size_t)M * QD;   u16* xl  = p; p += (size_t)M * QD;
  u16* prh = p; p += (size_t)NUM_PROMPT * PD;
  u16* prl = p; p += (size_t)NUM_PROMPT * PD;
  u16* WtPh = p; p += (size_t)TCD * PD;            u16* WtPl = p; p += (size_t)TCD * PD;
  u16* WtAh = p; p += (size_t)(TCD + INNER) * QD;  u16* WtAl = p; p += (size_t)(TCD + INNER) * QD;
  u16* WtBh = p; p += (size_t)(2 * INNER) * TCD;   u16* WtBl = p; p += (size_t)(2 * INNER) * TCD;
  u16* WtOh = p; p += (size_t)QD * INNER;          u16* WtOl = p; p += (size_t)QD * INNER;
  u16* qhp = p; p += qN;  u16* qlp = p; p += qN;   // q planes (pre-scaled)
  u16* khp = p; p += kN;  u16* klp = p; p += kN;   // K planes, JPADA rows per b
  u16* vhp = p; p += vN;  u16* vlp = p; p += vN;   // V planes
  u16* vthp = p; p += (size_t)BB * JPAD * INNER;   // V^T planes [B][INNER][JPAD]
  u16* vtlp = p; p += (size_t)BB * JPAD * INNER;

  // ---- pack inputs (one launch) ----
  const int n4x = M * QD / 4, n4p = NUM_PROMPT * PD / 4;
  pack_planes2<<<(n4x + n4p + 255) / 256, 256, 0, stream>>>(
      x, xh, xl, n4x, prompt, prh, prl, n4p);

  // ---- transpose+pack all 6 weights (one launch) ----
  TP6 tp;
  const float* srcs[6] = {w_prompt, w_img, w_q, w_k, w_v, w_out};
  u16* dhs[6] = {WtPh, WtAh, WtAh + (size_t)TCD * QD, WtBh, WtBh + (size_t)INNER * TCD, WtOh};
  u16* dls[6] = {WtPl, WtAl, WtAl + (size_t)TCD * QD, WtBl, WtBl + (size_t)INNER * TCD, WtOl};
  int Ks[6] = {PD, QD, QD, TCD, TCD, INNER};
  int Ns[6] = {TCD, TCD, INNER, INNER, INNER, QD};
  int acc_blk = 0;
  for (int i = 0; i < 6; ++i) {
    tp.src[i] = srcs[i]; tp.dh[i] = dhs[i]; tp.dl[i] = dls[i];
    tp.K[i] = Ks[i]; tp.N[i] = Ns[i];
    tp.blk0[i] = acc_blk;
    acc_blk += (Ns[i] / 32) * (Ks[i] / 32);
  }
  tp.blk0[6] = acc_blk;
  transpose_pack6<<<acc_blk, 256, 0, stream>>>(tp);

  // ---- prompt_ctx -> planes ----
  gemm_mfma<0><<<dim3(TCD / 64, 1), 256, 0, stream>>>(
      prh, prl, WtPh, WtPl, pch, pcl, nullptr, nullptr, nullptr, nullptr,
      NUM_PROMPT, PD, TCD);
  copy_ctx_kernel<<<(BB * 141 * TCD + 255) / 256, 256, 0, stream>>>(context, pch, pcl, cth, ctl);
  // ---- x @ [w_img | w_q] -> ctx planes (remap) + q planes (x SCALE) ----
  gemm_mfma<1><<<dim3((TCD + INNER) / 64, M / 128), 256, 0, stream>>>(
      xh, xl, WtAh, WtAl, cth, ctl, qhp, qlp, nullptr, nullptr,
      M, QD, TCD + INNER);
  // ---- ctx @ [w_k | w_v] -> K padded planes + V planes ----
  gemm_mfma<2><<<dim3((2 * INNER) / 64, (MJ + 127) / 128), 256, 0, stream>>>(
      cth, ctl, WtBh, WtBl, khp, klp, vhp, vlp, nullptr, nullptr,
      MJ, TCD, 2 * INNER);
  // ---- V -> V^T (zero-padded to JPAD) ----
  vtrans<<<dim3(NT_J, INNER / 64, BB * 2), 256, 0, stream>>>(vhp, vlp, vthp, vtlp);
  // ---- attention ----
  attn_mfma2<<<BB * HEADS * (NN / 64), 256, 0, stream>>>(
      qhp, qlp, khp, klp, vthp, vtlp, aoh, aol);
  // ---- out = ao @ w_out + b_out ----
  gemm_mfma<3><<<dim3(QD / 64, M / 128), 256, 0, stream>>>(
      aoh, aol, WtOh, WtOl, nullptr, nullptr, nullptr, nullptr, out, b_out,
      M, INNER, QD);
}

// Round 7
// 295.462 us; speedup vs baseline: 1.1215x; 1.1215x over previous
//
#include <hip/hip_runtime.h>
#include <hip/hip_bf16.h>
#include <math.h>

#define BB 2
#define NN 2048
#define QD 1024
#define CTX_LEN 77
#define TCD 768
#define NUM_PROMPT 64
#define PD 1024
#define HEADS 8
#define DIM_HEAD 64
#define INNER 512
#define JTOT (CTX_LEN + NUM_PROMPT + NN)   // 2189
#define SCALE 0.125f
#define MTOT (BB * NN)                     // 4096
#define JPAD 2240                          // 35 * 64, padded j extent
#define NT_J (JPAD / 64)                   // 35 j-tiles

typedef unsigned short u16;
typedef unsigned int u32;
typedef __attribute__((ext_vector_type(8))) short bf16x8;
typedef __attribute__((ext_vector_type(4))) float f32x4;

__device__ __forceinline__ u32 pack_split(float f) {   // interleaved: low16=hi, high16=lo
  u32 u = __builtin_bit_cast(u32, f);
  u32 hi = u & 0xffff0000u;
  float lo = f - __builtin_bit_cast(float, hi);
  u32 ul = __builtin_bit_cast(u32, lo);
  return __builtin_amdgcn_perm(ul, u, 0x07060302u);
}
__device__ __forceinline__ void split2(float f, u16& h, u16& l) {
  u32 u = __builtin_bit_cast(u32, f);
  u32 hm = u & 0xffff0000u;
  float lo = f - __builtin_bit_cast(float, hm);
  h = (u16)(u >> 16);
  l = (u16)(__builtin_bit_cast(u32, lo) >> 16);
}
__device__ __forceinline__ void pack4(const float4& f, ushort4& hh, ushort4& ll) {
  split2(f.x, hh.x, ll.x); split2(f.y, hh.y, ll.y);
  split2(f.z, hh.z, ll.z); split2(f.w, hh.w, ll.w);
}

// DPP lane move within 16-lane rows (ctrl must be ICE -> template)
template <int CTRL>
__device__ __forceinline__ float dpp_f(float x) {
  int i = __builtin_bit_cast(int, x);
  i = __builtin_amdgcn_update_dpp(0, i, CTRL, 0xF, 0xF, false);
  return __builtin_bit_cast(float, i);
}

// async global->LDS, 16B per lane; lds dest = base + lane*16
__device__ __forceinline__ void gload16(const u16* g, u32* l) {
  __builtin_amdgcn_global_load_lds(
      (const __attribute__((address_space(1))) u32*)(const void*)g,
      (__attribute__((address_space(3))) u32*)(void*)l, 16, 0, 0);
}

// ---------------- merged f32 -> hi/lo plane pack: x, prompt, and text-ctx rows ----------------
__global__ __launch_bounds__(256) void pack_planes3(
    const float* __restrict__ s0, u16* __restrict__ d0h, u16* __restrict__ d0l, int n0,
    const float* __restrict__ s1, u16* __restrict__ d1h, u16* __restrict__ d1l, int n1,
    const float* __restrict__ ctx, u16* __restrict__ ch, u16* __restrict__ cl, int n2) {
  int i = blockIdx.x * 256 + threadIdx.x;
  ushort4 hh, ll;
  if (i < n0) {
    pack4(((const float4*)s0)[i], hh, ll);
    ((ushort4*)d0h)[i] = hh; ((ushort4*)d0l)[i] = ll;
    return;
  }
  i -= n0;
  if (i < n1) {
    pack4(((const float4*)s1)[i], hh, ll);
    ((ushort4*)d1h)[i] = hh; ((ushort4*)d1l)[i] = ll;
    return;
  }
  i -= n1;
  if (i >= n2) return;
  // text context rows -> ctx planes rows [b*JTOT + r], r < CTX_LEN
  pack4(((const float4*)ctx)[i], hh, ll);
  int c4 = i % (TCD / 4);
  int rb = i / (TCD / 4);
  int r = rb % CTX_LEN, b = rb / CTX_LEN;
  size_t o = ((size_t)b * JTOT + r) * (TCD / 4) + c4;   // ushort4 units
  ((ushort4*)ch)[o] = hh; ((ushort4*)cl)[o] = ll;
}

// ---------------- merged weight transpose+pack: 6 sources, one launch ----------------
struct TP6 {
  const float* src[6];
  u16* dh[6];
  u16* dl[6];
  int K[6], N[6];
  int blk0[7];   // cumulative block offsets, blk0[6] = total blocks
};

__global__ __launch_bounds__(256) void transpose_pack6(TP6 P) {
  __shared__ u32 T[32][33];
  const int bid = blockIdx.x;
  int s = 0;
#pragma unroll
  for (int k = 1; k < 6; ++k) s += (bid >= P.blk0[k]);
  const int rel = bid - P.blk0[s];
  const int N = P.N[s], K = P.K[s];
  const int nbx = N >> 5;
  const int bx = rel % nbx, by = rel / nbx;
  const float* __restrict__ src = P.src[s];
  u16* __restrict__ dh = P.dh[s];
  u16* __restrict__ dl = P.dl[s];
  const int t = threadIdx.x;
  const int k0 = by * 32, n0 = bx * 32;
#pragma unroll
  for (int i = 0; i < 4; ++i) {
    int e = t + i * 256;
    int kr = e >> 5, nc = e & 31;
    T[kr][nc] = pack_split(src[(size_t)(k0 + kr) * N + n0 + nc]);
  }
  __syncthreads();
#pragma unroll
  for (int i = 0; i < 4; ++i) {
    int e = t + i * 256;
    int nr = e >> 5, kc = e & 31;
    u32 w = T[kc][nr];
    size_t idx = (size_t)(n0 + nr) * K + k0 + kc;
    dh[idx] = (u16)(w & 0xffff);
    dl[idx] = (u16)(w >> 16);
  }
}

// ---------------- split-bf16 MFMA GEMM, 128x64 tiles, BK=64, bijective XCD swizzle ----------------
// MODE 1: gn<TCD -> ctx planes (row remap); else q planes (x SCALE) -> O2h/O2l.
//         Extra grid band bm>=MTOT: prompt@w_prompt -> ctx rows 77..140 (both b).
// MODE 2: gn<INNER -> K planes with JPAD row remap -> O1h/O1l; else V planes -> O2h/O2l
// MODE 3: f32 out + bias
template <int MODE>
__global__ __launch_bounds__(256) void gemm_mfma(
    const u16* __restrict__ Agh, const u16* __restrict__ Agl,
    const u16* __restrict__ Bgh, const u16* __restrict__ Bgl,
    u16* __restrict__ O1h, u16* __restrict__ O1l,
    u16* __restrict__ O2h, u16* __restrict__ O2l,
    float* __restrict__ Of, const float* __restrict__ bias,
    int M, int K, int Ntot,
    const u16* __restrict__ A2h, const u16* __restrict__ A2l,
    const u16* __restrict__ B2h, const u16* __restrict__ B2l) {
  __shared__ __align__(16) u32 Ah_s[2][128 * 16];
  __shared__ __align__(16) u32 Al_s[2][128 * 16];
  __shared__ __align__(16) u32 Bh_s[2][64 * 16];
  __shared__ __align__(16) u32 Bl_s[2][64 * 16];

  // bijective chunked XCD swizzle (m204): each XCD owns a contiguous grid chunk
  int bxi = blockIdx.x, byi = blockIdx.y;
  {
    const int GX = gridDim.x;
    const int nwg = GX * gridDim.y;
    const int lid = byi * GX + bxi;
    const int qq = nwg >> 3, rr = nwg & 7;
    const int xcd = lid & 7, pos = lid >> 3;
    const int swz = (xcd < rr ? xcd * (qq + 1) : rr * (qq + 1) + (xcd - rr) * qq) + pos;
    bxi = swz % GX; byi = swz / GX;
  }
  const int bm = byi * 128, bn = bxi * 64;

  const bool pband = (MODE == 1) && (bm >= MTOT);
  if (pband && bn >= TCD) return;   // block-uniform: idle prompt-band columns

  const int t = threadIdx.x;
  const int w = t >> 6, lane = t & 63;
  const int m16 = lane & 15, quad = lane >> 4;
  const int wm = w >> 1, wn = w & 1;

  const u16* Abh = Agh; const u16* Abl = Agl;
  const u16* Bbh = Bgh; const u16* Bbl = Bgl;
  int rowlim = M - 1;
  int bmA = bm;
  if (pband) { Abh = A2h; Abl = A2l; Bbh = B2h; Bbl = B2l; rowlim = NUM_PROMPT - 1; bmA = 0; }

  // DMA staging geometry: 4 lanes per 64B row, lane's 16B slot = (lane&3)*8 u16.
  // Wave w: A rows 32w..32w+31 (2 calls of 16 rows), B rows 16w..16w+15 (1 call).
  const int acol = (lane & 3) * 8;
  const int ar0 = 32 * w + (lane >> 2);
  const int ar1 = ar0 + 16;
  const int ag0 = min(bmA + ar0, rowlim);   // clamp: OOB rows read valid garbage,
  const int ag1 = min(bmA + ar1, rowlim);   // results guarded out in epilogue
  const u16* a0h = Abh + (size_t)ag0 * K + acol;
  const u16* a1h = Abh + (size_t)ag1 * K + acol;
  const u16* a0l = Abl + (size_t)ag0 * K + acol;
  const u16* a1l = Abl + (size_t)ag1 * K + acol;
  const int br = 16 * w + (lane >> 2);
  const u16* b0h = Bbh + (size_t)(bn + br) * K + acol;
  const u16* b0l = Bbl + (size_t)(bn + br) * K + acol;

  f32x4 acc[4][2];
#pragma unroll
  for (int i = 0; i < 4; ++i)
#pragma unroll
    for (int j = 0; j < 2; ++j) acc[i][j] = (f32x4){0.f, 0.f, 0.f, 0.f};

  for (int k0 = 0; k0 < K; k0 += 64) {
    // ---- async stage both 32-col sub-tiles ----
#pragma unroll
    for (int s = 0; s < 2; ++s) {
      const int kc = k0 + s * 32;
      gload16(a0h + kc, &Ah_s[s][(2 * w) * 256]);
      gload16(a1h + kc, &Ah_s[s][(2 * w + 1) * 256]);
      gload16(a0l + kc, &Al_s[s][(2 * w) * 256]);
      gload16(a1l + kc, &Al_s[s][(2 * w + 1) * 256]);
      gload16(b0h + kc, &Bh_s[s][w * 256]);
      gload16(b0l + kc, &Bl_s[s][w * 256]);
    }
    __syncthreads();   // drains DMA (compiler emits vmcnt(0) before barrier)

#pragma unroll
    for (int s = 0; s < 2; ++s) {
      bf16x8 ah[4], al[4], bh[2], bl[2];
#pragma unroll
      for (int mt = 0; mt < 4; ++mt) {
        int off = (wm * 64 + mt * 16 + m16) * 16 + quad * 4;
        ah[mt] = *(const bf16x8*)&Ah_s[s][off];
        al[mt] = *(const bf16x8*)&Al_s[s][off];
      }
#pragma unroll
      for (int nt = 0; nt < 2; ++nt) {
        int off = (wn * 32 + nt * 16 + m16) * 16 + quad * 4;
        bh[nt] = *(const bf16x8*)&Bh_s[s][off];
        bl[nt] = *(const bf16x8*)&Bl_s[s][off];
      }
#pragma unroll
      for (int mt = 0; mt < 4; ++mt)
#pragma unroll
        for (int nt = 0; nt < 2; ++nt) {
          acc[mt][nt] = __builtin_amdgcn_mfma_f32_16x16x32_bf16(ah[mt], bh[nt], acc[mt][nt], 0, 0, 0);
          acc[mt][nt] = __builtin_amdgcn_mfma_f32_16x16x32_bf16(ah[mt], bl[nt], acc[mt][nt], 0, 0, 0);
          acc[mt][nt] = __builtin_amdgcn_mfma_f32_16x16x32_bf16(al[mt], bh[nt], acc[mt][nt], 0, 0, 0);
        }
    }
    __syncthreads();   // frag reads done before next DMA overwrites
  }

#pragma unroll
  for (int mt = 0; mt < 4; ++mt)
#pragma unroll
    for (int nt = 0; nt < 2; ++nt)
#pragma unroll
      for (int r = 0; r < 4; ++r) {
        int gm = bm + wm * 64 + mt * 16 + quad * 4 + r;
        int gn = bn + wn * 32 + nt * 16 + m16;
        float v = acc[mt][nt][r];
        u16 sh, sl;
        if (MODE == 1) {
          if (pband) {
            int pr = wm * 64 + mt * 16 + quad * 4 + r;
            if (pr < NUM_PROMPT && gn < TCD) {
              split2(v, sh, sl);
              size_t r0 = ((size_t)CTX_LEN + pr) * TCD + gn;          // b = 0
              size_t r1 = ((size_t)JTOT + CTX_LEN + pr) * TCD + gn;   // b = 1
              O1h[r0] = sh; O1l[r0] = sl;
              O1h[r1] = sh; O1l[r1] = sl;
            }
          } else if (gn < TCD) {
            split2(v, sh, sl);
            size_t row = (size_t)(gm >> 11) * JTOT + 141 + (gm & 2047);
            O1h[row * TCD + gn] = sh; O1l[row * TCD + gn] = sl;
          } else {
            split2(v * SCALE, sh, sl);
            size_t idx = (size_t)gm * INNER + (gn - TCD);
            O2h[idx] = sh; O2l[idx] = sl;
          }
        } else if (MODE == 2) {
          if (gm < M) {
            split2(v, sh, sl);
            if (gn < INNER) {
              // K: remap to [B][JPAD][INNER]; pad rows hold garbage, masked in attn
              int row = (gm < JTOT) ? gm : (gm + (JPAD - JTOT));
              size_t idx = (size_t)row * INNER + gn;
              O1h[idx] = sh; O1l[idx] = sl;
            } else {
              size_t idx = (size_t)gm * INNER + (gn - INNER);
              O2h[idx] = sh; O2l[idx] = sl;
            }
          }
        } else if (MODE == 3) {
          Of[(size_t)gm * QD + gn] = v + bias[gn];
        }
      }
}

// ---------------- V planes [MJ][INNER] -> V^T planes [B][INNER][JPAD], zero-padded ----------------
__global__ __launch_bounds__(256) void vtrans(
    const u16* __restrict__ vh, const u16* __restrict__ vl,
    u16* __restrict__ vth, u16* __restrict__ vtl) {
  __shared__ u16 T[64][65];
  const int j0 = blockIdx.x * 64;
  const int d0 = blockIdx.y * 64;
  const int bz = blockIdx.z;
  const int b = bz >> 1;
  const u16* src = (bz & 1) ? vl : vh;
  u16* dst = (bz & 1) ? vtl : vth;
  const int t = threadIdx.x;
#pragma unroll
  for (int i = 0; i < 16; ++i) {
    int e = i * 256 + t;
    int r = e >> 6, c = e & 63;           // r = j row, c = d col
    int jg = j0 + r;
    T[r][c] = (jg < JTOT) ? src[((size_t)b * JTOT + jg) * INNER + d0 + c] : (u16)0;
  }
  __syncthreads();
#pragma unroll
  for (int i = 0; i < 16; ++i) {
    int e = i * 256 + t;
    int r = e >> 6, c = e & 63;           // r = d row, c = j col
    dst[((size_t)b * INNER + d0 + r) * JPAD + j0 + c] = T[c][r];
  }
}

// ---------------- plane-format MFMA flash attention (R4 measured-best structure) ----------------
// K planes [B][JPAD][INNER], V^T planes [B][INNER][JPAD]; staged via global_load_lds
// with pre-swizzled source (XOR chunk swizzle) -> conflict-free ds_read_b128 fragments.
__global__ __launch_bounds__(256) void attn_mfma2(
    const u16* __restrict__ qhg, const u16* __restrict__ qlg,
    const u16* __restrict__ khg, const u16* __restrict__ klg,
    const u16* __restrict__ vtg_h, const u16* __restrict__ vtg_l,
    u16* __restrict__ aoh, u16* __restrict__ aol) {
  __shared__ __align__(16) u16 Kh_s[64 * 64];
  __shared__ __align__(16) u16 Kl_s[64 * 64];
  __shared__ __align__(16) u16 Vh_s[64 * 64];
  __shared__ __align__(16) u16 Vl_s[64 * 64];
  __shared__ __align__(16) u16 Ph_s[64 * 72];
  __shared__ __align__(16) u16 Pl_s[64 * 72];

  const int t = threadIdx.x;
  const int w = t >> 6, lane = t & 63;
  const int m16 = lane & 15, quad = lane >> 4;

  // XCD swizzle: 512 blocks = 8 * 64; each XCD gets 2 contiguous (b,h) groups
  const int id = blockIdx.x;
  const int swz = (id & 7) * 64 + (id >> 3);
  const int qt = swz & 31, bh = swz >> 5;
  const int b = bh >> 3, h = bh & 7;
  const int qrow0 = qt * 64;

  // Q fragments direct from global planes (A-frag: row=m16, k=ks*32+quad*8)
  bf16x8 qh[2], ql[2];
  {
    size_t qoff = ((size_t)(b * NN + qrow0 + w * 16 + m16)) * INNER + h * 64 + quad * 8;
#pragma unroll
    for (int ks = 0; ks < 2; ++ks) {
      qh[ks] = *(const bf16x8*)(qhg + qoff + ks * 32);
      ql[ks] = *(const bf16x8*)(qlg + qoff + ks * 32);
    }
  }

  // Staging: wave w stages plane w (0:Kh 1:Kl 2:Vh^T 3:Vl^T).
  // Per call: 8 rows x 8 chunks of 16B; dest linear, source chunk = (lane&7)^(lane>>3)
  // so LDS (row, cc) holds logical chunk cc^(row&7).
  const int sr = lane >> 3;
  const int sc = (lane & 7) ^ sr;
  const u16* gp;
  u32* lp;
  size_t cstr, jstr;
  if (w < 2) {
    gp = ((w == 0) ? khg : klg) + ((size_t)b * JPAD + sr) * INNER + h * 64 + sc * 8;
    lp = (u32*)((w == 0) ? Kh_s : Kl_s);
    cstr = (size_t)8 * INNER;
    jstr = (size_t)64 * INNER;
  } else {
    gp = ((w == 2) ? vtg_h : vtg_l) + ((size_t)b * INNER + h * 64 + sr) * JPAD + sc * 8;
    lp = (u32*)((w == 2) ? Vh_s : Vl_s);
    cstr = (size_t)8 * JPAD;
    jstr = 64;
  }

  f32x4 O[4] = {{0.f,0.f,0.f,0.f},{0.f,0.f,0.f,0.f},{0.f,0.f,0.f,0.f},{0.f,0.f,0.f,0.f}};
  float mrow[4], lrow[4];
#pragma unroll
  for (int r = 0; r < 4; ++r) { mrow[r] = -INFINITY; lrow[r] = 0.f; }

  for (int tile = 0; tile < NT_J; ++tile) {
    const int j0 = tile * 64;
    __syncthreads();                       // prior tile fully consumed
#pragma unroll
    for (int c = 0; c < 8; ++c) gload16(gp + (size_t)c * cstr, lp + c * 256);
    gp += jstr;
    __syncthreads();                       // drain DMA (vmcnt(0) before barrier)

    // ---- QK^T ----
    f32x4 S[4];
    __builtin_amdgcn_s_setprio(1);
#pragma unroll
    for (int jt = 0; jt < 4; ++jt) {
      const int row = jt * 16 + m16;
      f32x4 acc = {0.f, 0.f, 0.f, 0.f};
#pragma unroll
      for (int ks = 0; ks < 2; ++ks) {
        const int cc = row * 64 + (((ks * 4 + quad) ^ (row & 7)) << 3);
        bf16x8 kh = *(const bf16x8*)&Kh_s[cc];
        bf16x8 kl = *(const bf16x8*)&Kl_s[cc];
        acc = __builtin_amdgcn_mfma_f32_16x16x32_bf16(qh[ks], kh, acc, 0, 0, 0);
        acc = __builtin_amdgcn_mfma_f32_16x16x32_bf16(qh[ks], kl, acc, 0, 0, 0);
        acc = __builtin_amdgcn_mfma_f32_16x16x32_bf16(ql[ks], kh, acc, 0, 0, 0);
      }
      S[jt] = acc;
    }
    __builtin_amdgcn_s_setprio(0);

    // mask tail columns (also covers K pad-row garbage)
#pragma unroll
    for (int jt = 0; jt < 4; ++jt) {
      int jc = j0 + jt * 16 + m16;
      if (jc >= JTOT)
#pragma unroll
        for (int r = 0; r < 4; ++r) S[jt][r] = -INFINITY;
    }

    // ---- online softmax: DPP reductions over 16-lane rows (off the LDS pipe) ----
    float pj[4][4];
#pragma unroll
    for (int r = 0; r < 4; ++r) {
      float mx = fmaxf(fmaxf(S[0][r], S[1][r]), fmaxf(S[2][r], S[3][r]));
      mx = fmaxf(mx, dpp_f<0xB1>(mx));     // quad_perm [1,0,3,2] = xor1
      mx = fmaxf(mx, dpp_f<0x4E>(mx));     // quad_perm [2,3,0,1] = xor2
      mx = fmaxf(mx, dpp_f<0x124>(mx));    // row_ror:4
      mx = fmaxf(mx, dpp_f<0x128>(mx));    // row_ror:8
      float mnew = fmaxf(mrow[r], mx);
      float alpha = __expf(mrow[r] - mnew);
      mrow[r] = mnew;
      float rs = 0.f;
#pragma unroll
      for (int jt = 0; jt < 4; ++jt) {
        float pv = __expf(S[jt][r] - mnew);
        pj[jt][r] = pv;
        rs += pv;
      }
      rs += dpp_f<0xB1>(rs);
      rs += dpp_f<0x4E>(rs);
      rs += dpp_f<0x124>(rs);
      rs += dpp_f<0x128>(rs);
      lrow[r] = lrow[r] * alpha + rs;
#pragma unroll
      for (int nt = 0; nt < 4; ++nt) O[nt][r] *= alpha;
    }

    // ---- P -> LDS planes (rows are wave-private: no barrier needed) ----
#pragma unroll
    for (int jt = 0; jt < 4; ++jt)
#pragma unroll
      for (int r = 0; r < 4; ++r) {
        u16 sh, sl;
        split2(pj[jt][r], sh, sl);
        int pq = (w * 16 + quad * 4 + r) * 72 + jt * 16 + m16;
        Ph_s[pq] = sh;
        Pl_s[pq] = sl;
      }

    bf16x8 ph[2], pl[2];
#pragma unroll
    for (int ks = 0; ks < 2; ++ks) {
      int po = (w * 16 + m16) * 72 + ks * 32 + quad * 8;
      ph[ks] = *(const bf16x8*)&Ph_s[po];
      pl[ks] = *(const bf16x8*)&Pl_s[po];
    }

    // ---- PV (B-frag = V^T rows d) ----
    __builtin_amdgcn_s_setprio(1);
#pragma unroll
    for (int nt = 0; nt < 4; ++nt) {
      const int row = nt * 16 + m16;
#pragma unroll
      for (int ks = 0; ks < 2; ++ks) {
        const int cc = row * 64 + (((ks * 4 + quad) ^ (row & 7)) << 3);
        bf16x8 vh = *(const bf16x8*)&Vh_s[cc];
        bf16x8 vl = *(const bf16x8*)&Vl_s[cc];
        O[nt] = __builtin_amdgcn_mfma_f32_16x16x32_bf16(ph[ks], vh, O[nt], 0, 0, 0);
        O[nt] = __builtin_amdgcn_mfma_f32_16x16x32_bf16(ph[ks], vl, O[nt], 0, 0, 0);
        O[nt] = __builtin_amdgcn_mfma_f32_16x16x32_bf16(pl[ks], vh, O[nt], 0, 0, 0);
      }
    }
    __builtin_amdgcn_s_setprio(0);
  }

  float inv[4];
#pragma unroll
  for (int r = 0; r < 4; ++r) inv[r] = 1.f / lrow[r];
#pragma unroll
  for (int nt = 0; nt < 4; ++nt)
#pragma unroll
    for (int r = 0; r < 4; ++r) {
      size_t idx = ((size_t)(b * NN + qrow0 + w * 16 + quad * 4 + r)) * INNER +
                   h * 64 + nt * 16 + m16;
      u16 sh, sl;
      split2(O[nt][r] * inv[r], sh, sl);
      aoh[idx] = sh; aol[idx] = sl;
    }
}

// ---------------- launch ----------------
extern "C" void kernel_launch(void* const* d_in, const int* in_sizes, int n_in,
                              void* d_out, int out_size, void* d_ws, size_t ws_size,
                              hipStream_t stream) {
  const float* x        = (const float*)d_in[0];
  const float* context  = (const float*)d_in[1];
  const float* prompt   = (const float*)d_in[2];
  const float* w_prompt = (const float*)d_in[3];
  const float* w_img    = (const float*)d_in[4];
  const float* w_q      = (const float*)d_in[5];
  const float* w_k      = (const float*)d_in[6];
  const float* w_v      = (const float*)d_in[7];
  const float* w_out    = (const float*)d_in[8];
  const float* b_out    = (const float*)d_in[9];
  float* out = (float*)d_out;

  const int M = MTOT;             // 4096
  const int MJ = BB * JTOT;       // 4378

  u16* p = (u16*)d_ws;
  const size_t qN = (size_t)M * INNER;
  const size_t ctxN = (size_t)MJ * TCD;
  const size_t kN = (size_t)BB * JPAD * INNER;   // padded K planes
  const size_t vN = (size_t)MJ * INNER;
  u16* cth = p; p += ctxN; u16* ctl = p; p += ctxN;
  u16* aoh = p; p += qN;   u16* aol = p; p += qN;
  u16* xh  = p; p += (size_t)M * QD;   u16* xl  = p; p += (size_t)M * QD;
  u16* prh = p; p += (size_t)NUM_PROMPT * PD;
  u16* prl = p; p += (size_t)NUM_PROMPT * PD;
  u16* WtPh = p; p += (size_t)TCD * PD;            u16* WtPl = p; p += (size_t)TCD * PD;
  u16* WtAh = p; p += (size_t)(TCD + INNER) * QD;  u16* WtAl = p; p += (size_t)(TCD + INNER) * QD;
  u16* WtBh = p; p += (size_t)(2 * INNER) * TCD;   u16* WtBl = p; p += (size_t)(2 * INNER) * TCD;
  u16* WtOh = p; p += (size_t)QD * INNER;          u16* WtOl = p; p += (size_t)QD * INNER;
  u16* qhp = p; p += qN;  u16* qlp = p; p += qN;   // q planes (pre-scaled)
  u16* khp = p; p += kN;  u16* klp = p; p += kN;   // K planes, JPAD rows per b
  u16* vhp = p; p += vN;  u16* vlp = p; p += vN;   // V planes
  u16* vthp = p; p += kN; u16* vtlp = p; p += kN;  // V^T planes [B][INNER][JPAD]

  // ---- pack inputs + text ctx rows (one launch) ----
  const int n4x = M * QD / 4, n4p = NUM_PROMPT * PD / 4;
  const int n4c = BB * CTX_LEN * TCD / 4;
  pack_planes3<<<(n4x + n4p + n4c + 255) / 256, 256, 0, stream>>>(
      x, xh, xl, n4x, prompt, prh, prl, n4p, context, cth, ctl, n4c);

  // ---- transpose+pack all 6 weights (one launch) ----
  TP6 tp;
  const float* srcs[6] = {w_prompt, w_img, w_q, w_k, w_v, w_out};
  u16* dhs[6] = {WtPh, WtAh, WtAh + (size_t)TCD * QD, WtBh, WtBh + (size_t)INNER * TCD, WtOh};
  u16* dls[6] = {WtPl, WtAl, WtAl + (size_t)TCD * QD, WtBl, WtBl + (size_t)INNER * TCD, WtOl};
  int Ks[6] = {PD, QD, QD, TCD, TCD, INNER};
  int Ns[6] = {TCD, TCD, INNER, INNER, INNER, QD};
  int acc_blk = 0;
  for (int i = 0; i < 6; ++i) {
    tp.src[i] = srcs[i]; tp.dh[i] = dhs[i]; tp.dl[i] = dls[i];
    tp.K[i] = Ks[i]; tp.N[i] = Ns[i];
    tp.blk0[i] = acc_blk;
    acc_blk += (Ns[i] / 32) * (Ks[i] / 32);
  }
  tp.blk0[6] = acc_blk;
  transpose_pack6<<<acc_blk, 256, 0, stream>>>(tp);

  // ---- x @ [w_img | w_q] -> ctx planes (remap) + q planes (x SCALE);
  //      extra band: prompt @ w_prompt -> ctx rows 77..140 (both b) ----
  gemm_mfma<1><<<dim3((TCD + INNER) / 64, M / 128 + 1), 256, 0, stream>>>(
      xh, xl, WtAh, WtAl, cth, ctl, qhp, qlp, nullptr, nullptr,
      M, QD, TCD + INNER, prh, prl, WtPh, WtPl);
  // ---- ctx @ [w_k | w_v] -> K padded planes + V planes ----
  gemm_mfma<2><<<dim3((2 * INNER) / 64, (MJ + 127) / 128), 256, 0, stream>>>(
      cth, ctl, WtBh, WtBl, khp, klp, vhp, vlp, nullptr, nullptr,
      MJ, TCD, 2 * INNER, nullptr, nullptr, nullptr, nullptr);
  // ---- V -> V^T (zero-padded to JPAD) ----
  vtrans<<<dim3(NT_J, INNER / 64, BB * 2), 256, 0, stream>>>(vhp, vlp, vthp, vtlp);
  // ---- attention ----
  attn_mfma2<<<BB * HEADS * (NN / 64), 256, 0, stream>>>(
      qhp, qlp, khp, klp, vthp, vtlp, aoh, aol);
  // ---- out = ao @ w_out + b_out ----
  gemm_mfma<3><<<dim3(QD / 64, M / 128), 256, 0, stream>>>(
      aoh, aol, WtOh, WtOl, nullptr, nullptr, nullptr, nullptr, out, b_out,
      M, INNER, QD, nullptr, nullptr, nullptr, nullptr);
}

// Round 8
// 286.719 us; speedup vs baseline: 1.1557x; 1.0305x over previous
//
#include <hip/hip_runtime.h>
#include <hip/hip_bf16.h>
#include <math.h>

#define BB 2
#define NN 2048
#define QD 1024
#define CTX_LEN 77
#define TCD 768
#define NUM_PROMPT 64
#define PD 1024
#define HEADS 8
#define DIM_HEAD 64
#define INNER 512
#define JTOT (CTX_LEN + NUM_PROMPT + NN)   // 2189
#define SCALE 0.125f
#define MTOT (BB * NN)                     // 4096
#define JPAD 2240                          // 35 * 64, attn j extent
#define KVPAD 2304                         // 18 * 128, K/V^T padded j extent (grid-friendly)
#define NT_J (JPAD / 64)                   // 35 j-tiles

typedef unsigned short u16;
typedef unsigned int u32;
typedef __attribute__((ext_vector_type(8))) short bf16x8;
typedef __attribute__((ext_vector_type(4))) float f32x4;

__device__ __forceinline__ u32 pack_split(float f) {   // interleaved: low16=hi, high16=lo
  u32 u = __builtin_bit_cast(u32, f);
  u32 hi = u & 0xffff0000u;
  float lo = f - __builtin_bit_cast(float, hi);
  u32 ul = __builtin_bit_cast(u32, lo);
  return __builtin_amdgcn_perm(ul, u, 0x07060302u);
}
__device__ __forceinline__ void split2(float f, u16& h, u16& l) {
  u32 u = __builtin_bit_cast(u32, f);
  u32 hm = u & 0xffff0000u;
  float lo = f - __builtin_bit_cast(float, hm);
  h = (u16)(u >> 16);
  l = (u16)(__builtin_bit_cast(u32, lo) >> 16);
}
__device__ __forceinline__ void pack4(const float4& f, ushort4& hh, ushort4& ll) {
  split2(f.x, hh.x, ll.x); split2(f.y, hh.y, ll.y);
  split2(f.z, hh.z, ll.z); split2(f.w, hh.w, ll.w);
}

// DPP lane move within 16-lane rows (ctrl must be ICE -> template)
template <int CTRL>
__device__ __forceinline__ float dpp_f(float x) {
  int i = __builtin_bit_cast(int, x);
  i = __builtin_amdgcn_update_dpp(0, i, CTRL, 0xF, 0xF, false);
  return __builtin_bit_cast(float, i);
}

// async global->LDS, 16B per lane; lds dest = base + lane*16
__device__ __forceinline__ void gload16(const u16* g, u32* l) {
  __builtin_amdgcn_global_load_lds(
      (const __attribute__((address_space(1))) u32*)(const void*)g,
      (__attribute__((address_space(3))) u32*)(void*)l, 16, 0, 0);
}

// ---------------- merged f32 -> hi/lo plane pack: x, prompt, text-ctx rows, V^T pad-zero ----------------
__global__ __launch_bounds__(256) void pack_planes4(
    const float* __restrict__ s0, u16* __restrict__ d0h, u16* __restrict__ d0l, int n0,
    const float* __restrict__ s1, u16* __restrict__ d1h, u16* __restrict__ d1l, int n1,
    const float* __restrict__ ctx, u16* __restrict__ ch, u16* __restrict__ cl, int n2,
    u16* __restrict__ zh, u16* __restrict__ zl, int n3) {
  int i = blockIdx.x * 256 + threadIdx.x;
  ushort4 hh, ll;
  if (i < n0) {
    pack4(((const float4*)s0)[i], hh, ll);
    ((ushort4*)d0h)[i] = hh; ((ushort4*)d0l)[i] = ll;
    return;
  }
  i -= n0;
  if (i < n1) {
    pack4(((const float4*)s1)[i], hh, ll);
    ((ushort4*)d1h)[i] = hh; ((ushort4*)d1l)[i] = ll;
    return;
  }
  i -= n1;
  if (i < n2) {
    // text context rows -> ctx planes rows [b*JTOT + r], r < CTX_LEN
    pack4(((const float4*)ctx)[i], hh, ll);
    int c4 = i % (TCD / 4);
    int rb = i / (TCD / 4);
    int r = rb % CTX_LEN, b = rb / CTX_LEN;
    size_t o = ((size_t)b * JTOT + r) * (TCD / 4) + c4;   // ushort4 units
    ((ushort4*)ch)[o] = hh; ((ushort4*)cl)[o] = ll;
    return;
  }
  i -= n2;
  if (i >= n3) return;
  // zero-fill V^T j in [2176, 2240): 8 chunks of 8 u16 per (plane,b,d) row
  int c = i & 7;
  int row = i >> 3;            // [plane(2)][b(2)][d(512)]
  int d = row & 511;
  int b = (row >> 9) & 1;
  u16* base = (row >> 10) ? zl : zh;
  uint4 z = {0u, 0u, 0u, 0u};
  *(uint4*)&base[((size_t)b * INNER + d) * KVPAD + 2176 + c * 8] = z;
}

// ---------------- merged weight transpose+pack: 6 sources, one launch ----------------
struct TP6 {
  const float* src[6];
  u16* dh[6];
  u16* dl[6];
  int K[6], N[6];
  int blk0[7];   // cumulative block offsets, blk0[6] = total blocks
};

__global__ __launch_bounds__(256) void transpose_pack6(TP6 P) {
  __shared__ u32 T[32][33];
  const int bid = blockIdx.x;
  int s = 0;
#pragma unroll
  for (int k = 1; k < 6; ++k) s += (bid >= P.blk0[k]);
  const int rel = bid - P.blk0[s];
  const int N = P.N[s], K = P.K[s];
  const int nbx = N >> 5;
  const int bx = rel % nbx, by = rel / nbx;
  const float* __restrict__ src = P.src[s];
  u16* __restrict__ dh = P.dh[s];
  u16* __restrict__ dl = P.dl[s];
  const int t = threadIdx.x;
  const int k0 = by * 32, n0 = bx * 32;
#pragma unroll
  for (int i = 0; i < 4; ++i) {
    int e = t + i * 256;
    int kr = e >> 5, nc = e & 31;
    T[kr][nc] = pack_split(src[(size_t)(k0 + kr) * N + n0 + nc]);
  }
  __syncthreads();
#pragma unroll
  for (int i = 0; i < 4; ++i) {
    int e = t + i * 256;
    int nr = e >> 5, kc = e & 31;
    u32 w = T[kc][nr];
    size_t idx = (size_t)(n0 + nr) * K + k0 + kc;
    dh[idx] = (u16)(w & 0xffff);
    dl[idx] = (u16)(w >> 16);
  }
}

// ---------------- split-bf16 MFMA GEMM, 128x64 tiles, BK=64, bijective XCD swizzle ----------------
// MODE 1: gn<TCD -> ctx planes (row remap); else q planes (x SCALE) -> O2h/O2l.
//         Extra grid band bm>=MTOT: prompt@w_prompt -> ctx rows 77..140 (both b).
// MODE 2: grid y = 36 (18 per batch, no batch straddle). gn<INNER -> K planes
//         [B][KVPAD][INNER]; else V^T planes [B][INNER][KVPAD] via LDS transpose.
// MODE 3: f32 out + bias
template <int MODE>
__global__ __launch_bounds__(256) void gemm_mfma(
    const u16* __restrict__ Agh, const u16* __restrict__ Agl,
    const u16* __restrict__ Bgh, const u16* __restrict__ Bgl,
    u16* __restrict__ O1h, u16* __restrict__ O1l,
    u16* __restrict__ O2h, u16* __restrict__ O2l,
    float* __restrict__ Of, const float* __restrict__ bias,
    int M, int K, int Ntot,
    const u16* __restrict__ A2h, const u16* __restrict__ A2l,
    const u16* __restrict__ B2h, const u16* __restrict__ B2l) {
  __shared__ __align__(16) u32 Ah_s[2][128 * 16];
  __shared__ __align__(16) u32 Al_s[2][128 * 16];
  __shared__ __align__(16) u32 Bh_s[2][64 * 16];
  __shared__ __align__(16) u32 Bl_s[2][64 * 16];

  // bijective chunked XCD swizzle (m204): each XCD owns a contiguous grid chunk
  int bxi = blockIdx.x, byi = blockIdx.y;
  {
    const int GX = gridDim.x;
    const int nwg = GX * gridDim.y;
    const int lid = byi * GX + bxi;
    const int qq = nwg >> 3, rr = nwg & 7;
    const int xcd = lid & 7, pos = lid >> 3;
    const int swz = (xcd < rr ? xcd * (qq + 1) : rr * (qq + 1) + (xcd - rr) * qq) + pos;
    bxi = swz % GX; byi = swz / GX;
  }
  const int bm = byi * 128, bn = bxi * 64;

  const bool pband = (MODE == 1) && (bm >= MTOT);
  if (pband && bn >= TCD) return;   // block-uniform: idle prompt-band columns

  int b2 = 0, jbase = 0;
  if (MODE == 2) { b2 = (byi >= 18); jbase = (byi - b2 * 18) * 128; }

  const int t = threadIdx.x;
  const int w = t >> 6, lane = t & 63;
  const int m16 = lane & 15, quad = lane >> 4;
  const int wm = w >> 1, wn = w & 1;

  const u16* Abh = Agh; const u16* Abl = Agl;
  const u16* Bbh = Bgh; const u16* Bbl = Bgl;
  int rowlim = M - 1;
  int bmA = bm;
  if (pband) { Abh = A2h; Abl = A2l; Bbh = B2h; Bbl = B2l; rowlim = NUM_PROMPT - 1; bmA = 0; }

  // DMA staging geometry: 4 lanes per 64B row, lane's 16B slot = (lane&3)*8 u16.
  // Wave w: A rows 32w..32w+31 (2 calls of 16 rows), B rows 16w..16w+15 (1 call).
  const int acol = (lane & 3) * 8;
  const int ar0 = 32 * w + (lane >> 2);
  const int ar1 = ar0 + 16;
  int ag0, ag1;
  if (MODE == 2) {
    ag0 = b2 * JTOT + min(jbase + ar0, JTOT - 1);   // clamp inside batch: no straddle
    ag1 = b2 * JTOT + min(jbase + ar1, JTOT - 1);
  } else {
    ag0 = min(bmA + ar0, rowlim);
    ag1 = min(bmA + ar1, rowlim);
  }
  const u16* a0h = Abh + (size_t)ag0 * K + acol;
  const u16* a1h = Abh + (size_t)ag1 * K + acol;
  const u16* a0l = Abl + (size_t)ag0 * K + acol;
  const u16* a1l = Abl + (size_t)ag1 * K + acol;
  const int br = 16 * w + (lane >> 2);
  const u16* b0h = Bbh + (size_t)(bn + br) * K + acol;
  const u16* b0l = Bbl + (size_t)(bn + br) * K + acol;

  f32x4 acc[4][2];
#pragma unroll
  for (int i = 0; i < 4; ++i)
#pragma unroll
    for (int j = 0; j < 2; ++j) acc[i][j] = (f32x4){0.f, 0.f, 0.f, 0.f};

  for (int k0 = 0; k0 < K; k0 += 64) {
    // ---- async stage both 32-col sub-tiles ----
#pragma unroll
    for (int s = 0; s < 2; ++s) {
      const int kc = k0 + s * 32;
      gload16(a0h + kc, &Ah_s[s][(2 * w) * 256]);
      gload16(a1h + kc, &Ah_s[s][(2 * w + 1) * 256]);
      gload16(a0l + kc, &Al_s[s][(2 * w) * 256]);
      gload16(a1l + kc, &Al_s[s][(2 * w + 1) * 256]);
      gload16(b0h + kc, &Bh_s[s][w * 256]);
      gload16(b0l + kc, &Bl_s[s][w * 256]);
    }
    __syncthreads();   // drains DMA (compiler emits vmcnt(0) before barrier)

#pragma unroll
    for (int s = 0; s < 2; ++s) {
      bf16x8 ah[4], al[4], bh[2], bl[2];
#pragma unroll
      for (int mt = 0; mt < 4; ++mt) {
        int off = (wm * 64 + mt * 16 + m16) * 16 + quad * 4;
        ah[mt] = *(const bf16x8*)&Ah_s[s][off];
        al[mt] = *(const bf16x8*)&Al_s[s][off];
      }
#pragma unroll
      for (int nt = 0; nt < 2; ++nt) {
        int off = (wn * 32 + nt * 16 + m16) * 16 + quad * 4;
        bh[nt] = *(const bf16x8*)&Bh_s[s][off];
        bl[nt] = *(const bf16x8*)&Bl_s[s][off];
      }
#pragma unroll
      for (int mt = 0; mt < 4; ++mt)
#pragma unroll
        for (int nt = 0; nt < 2; ++nt) {
          acc[mt][nt] = __builtin_amdgcn_mfma_f32_16x16x32_bf16(ah[mt], bh[nt], acc[mt][nt], 0, 0, 0);
          acc[mt][nt] = __builtin_amdgcn_mfma_f32_16x16x32_bf16(ah[mt], bl[nt], acc[mt][nt], 0, 0, 0);
          acc[mt][nt] = __builtin_amdgcn_mfma_f32_16x16x32_bf16(al[mt], bh[nt], acc[mt][nt], 0, 0, 0);
        }
    }
    __syncthreads();   // frag reads done before next DMA overwrites
  }

  if (MODE == 2 && bn >= INNER) {
    // ---- V^T direct write: LDS transpose (XOR-swizzled) + coalesced 16B stores ----
    u16* Th = (u16*)Ah_s;   // 16KB = [64 d][128 j] u16, chunk-XOR layout
    u16* Tl = (u16*)Al_s;
#pragma unroll
    for (int mt = 0; mt < 4; ++mt)
#pragma unroll
      for (int nt = 0; nt < 2; ++nt)
#pragma unroll
        for (int r = 0; r < 4; ++r) {
          int dl = wn * 32 + nt * 16 + m16;
          int jl = wm * 64 + mt * 16 + quad * 4 + r;
          u16 sh, sl;
          split2(acc[mt][nt][r], sh, sl);
          int adr = dl * 128 + ((((jl >> 3) ^ (dl & 15)) << 3) | (jl & 7));
          Th[adr] = sh;
          Tl[adr] = sl;
        }
    __syncthreads();
#pragma unroll
    for (int i = 0; i < 4; ++i) {
      int chunk = t + i * 256;            // 1024 chunks = 64 d x 16 j-chunks
      int dl = chunk >> 4, jc = chunk & 15;
      int jg = jbase + jc * 8;
      int lofs = dl * 128 + ((jc ^ (dl & 15)) << 3);
      uint4 vh4 = *(const uint4*)&Th[lofs];
      uint4 vl4 = *(const uint4*)&Tl[lofs];
      size_t rowo = ((size_t)b2 * INNER + (bn - INNER) + dl) * KVPAD;
      if (jg + 8 <= JTOT) {
        *(uint4*)&O2h[rowo + jg] = vh4;
        *(uint4*)&O2l[rowo + jg] = vl4;
      } else if (jg < JTOT) {
        const u16* eh = (const u16*)&vh4;
        const u16* el = (const u16*)&vl4;
#pragma unroll
        for (int e = 0; e < 8; ++e)
          if (jg + e < JTOT) { O2h[rowo + jg + e] = eh[e]; O2l[rowo + jg + e] = el[e]; }
      }   // jg >= JTOT: keep pre-zeroed pad
    }
    return;
  }

#pragma unroll
  for (int mt = 0; mt < 4; ++mt)
#pragma unroll
    for (int nt = 0; nt < 2; ++nt)
#pragma unroll
      for (int r = 0; r < 4; ++r) {
        int gm = bm + wm * 64 + mt * 16 + quad * 4 + r;
        int gn = bn + wn * 32 + nt * 16 + m16;
        float v = acc[mt][nt][r];
        u16 sh, sl;
        if (MODE == 1) {
          if (pband) {
            int pr = wm * 64 + mt * 16 + quad * 4 + r;
            if (pr < NUM_PROMPT && gn < TCD) {
              split2(v, sh, sl);
              size_t r0 = ((size_t)CTX_LEN + pr) * TCD + gn;          // b = 0
              size_t r1 = ((size_t)JTOT + CTX_LEN + pr) * TCD + gn;   // b = 1
              O1h[r0] = sh; O1l[r0] = sl;
              O1h[r1] = sh; O1l[r1] = sl;
            }
          } else if (gn < TCD) {
            split2(v, sh, sl);
            size_t row = (size_t)(gm >> 11) * JTOT + 141 + (gm & 2047);
            O1h[row * TCD + gn] = sh; O1l[row * TCD + gn] = sl;
          } else {
            split2(v * SCALE, sh, sl);
            size_t idx = (size_t)gm * INNER + (gn - TCD);
            O2h[idx] = sh; O2l[idx] = sl;
          }
        } else if (MODE == 2) {
          // K half: [B][KVPAD][INNER]; rows >= JTOT hold clamped dup data, masked in attn
          int jloc = jbase + wm * 64 + mt * 16 + quad * 4 + r;
          split2(v, sh, sl);
          size_t idx = ((size_t)b2 * KVPAD + jloc) * INNER + gn;
          O1h[idx] = sh; O1l[idx] = sl;
        } else if (MODE == 3) {
          Of[(size_t)gm * QD + gn] = v + bias[gn];
        }
      }
}

// ---------------- plane-format MFMA flash attention (R4 structure + T13 defer-max) ----------------
// K planes [B][KVPAD][INNER], V^T planes [B][INNER][KVPAD]; staged via global_load_lds
// with pre-swizzled source (XOR chunk swizzle) -> conflict-free ds_read_b128 fragments.
__global__ __launch_bounds__(256) void attn_mfma2(
    const u16* __restrict__ qhg, const u16* __restrict__ qlg,
    const u16* __restrict__ khg, const u16* __restrict__ klg,
    const u16* __restrict__ vtg_h, const u16* __restrict__ vtg_l,
    u16* __restrict__ aoh, u16* __restrict__ aol) {
  __shared__ __align__(16) u16 Kh_s[64 * 64];
  __shared__ __align__(16) u16 Kl_s[64 * 64];
  __shared__ __align__(16) u16 Vh_s[64 * 64];
  __shared__ __align__(16) u16 Vl_s[64 * 64];
  __shared__ __align__(16) u16 Ph_s[64 * 72];
  __shared__ __align__(16) u16 Pl_s[64 * 72];

  const int t = threadIdx.x;
  const int w = t >> 6, lane = t & 63;
  const int m16 = lane & 15, quad = lane >> 4;

  // XCD swizzle: 512 blocks = 8 * 64; each XCD gets 2 contiguous (b,h) groups
  const int id = blockIdx.x;
  const int swz = (id & 7) * 64 + (id >> 3);
  const int qt = swz & 31, bh = swz >> 5;
  const int b = bh >> 3, h = bh & 7;
  const int qrow0 = qt * 64;

  // Q fragments direct from global planes (A-frag: row=m16, k=ks*32+quad*8)
  bf16x8 qh[2], ql[2];
  {
    size_t qoff = ((size_t)(b * NN + qrow0 + w * 16 + m16)) * INNER + h * 64 + quad * 8;
#pragma unroll
    for (int ks = 0; ks < 2; ++ks) {
      qh[ks] = *(const bf16x8*)(qhg + qoff + ks * 32);
      ql[ks] = *(const bf16x8*)(qlg + qoff + ks * 32);
    }
  }

  // Staging: wave w stages plane w (0:Kh 1:Kl 2:Vh^T 3:Vl^T).
  // Per call: 8 rows x 8 chunks of 16B; dest linear, source chunk = (lane&7)^(lane>>3)
  // so LDS (row, cc) holds logical chunk cc^(row&7).
  const int sr = lane >> 3;
  const int sc = (lane & 7) ^ sr;
  const u16* gp;
  u32* lp;
  size_t cstr, jstr;
  if (w < 2) {
    gp = ((w == 0) ? khg : klg) + ((size_t)b * KVPAD + sr) * INNER + h * 64 + sc * 8;
    lp = (u32*)((w == 0) ? Kh_s : Kl_s);
    cstr = (size_t)8 * INNER;
    jstr = (size_t)64 * INNER;
  } else {
    gp = ((w == 2) ? vtg_h : vtg_l) + ((size_t)b * INNER + h * 64 + sr) * KVPAD + sc * 8;
    lp = (u32*)((w == 2) ? Vh_s : Vl_s);
    cstr = (size_t)8 * KVPAD;
    jstr = 64;
  }

  f32x4 O[4] = {{0.f,0.f,0.f,0.f},{0.f,0.f,0.f,0.f},{0.f,0.f,0.f,0.f},{0.f,0.f,0.f,0.f}};
  float mrow[4], lrow[4];
#pragma unroll
  for (int r = 0; r < 4; ++r) { mrow[r] = -INFINITY; lrow[r] = 0.f; }

  for (int tile = 0; tile < NT_J; ++tile) {
    const int j0 = tile * 64;
    __syncthreads();                       // prior tile fully consumed
#pragma unroll
    for (int c = 0; c < 8; ++c) gload16(gp + (size_t)c * cstr, lp + c * 256);
    gp += jstr;
    __syncthreads();                       // drain DMA (vmcnt(0) before barrier)

    // ---- QK^T ----
    f32x4 S[4];
    __builtin_amdgcn_s_setprio(1);
#pragma unroll
    for (int jt = 0; jt < 4; ++jt) {
      const int row = jt * 16 + m16;
      f32x4 acc = {0.f, 0.f, 0.f, 0.f};
#pragma unroll
      for (int ks = 0; ks < 2; ++ks) {
        const int cc = row * 64 + (((ks * 4 + quad) ^ (row & 7)) << 3);
        bf16x8 kh = *(const bf16x8*)&Kh_s[cc];
        bf16x8 kl = *(const bf16x8*)&Kl_s[cc];
        acc = __builtin_amdgcn_mfma_f32_16x16x32_bf16(qh[ks], kh, acc, 0, 0, 0);
        acc = __builtin_amdgcn_mfma_f32_16x16x32_bf16(qh[ks], kl, acc, 0, 0, 0);
        acc = __builtin_amdgcn_mfma_f32_16x16x32_bf16(ql[ks], kh, acc, 0, 0, 0);
      }
      S[jt] = acc;
    }
    __builtin_amdgcn_s_setprio(0);

    // mask tail columns (also covers K pad-row garbage)
#pragma unroll
    for (int jt = 0; jt < 4; ++jt) {
      int jc = j0 + jt * 16 + m16;
      if (jc >= JTOT)
#pragma unroll
        for (int r = 0; r < 4; ++r) S[jt][r] = -INFINITY;
    }

    // ---- online softmax: DPP reductions + T13 defer-max (skip rescale unless max grew >8) ----
    float pj[4][4];
#pragma unroll
    for (int r = 0; r < 4; ++r) {
      float mx = fmaxf(fmaxf(S[0][r], S[1][r]), fmaxf(S[2][r], S[3][r]));
      mx = fmaxf(mx, dpp_f<0xB1>(mx));     // quad_perm [1,0,3,2] = xor1
      mx = fmaxf(mx, dpp_f<0x4E>(mx));     // quad_perm [2,3,0,1] = xor2
      mx = fmaxf(mx, dpp_f<0x124>(mx));    // row_ror:4
      mx = fmaxf(mx, dpp_f<0x128>(mx));    // row_ror:8
      float alpha = 1.f;
      if (__any(mx - mrow[r] > 8.f)) {     // wave-uniform vote
        float mnew = fmaxf(mrow[r], mx);
        alpha = __expf(mrow[r] - mnew);
        mrow[r] = mnew;
#pragma unroll
        for (int nt = 0; nt < 4; ++nt) O[nt][r] *= alpha;
      }
      float rs = 0.f;
#pragma unroll
      for (int jt = 0; jt < 4; ++jt) {
        float pv = __expf(S[jt][r] - mrow[r]);
        pj[jt][r] = pv;
        rs += pv;
      }
      rs += dpp_f<0xB1>(rs);
      rs += dpp_f<0x4E>(rs);
      rs += dpp_f<0x124>(rs);
      rs += dpp_f<0x128>(rs);
      lrow[r] = lrow[r] * alpha + rs;
    }

    // ---- P -> LDS planes (rows are wave-private: no barrier needed) ----
#pragma unroll
    for (int jt = 0; jt < 4; ++jt)
#pragma unroll
      for (int r = 0; r < 4; ++r) {
        u16 sh, sl;
        split2(pj[jt][r], sh, sl);
        int pq = (w * 16 + quad * 4 + r) * 72 + jt * 16 + m16;
        Ph_s[pq] = sh;
        Pl_s[pq] = sl;
      }

    bf16x8 ph[2], pl[2];
#pragma unroll
    for (int ks = 0; ks < 2; ++ks) {
      int po = (w * 16 + m16) * 72 + ks * 32 + quad * 8;
      ph[ks] = *(const bf16x8*)&Ph_s[po];
      pl[ks] = *(const bf16x8*)&Pl_s[po];
    }

    // ---- PV (B-frag = V^T rows d) ----
    __builtin_amdgcn_s_setprio(1);
#pragma unroll
    for (int nt = 0; nt < 4; ++nt) {
      const int row = nt * 16 + m16;
#pragma unroll
      for (int ks = 0; ks < 2; ++ks) {
        const int cc = row * 64 + (((ks * 4 + quad) ^ (row & 7)) << 3);
        bf16x8 vh = *(const bf16x8*)&Vh_s[cc];
        bf16x8 vl = *(const bf16x8*)&Vl_s[cc];
        O[nt] = __builtin_amdgcn_mfma_f32_16x16x32_bf16(ph[ks], vh, O[nt], 0, 0, 0);
        O[nt] = __builtin_amdgcn_mfma_f32_16x16x32_bf16(ph[ks], vl, O[nt], 0, 0, 0);
        O[nt] = __builtin_amdgcn_mfma_f32_16x16x32_bf16(pl[ks], vh, O[nt], 0, 0, 0);
      }
    }
    __builtin_amdgcn_s_setprio(0);
  }

  float inv[4];
#pragma unroll
  for (int r = 0; r < 4; ++r) inv[r] = 1.f / lrow[r];
#pragma unroll
  for (int nt = 0; nt < 4; ++nt)
#pragma unroll
    for (int r = 0; r < 4; ++r) {
      size_t idx = ((size_t)(b * NN + qrow0 + w * 16 + quad * 4 + r)) * INNER +
                   h * 64 + nt * 16 + m16;
      u16 sh, sl;
      split2(O[nt][r] * inv[r], sh, sl);
      aoh[idx] = sh; aol[idx] = sl;
    }
}

// ---------------- launch ----------------
extern "C" void kernel_launch(void* const* d_in, const int* in_sizes, int n_in,
                              void* d_out, int out_size, void* d_ws, size_t ws_size,
                              hipStream_t stream) {
  const float* x        = (const float*)d_in[0];
  const float* context  = (const float*)d_in[1];
  const float* prompt   = (const float*)d_in[2];
  const float* w_prompt = (const float*)d_in[3];
  const float* w_img    = (const float*)d_in[4];
  const float* w_q      = (const float*)d_in[5];
  const float* w_k      = (const float*)d_in[6];
  const float* w_v      = (const float*)d_in[7];
  const float* w_out    = (const float*)d_in[8];
  const float* b_out    = (const float*)d_in[9];
  float* out = (float*)d_out;

  const int M = MTOT;             // 4096
  const int MJ = BB * JTOT;       // 4378

  u16* p = (u16*)d_ws;
  const size_t qN = (size_t)M * INNER;
  const size_t ctxN = (size_t)MJ * TCD;
  const size_t kN = (size_t)BB * KVPAD * INNER;  // K / V^T plane size
  u16* cth = p; p += ctxN; u16* ctl = p; p += ctxN;
  u16* aoh = p; p += qN;   u16* aol = p; p += qN;
  u16* xh  = p; p += (size_t)M * QD;   u16* xl  = p; p += (size_t)M * QD;
  u16* prh = p; p += (size_t)NUM_PROMPT * PD;
  u16* prl = p; p += (size_t)NUM_PROMPT * PD;
  u16* WtPh = p; p += (size_t)TCD * PD;            u16* WtPl = p; p += (size_t)TCD * PD;
  u16* WtAh = p; p += (size_t)(TCD + INNER) * QD;  u16* WtAl = p; p += (size_t)(TCD + INNER) * QD;
  u16* WtBh = p; p += (size_t)(2 * INNER) * TCD;   u16* WtBl = p; p += (size_t)(2 * INNER) * TCD;
  u16* WtOh = p; p += (size_t)QD * INNER;          u16* WtOl = p; p += (size_t)QD * INNER;
  u16* qhp = p; p += qN;  u16* qlp = p; p += qN;   // q planes (pre-scaled)
  u16* khp = p; p += kN;  u16* klp = p; p += kN;   // K planes [B][KVPAD][INNER]
  u16* vthp = p; p += kN; u16* vtlp = p; p += kN;  // V^T planes [B][INNER][KVPAD]

  // ---- pack inputs + text ctx rows + V^T pad zero-fill (one launch) ----
  const int n4x = M * QD / 4, n4p = NUM_PROMPT * PD / 4;
  const int n4c = BB * CTX_LEN * TCD / 4;
  const int n4z = 2 * BB * INNER * 8;   // 16384 zero chunks of 16B
  pack_planes4<<<(n4x + n4p + n4c + n4z + 255) / 256, 256, 0, stream>>>(
      x, xh, xl, n4x, prompt, prh, prl, n4p, context, cth, ctl, n4c,
      vthp, vtlp, n4z);

  // ---- transpose+pack all 6 weights (one launch) ----
  TP6 tp;
  const float* srcs[6] = {w_prompt, w_img, w_q, w_k, w_v, w_out};
  u16* dhs[6] = {WtPh, WtAh, WtAh + (size_t)TCD * QD, WtBh, WtBh + (size_t)INNER * TCD, WtOh};
  u16* dls[6] = {WtPl, WtAl, WtAl + (size_t)TCD * QD, WtBl, WtBl + (size_t)INNER * TCD, WtOl};
  int Ks[6] = {PD, QD, QD, TCD, TCD, INNER};
  int Ns[6] = {TCD, TCD, INNER, INNER, INNER, QD};
  int acc_blk = 0;
  for (int i = 0; i < 6; ++i) {
    tp.src[i] = srcs[i]; tp.dh[i] = dhs[i]; tp.dl[i] = dls[i];
    tp.K[i] = Ks[i]; tp.N[i] = Ns[i];
    tp.blk0[i] = acc_blk;
    acc_blk += (Ns[i] / 32) * (Ks[i] / 32);
  }
  tp.blk0[6] = acc_blk;
  transpose_pack6<<<acc_blk, 256, 0, stream>>>(tp);

  // ---- x @ [w_img | w_q] -> ctx planes (remap) + q planes (x SCALE);
  //      extra band: prompt @ w_prompt -> ctx rows 77..140 (both b) ----
  gemm_mfma<1><<<dim3((TCD + INNER) / 64, M / 128 + 1), 256, 0, stream>>>(
      xh, xl, WtAh, WtAl, cth, ctl, qhp, qlp, nullptr, nullptr,
      M, QD, TCD + INNER, prh, prl, WtPh, WtPl);
  // ---- ctx @ [w_k | w_v] -> K planes + V^T planes (direct transpose write) ----
  gemm_mfma<2><<<dim3((2 * INNER) / 64, 2 * (KVPAD / 128)), 256, 0, stream>>>(
      cth, ctl, WtBh, WtBl, khp, klp, vthp, vtlp, nullptr, nullptr,
      MJ, TCD, 2 * INNER, nullptr, nullptr, nullptr, nullptr);
  // ---- attention ----
  attn_mfma2<<<BB * HEADS * (NN / 64), 256, 0, stream>>>(
      qhp, qlp, khp, klp, vthp, vtlp, aoh, aol);
  // ---- out = ao @ w_out + b_out ----
  gemm_mfma<3><<<dim3(QD / 64, M / 128), 256, 0, stream>>>(
      aoh, aol, WtOh, WtOl, nullptr, nullptr, nullptr, nullptr, out, b_out,
      M, INNER, QD, nullptr, nullptr, nullptr, nullptr);
}

// Round 10
// 285.739 us; speedup vs baseline: 1.1597x; 1.0034x over previous
//
#include <hip/hip_runtime.h>
#include <hip/hip_bf16.h>
#include <math.h>

#define BB 2
#define NN 2048
#define QD 1024
#define CTX_LEN 77
#define TCD 768
#define NUM_PROMPT 64
#define PD 1024
#define HEADS 8
#define DIM_HEAD 64
#define INNER 512
#define JTOT (CTX_LEN + NUM_PROMPT + NN)   // 2189
#define SCALE 0.125f
#define SCALEL2 (0.125f * 1.44269504088896f)   // fold log2(e): softmax in exp2 domain
#define MTOT (BB * NN)                     // 4096
#define JPAD 2240                          // 35 * 64, attn j extent
#define KVPAD 2304                         // 18 * 128, K/V^T padded j extent (grid-friendly)
#define NT_J (JPAD / 64)                   // 35 j-tiles

typedef unsigned short u16;
typedef unsigned int u32;
typedef __attribute__((ext_vector_type(8))) short bf16x8;
typedef __attribute__((ext_vector_type(4))) float f32x4;

__device__ __forceinline__ u32 pack_split(float f) {   // interleaved: low16=hi, high16=lo
  u32 u = __builtin_bit_cast(u32, f);
  u32 hi = u & 0xffff0000u;
  float lo = f - __builtin_bit_cast(float, hi);
  u32 ul = __builtin_bit_cast(u32, lo);
  return __builtin_amdgcn_perm(ul, u, 0x07060302u);
}
__device__ __forceinline__ void split2(float f, u16& h, u16& l) {
  u32 u = __builtin_bit_cast(u32, f);
  u32 hm = u & 0xffff0000u;
  float lo = f - __builtin_bit_cast(float, hm);
  h = (u16)(u >> 16);
  l = (u16)(__builtin_bit_cast(u32, lo) >> 16);
}
__device__ __forceinline__ void pack4(const float4& f, ushort4& hh, ushort4& ll) {
  split2(f.x, hh.x, ll.x); split2(f.y, hh.y, ll.y);
  split2(f.z, hh.z, ll.z); split2(f.w, hh.w, ll.w);
}

// DPP lane move within 16-lane rows (ctrl must be ICE -> template)
template <int CTRL>
__device__ __forceinline__ float dpp_f(float x) {
  int i = __builtin_bit_cast(int, x);
  i = __builtin_amdgcn_update_dpp(0, i, CTRL, 0xF, 0xF, false);
  return __builtin_bit_cast(float, i);
}

// async global->LDS, 16B per lane; lds dest = base + lane*16
__device__ __forceinline__ void gload16(const u16* g, u32* l) {
  __builtin_amdgcn_global_load_lds(
      (const __attribute__((address_space(1))) u32*)(const void*)g,
      (__attribute__((address_space(3))) u32*)(void*)l, 16, 0, 0);
}

// ---------------- merged f32 -> hi/lo plane pack: x, prompt, text-ctx rows, V^T pad-zero ----------------
__global__ __launch_bounds__(256) void pack_planes4(
    const float* __restrict__ s0, u16* __restrict__ d0h, u16* __restrict__ d0l, int n0,
    const float* __restrict__ s1, u16* __restrict__ d1h, u16* __restrict__ d1l, int n1,
    const float* __restrict__ ctx, u16* __restrict__ ch, u16* __restrict__ cl, int n2,
    u16* __restrict__ zh, u16* __restrict__ zl, int n3) {
  int i = blockIdx.x * 256 + threadIdx.x;
  ushort4 hh, ll;
  if (i < n0) {
    pack4(((const float4*)s0)[i], hh, ll);
    ((ushort4*)d0h)[i] = hh; ((ushort4*)d0l)[i] = ll;
    return;
  }
  i -= n0;
  if (i < n1) {
    pack4(((const float4*)s1)[i], hh, ll);
    ((ushort4*)d1h)[i] = hh; ((ushort4*)d1l)[i] = ll;
    return;
  }
  i -= n1;
  if (i < n2) {
    // text context rows -> ctx planes rows [b*JTOT + r], r < CTX_LEN
    pack4(((const float4*)ctx)[i], hh, ll);
    int c4 = i % (TCD / 4);
    int rb = i / (TCD / 4);
    int r = rb % CTX_LEN, b = rb / CTX_LEN;
    size_t o = ((size_t)b * JTOT + r) * (TCD / 4) + c4;   // ushort4 units
    ((ushort4*)ch)[o] = hh; ((ushort4*)cl)[o] = ll;
    return;
  }
  i -= n2;
  if (i >= n3) return;
  // zero-fill V^T j in [2176, 2240): 8 chunks of 8 u16 per (plane,b,d) row
  int c = i & 7;
  int row = i >> 3;            // [plane(2)][b(2)][d(512)]
  int d = row & 511;
  int b = (row >> 9) & 1;
  u16* base = (row >> 10) ? zl : zh;
  uint4 z = {0u, 0u, 0u, 0u};
  *(uint4*)&base[((size_t)b * INNER + d) * KVPAD + 2176 + c * 8] = z;
}

// ---------------- merged weight transpose+pack: 6 sources, one launch ----------------
struct TP6 {
  const float* src[6];
  u16* dh[6];
  u16* dl[6];
  int K[6], N[6];
  int blk0[7];   // cumulative block offsets, blk0[6] = total blocks
};

__global__ __launch_bounds__(256) void transpose_pack6(TP6 P) {
  __shared__ u32 T[32][33];
  const int bid = blockIdx.x;
  int s = 0;
#pragma unroll
  for (int k = 1; k < 6; ++k) s += (bid >= P.blk0[k]);
  const int rel = bid - P.blk0[s];
  const int N = P.N[s], K = P.K[s];
  const int nbx = N >> 5;
  const int bx = rel % nbx, by = rel / nbx;
  const float* __restrict__ src = P.src[s];
  u16* __restrict__ dh = P.dh[s];
  u16* __restrict__ dl = P.dl[s];
  const int t = threadIdx.x;
  const int k0 = by * 32, n0 = bx * 32;
#pragma unroll
  for (int i = 0; i < 4; ++i) {
    int e = t + i * 256;
    int kr = e >> 5, nc = e & 31;
    T[kr][nc] = pack_split(src[(size_t)(k0 + kr) * N + n0 + nc]);
  }
  __syncthreads();
#pragma unroll
  for (int i = 0; i < 4; ++i) {
    int e = t + i * 256;
    int nr = e >> 5, kc = e & 31;
    u32 w = T[kc][nr];
    size_t idx = (size_t)(n0 + nr) * K + k0 + kc;
    dh[idx] = (u16)(w & 0xffff);
    dl[idx] = (u16)(w >> 16);
  }
}

// ---------------- split-bf16 MFMA GEMM, 128x64 tiles, BK=64, bijective XCD swizzle ----------------
// MODE 1: gn<TCD -> ctx planes (row remap); else q planes (x SCALEL2) -> O2h/O2l.
//         Extra grid band bm>=MTOT: prompt@w_prompt -> ctx rows 77..140 (both b).
// MODE 2: grid y = 36 (18 per batch, no batch straddle). gn<INNER -> K planes
//         [B][KVPAD][INNER]; else V^T planes [B][INNER][KVPAD] via LDS transpose.
// MODE 3: f32 out + bias
template <int MODE>
__global__ __launch_bounds__(256) void gemm_mfma(
    const u16* __restrict__ Agh, const u16* __restrict__ Agl,
    const u16* __restrict__ Bgh, const u16* __restrict__ Bgl,
    u16* __restrict__ O1h, u16* __restrict__ O1l,
    u16* __restrict__ O2h, u16* __restrict__ O2l,
    float* __restrict__ Of, const float* __restrict__ bias,
    int M, int K, int Ntot,
    const u16* __restrict__ A2h, const u16* __restrict__ A2l,
    const u16* __restrict__ B2h, const u16* __restrict__ B2l) {
  __shared__ __align__(16) u32 Ah_s[2][128 * 16];
  __shared__ __align__(16) u32 Al_s[2][128 * 16];
  __shared__ __align__(16) u32 Bh_s[2][64 * 16];
  __shared__ __align__(16) u32 Bl_s[2][64 * 16];

  // bijective chunked XCD swizzle (m204): each XCD owns a contiguous grid chunk
  int bxi = blockIdx.x, byi = blockIdx.y;
  {
    const int GX = gridDim.x;
    const int nwg = GX * gridDim.y;
    const int lid = byi * GX + bxi;
    const int qq = nwg >> 3, rr = nwg & 7;
    const int xcd = lid & 7, pos = lid >> 3;
    const int swz = (xcd < rr ? xcd * (qq + 1) : rr * (qq + 1) + (xcd - rr) * qq) + pos;
    bxi = swz % GX; byi = swz / GX;
  }
  const int bm = byi * 128, bn = bxi * 64;

  const bool pband = (MODE == 1) && (bm >= MTOT);
  if (pband && bn >= TCD) return;   // block-uniform: idle prompt-band columns

  int b2 = 0, jbase = 0;
  if (MODE == 2) { b2 = (byi >= 18); jbase = (byi - b2 * 18) * 128; }

  const int t = threadIdx.x;
  const int w = t >> 6, lane = t & 63;
  const int m16 = lane & 15, quad = lane >> 4;
  const int wm = w >> 1, wn = w & 1;

  const u16* Abh = Agh; const u16* Abl = Agl;
  const u16* Bbh = Bgh; const u16* Bbl = Bgl;
  int rowlim = M - 1;
  int bmA = bm;
  if (pband) { Abh = A2h; Abl = A2l; Bbh = B2h; Bbl = B2l; rowlim = NUM_PROMPT - 1; bmA = 0; }

  // DMA staging geometry: 4 lanes per 64B row, lane's 16B slot = (lane&3)*8 u16.
  // Wave w: A rows 32w..32w+31 (2 calls of 16 rows), B rows 16w..16w+15 (1 call).
  const int acol = (lane & 3) * 8;
  const int ar0 = 32 * w + (lane >> 2);
  const int ar1 = ar0 + 16;
  int ag0, ag1;
  if (MODE == 2) {
    ag0 = b2 * JTOT + min(jbase + ar0, JTOT - 1);   // clamp inside batch: no straddle
    ag1 = b2 * JTOT + min(jbase + ar1, JTOT - 1);
  } else {
    ag0 = min(bmA + ar0, rowlim);
    ag1 = min(bmA + ar1, rowlim);
  }
  const u16* a0h = Abh + (size_t)ag0 * K + acol;
  const u16* a1h = Abh + (size_t)ag1 * K + acol;
  const u16* a0l = Abl + (size_t)ag0 * K + acol;
  const u16* a1l = Abl + (size_t)ag1 * K + acol;
  const int br = 16 * w + (lane >> 2);
  const u16* b0h = Bbh + (size_t)(bn + br) * K + acol;
  const u16* b0l = Bbl + (size_t)(bn + br) * K + acol;

  f32x4 acc[4][2];
#pragma unroll
  for (int i = 0; i < 4; ++i)
#pragma unroll
    for (int j = 0; j < 2; ++j) acc[i][j] = (f32x4){0.f, 0.f, 0.f, 0.f};

  for (int k0 = 0; k0 < K; k0 += 64) {
    // ---- async stage both 32-col sub-tiles ----
#pragma unroll
    for (int s = 0; s < 2; ++s) {
      const int kc = k0 + s * 32;
      gload16(a0h + kc, &Ah_s[s][(2 * w) * 256]);
      gload16(a1h + kc, &Ah_s[s][(2 * w + 1) * 256]);
      gload16(a0l + kc, &Al_s[s][(2 * w) * 256]);
      gload16(a1l + kc, &Al_s[s][(2 * w + 1) * 256]);
      gload16(b0h + kc, &Bh_s[s][w * 256]);
      gload16(b0l + kc, &Bl_s[s][w * 256]);
    }
    __syncthreads();   // drains DMA (compiler emits vmcnt(0) before barrier)

#pragma unroll
    for (int s = 0; s < 2; ++s) {
      bf16x8 ah[4], al[4], bh[2], bl[2];
#pragma unroll
      for (int mt = 0; mt < 4; ++mt) {
        int off = (wm * 64 + mt * 16 + m16) * 16 + quad * 4;
        ah[mt] = *(const bf16x8*)&Ah_s[s][off];
        al[mt] = *(const bf16x8*)&Al_s[s][off];
      }
#pragma unroll
      for (int nt = 0; nt < 2; ++nt) {
        int off = (wn * 32 + nt * 16 + m16) * 16 + quad * 4;
        bh[nt] = *(const bf16x8*)&Bh_s[s][off];
        bl[nt] = *(const bf16x8*)&Bl_s[s][off];
      }
#pragma unroll
      for (int mt = 0; mt < 4; ++mt)
#pragma unroll
        for (int nt = 0; nt < 2; ++nt) {
          acc[mt][nt] = __builtin_amdgcn_mfma_f32_16x16x32_bf16(ah[mt], bh[nt], acc[mt][nt], 0, 0, 0);
          acc[mt][nt] = __builtin_amdgcn_mfma_f32_16x16x32_bf16(ah[mt], bl[nt], acc[mt][nt], 0, 0, 0);
          acc[mt][nt] = __builtin_amdgcn_mfma_f32_16x16x32_bf16(al[mt], bh[nt], acc[mt][nt], 0, 0, 0);
        }
    }
    __syncthreads();   // frag reads done before next DMA overwrites
  }

  if (MODE == 2 && bn >= INNER) {
    // ---- V^T direct write: LDS transpose (XOR-swizzled) + coalesced 16B stores ----
    u16* Th = (u16*)Ah_s;   // 16KB = [64 d][128 j] u16, chunk-XOR layout
    u16* Tl = (u16*)Al_s;
#pragma unroll
    for (int mt = 0; mt < 4; ++mt)
#pragma unroll
      for (int nt = 0; nt < 2; ++nt)
#pragma unroll
        for (int r = 0; r < 4; ++r) {
          int dl = wn * 32 + nt * 16 + m16;
          int jl = wm * 64 + mt * 16 + quad * 4 + r;
          u16 sh, sl;
          split2(acc[mt][nt][r], sh, sl);
          int adr = dl * 128 + ((((jl >> 3) ^ (dl & 15)) << 3) | (jl & 7));
          Th[adr] = sh;
          Tl[adr] = sl;
        }
    __syncthreads();
#pragma unroll
    for (int i = 0; i < 4; ++i) {
      int chunk = t + i * 256;            // 1024 chunks = 64 d x 16 j-chunks
      int dl = chunk >> 4, jc = chunk & 15;
      int jg = jbase + jc * 8;
      int lofs = dl * 128 + ((jc ^ (dl & 15)) << 3);
      uint4 vh4 = *(const uint4*)&Th[lofs];
      uint4 vl4 = *(const uint4*)&Tl[lofs];
      size_t rowo = ((size_t)b2 * INNER + (bn - INNER) + dl) * KVPAD;
      if (jg + 8 <= JTOT) {
        *(uint4*)&O2h[rowo + jg] = vh4;
        *(uint4*)&O2l[rowo + jg] = vl4;
      } else if (jg < JTOT) {
        const u16* eh = (const u16*)&vh4;
        const u16* el = (const u16*)&vl4;
#pragma unroll
        for (int e = 0; e < 8; ++e)
          if (jg + e < JTOT) { O2h[rowo + jg + e] = eh[e]; O2l[rowo + jg + e] = el[e]; }
      }   // jg >= JTOT: keep pre-zeroed pad
    }
    return;
  }

#pragma unroll
  for (int mt = 0; mt < 4; ++mt)
#pragma unroll
    for (int nt = 0; nt < 2; ++nt)
#pragma unroll
      for (int r = 0; r < 4; ++r) {
        int gm = bm + wm * 64 + mt * 16 + quad * 4 + r;
        int gn = bn + wn * 32 + nt * 16 + m16;
        float v = acc[mt][nt][r];
        u16 sh, sl;
        if (MODE == 1) {
          if (pband) {
            int pr = wm * 64 + mt * 16 + quad * 4 + r;
            if (pr < NUM_PROMPT && gn < TCD) {
              split2(v, sh, sl);
              size_t r0 = ((size_t)CTX_LEN + pr) * TCD + gn;          // b = 0
              size_t r1 = ((size_t)JTOT + CTX_LEN + pr) * TCD + gn;   // b = 1
              O1h[r0] = sh; O1l[r0] = sl;
              O1h[r1] = sh; O1l[r1] = sl;
            }
          } else if (gn < TCD) {
            split2(v, sh, sl);
            size_t row = (size_t)(gm >> 11) * JTOT + 141 + (gm & 2047);
            O1h[row * TCD + gn] = sh; O1l[row * TCD + gn] = sl;
          } else {
            split2(v * SCALEL2, sh, sl);
            size_t idx = (size_t)gm * INNER + (gn - TCD);
            O2h[idx] = sh; O2l[idx] = sl;
          }
        } else if (MODE == 2) {
          // K half: [B][KVPAD][INNER]; rows >= JTOT hold clamped dup data, masked in attn
          int jloc = jbase + wm * 64 + mt * 16 + quad * 4 + r;
          split2(v, sh, sl);
          size_t idx = ((size_t)b2 * KVPAD + jloc) * INNER + gn;
          O1h[idx] = sh; O1l[idx] = sl;
        } else if (MODE == 3) {
          Of[(size_t)gm * QD + gn] = v + bias[gn];
        }
      }
}

// ---------------- plane-format MFMA flash attention (R4 structure, exp2-domain softmax) ----------------
// K planes [B][KVPAD][INNER], V^T planes [B][INNER][KVPAD]; staged via global_load_lds
// with pre-swizzled source (XOR chunk swizzle) -> conflict-free ds_read_b128 fragments.
// Q pre-scaled by SCALE*log2(e) -> softmax uses v_exp_f32 directly (2^x).
__global__ __launch_bounds__(256) void attn_mfma2(
    const u16* __restrict__ qhg, const u16* __restrict__ qlg,
    const u16* __restrict__ khg, const u16* __restrict__ klg,
    const u16* __restrict__ vtg_h, const u16* __restrict__ vtg_l,
    u16* __restrict__ aoh, u16* __restrict__ aol) {
  __shared__ __align__(16) u16 Kh_s[64 * 64];
  __shared__ __align__(16) u16 Kl_s[64 * 64];
  __shared__ __align__(16) u16 Vh_s[64 * 64];
  __shared__ __align__(16) u16 Vl_s[64 * 64];
  __shared__ __align__(16) u16 Ph_s[64 * 72];
  __shared__ __align__(16) u16 Pl_s[64 * 72];

  const int t = threadIdx.x;
  const int w = t >> 6, lane = t & 63;
  const int m16 = lane & 15, quad = lane >> 4;

  // XCD swizzle: 512 blocks = 8 * 64; each XCD gets 2 contiguous (b,h) groups
  const int id = blockIdx.x;
  const int swz = (id & 7) * 64 + (id >> 3);
  const int qt = swz & 31, bh = swz >> 5;
  const int b = bh >> 3, h = bh & 7;
  const int qrow0 = qt * 64;

  // Q fragments direct from global planes (A-frag: row=m16, k=ks*32+quad*8)
  bf16x8 qh[2], ql[2];
  {
    size_t qoff = ((size_t)(b * NN + qrow0 + w * 16 + m16)) * INNER + h * 64 + quad * 8;
#pragma unroll
    for (int ks = 0; ks < 2; ++ks) {
      qh[ks] = *(const bf16x8*)(qhg + qoff + ks * 32);
      ql[ks] = *(const bf16x8*)(qlg + qoff + ks * 32);
    }
  }

  // Staging: wave w stages plane w (0:Kh 1:Kl 2:Vh^T 3:Vl^T).
  // Per call: 8 rows x 8 chunks of 16B; dest linear, source chunk = (lane&7)^(lane>>3)
  // so LDS (row, cc) holds logical chunk cc^(row&7).
  const int sr = lane >> 3;
  const int sc = (lane & 7) ^ sr;
  const u16* gp;
  u32* lp;
  size_t cstr, jstr;
  if (w < 2) {
    gp = ((w == 0) ? khg : klg) + ((size_t)b * KVPAD + sr) * INNER + h * 64 + sc * 8;
    lp = (u32*)((w == 0) ? Kh_s : Kl_s);
    cstr = (size_t)8 * INNER;
    jstr = (size_t)64 * INNER;
  } else {
    gp = ((w == 2) ? vtg_h : vtg_l) + ((size_t)b * INNER + h * 64 + sr) * KVPAD + sc * 8;
    lp = (u32*)((w == 2) ? Vh_s : Vl_s);
    cstr = (size_t)8 * KVPAD;
    jstr = 64;
  }

  f32x4 O[4] = {{0.f,0.f,0.f,0.f},{0.f,0.f,0.f,0.f},{0.f,0.f,0.f,0.f},{0.f,0.f,0.f,0.f}};
  float mrow[4], lrow[4];
#pragma unroll
  for (int r = 0; r < 4; ++r) { mrow[r] = -INFINITY; lrow[r] = 0.f; }

  for (int tile = 0; tile < NT_J; ++tile) {
    const int j0 = tile * 64;
    __syncthreads();                       // prior tile fully consumed
#pragma unroll
    for (int c = 0; c < 8; ++c) gload16(gp + (size_t)c * cstr, lp + c * 256);
    gp += jstr;
    __syncthreads();                       // drain DMA (vmcnt(0) before barrier)

    // ---- QK^T ----
    f32x4 S[4];
    __builtin_amdgcn_s_setprio(1);
#pragma unroll
    for (int jt = 0; jt < 4; ++jt) {
      const int row = jt * 16 + m16;
      f32x4 acc = {0.f, 0.f, 0.f, 0.f};
#pragma unroll
      for (int ks = 0; ks < 2; ++ks) {
        const int cc = row * 64 + (((ks * 4 + quad) ^ (row & 7)) << 3);
        bf16x8 kh = *(const bf16x8*)&Kh_s[cc];
        bf16x8 kl = *(const bf16x8*)&Kl_s[cc];
        acc = __builtin_amdgcn_mfma_f32_16x16x32_bf16(qh[ks], kh, acc, 0, 0, 0);
        acc = __builtin_amdgcn_mfma_f32_16x16x32_bf16(qh[ks], kl, acc, 0, 0, 0);
        acc = __builtin_amdgcn_mfma_f32_16x16x32_bf16(ql[ks], kh, acc, 0, 0, 0);
      }
      S[jt] = acc;
    }
    __builtin_amdgcn_s_setprio(0);

    // mask tail columns (also covers K pad-row garbage)
#pragma unroll
    for (int jt = 0; jt < 4; ++jt) {
      int jc = j0 + jt * 16 + m16;
      if (jc >= JTOT)
#pragma unroll
        for (int r = 0; r < 4; ++r) S[jt][r] = -INFINITY;
    }

    // ---- online softmax (exp2 domain): DPP reductions over 16-lane rows ----
    float pj[4][4];
#pragma unroll
    for (int r = 0; r < 4; ++r) {
      float mx = fmaxf(fmaxf(S[0][r], S[1][r]), fmaxf(S[2][r], S[3][r]));
      mx = fmaxf(mx, dpp_f<0xB1>(mx));     // quad_perm [1,0,3,2] = xor1
      mx = fmaxf(mx, dpp_f<0x4E>(mx));     // quad_perm [2,3,0,1] = xor2
      mx = fmaxf(mx, dpp_f<0x124>(mx));    // row_ror:4
      mx = fmaxf(mx, dpp_f<0x128>(mx));    // row_ror:8
      float mnew = fmaxf(mrow[r], mx);
      float alpha = __builtin_amdgcn_exp2f(mrow[r] - mnew);
      mrow[r] = mnew;
      float rs = 0.f;
#pragma unroll
      for (int jt = 0; jt < 4; ++jt) {
        float pv = __builtin_amdgcn_exp2f(S[jt][r] - mnew);
        pj[jt][r] = pv;
        rs += pv;
      }
      rs += dpp_f<0xB1>(rs);
      rs += dpp_f<0x4E>(rs);
      rs += dpp_f<0x124>(rs);
      rs += dpp_f<0x128>(rs);
      lrow[r] = lrow[r] * alpha + rs;
#pragma unroll
      for (int nt = 0; nt < 4; ++nt) O[nt][r] *= alpha;
    }

    // ---- P -> LDS planes (rows are wave-private: no barrier needed) ----
#pragma unroll
    for (int jt = 0; jt < 4; ++jt)
#pragma unroll
      for (int r = 0; r < 4; ++r) {
        u16 sh, sl;
        split2(pj[jt][r], sh, sl);
        int pq = (w * 16 + quad * 4 + r) * 72 + jt * 16 + m16;
        Ph_s[pq] = sh;
        Pl_s[pq] = sl;
      }

    bf16x8 ph[2], pl[2];
#pragma unroll
    for (int ks = 0; ks < 2; ++ks) {
      int po = (w * 16 + m16) * 72 + ks * 32 + quad * 8;
      ph[ks] = *(const bf16x8*)&Ph_s[po];
      pl[ks] = *(const bf16x8*)&Pl_s[po];
    }

    // ---- PV (B-frag = V^T rows d) ----
    __builtin_amdgcn_s_setprio(1);
#pragma unroll
    for (int nt = 0; nt < 4; ++nt) {
      const int row = nt * 16 + m16;
#pragma unroll
      for (int ks = 0; ks < 2; ++ks) {
        const int cc = row * 64 + (((ks * 4 + quad) ^ (row & 7)) << 3);
        bf16x8 vh = *(const bf16x8*)&Vh_s[cc];
        bf16x8 vl = *(const bf16x8*)&Vl_s[cc];
        O[nt] = __builtin_amdgcn_mfma_f32_16x16x32_bf16(ph[ks], vh, O[nt], 0, 0, 0);
        O[nt] = __builtin_amdgcn_mfma_f32_16x16x32_bf16(ph[ks], vl, O[nt], 0, 0, 0);
        O[nt] = __builtin_amdgcn_mfma_f32_16x16x32_bf16(pl[ks], vh, O[nt], 0, 0, 0);
      }
    }
    __builtin_amdgcn_s_setprio(0);
  }

  float inv[4];
#pragma unroll
  for (int r = 0; r < 4; ++r) inv[r] = 1.f / lrow[r];
#pragma unroll
  for (int nt = 0; nt < 4; ++nt)
#pragma unroll
    for (int r = 0; r < 4; ++r) {
      size_t idx = ((size_t)(b * NN + qrow0 + w * 16 + quad * 4 + r)) * INNER +
                   h * 64 + nt * 16 + m16;
      u16 sh, sl;
      split2(O[nt][r] * inv[r], sh, sl);
      aoh[idx] = sh; aol[idx] = sl;
    }
}

// ---------------- launch ----------------
extern "C" void kernel_launch(void* const* d_in, const int* in_sizes, int n_in,
                              void* d_out, int out_size, void* d_ws, size_t ws_size,
                              hipStream_t stream) {
  const float* x        = (const float*)d_in[0];
  const float* context  = (const float*)d_in[1];
  const float* prompt   = (const float*)d_in[2];
  const float* w_prompt = (const float*)d_in[3];
  const float* w_img    = (const float*)d_in[4];
  const float* w_q      = (const float*)d_in[5];
  const float* w_k      = (const float*)d_in[6];
  const float* w_v      = (const float*)d_in[7];
  const float* w_out    = (const float*)d_in[8];
  const float* b_out    = (const float*)d_in[9];
  float* out = (float*)d_out;

  const int M = MTOT;             // 4096
  const int MJ = BB * JTOT;       // 4378

  u16* p = (u16*)d_ws;
  const size_t qN = (size_t)M * INNER;
  const size_t ctxN = (size_t)MJ * TCD;
  const size_t kN = (size_t)BB * KVPAD * INNER;  // K / V^T plane size
  u16* cth = p; p += ctxN; u16* ctl = p; p += ctxN;
  u16* aoh = p; p += qN;   u16* aol = p; p += qN;
  u16* xh  = p; p += (size_t)M * QD;   u16* xl  = p; p += (size_t)M * QD;
  u16* prh = p; p += (size_t)NUM_PROMPT * PD;
  u16* prl = p; p += (size_t)NUM_PROMPT * PD;
  u16* WtPh = p; p += (size_t)TCD * PD;            u16* WtPl = p; p += (size_t)TCD * PD;
  u16* WtAh = p; p += (size_t)(TCD + INNER) * QD;  u16* WtAl = p; p += (size_t)(TCD + INNER) * QD;
  u16* WtBh = p; p += (size_t)(2 * INNER) * TCD;   u16* WtBl = p; p += (size_t)(2 * INNER) * TCD;
  u16* WtOh = p; p += (size_t)QD * INNER;          u16* WtOl = p; p += (size_t)QD * INNER;
  u16* qhp = p; p += qN;  u16* qlp = p; p += qN;   // q planes (pre-scaled, exp2 domain)
  u16* khp = p; p += kN;  u16* klp = p; p += kN;   // K planes [B][KVPAD][INNER]
  u16* vthp = p; p += kN; u16* vtlp = p; p += kN;  // V^T planes [B][INNER][KVPAD]

  // ---- pack inputs + text ctx rows + V^T pad zero-fill (one launch) ----
  const int n4x = M * QD / 4, n4p = NUM_PROMPT * PD / 4;
  const int n4c = BB * CTX_LEN * TCD / 4;
  const int n4z = 2 * BB * INNER * 8;   // 16384 zero chunks of 16B
  pack_planes4<<<(n4x + n4p + n4c + n4z + 255) / 256, 256, 0, stream>>>(
      x, xh, xl, n4x, prompt, prh, prl, n4p, context, cth, ctl, n4c,
      vthp, vtlp, n4z);

  // ---- transpose+pack all 6 weights (one launch) ----
  TP6 tp;
  const float* srcs[6] = {w_prompt, w_img, w_q, w_k, w_v, w_out};
  u16* dhs[6] = {WtPh, WtAh, WtAh + (size_t)TCD * QD, WtBh, WtBh + (size_t)INNER * TCD, WtOh};
  u16* dls[6] = {WtPl, WtAl, WtAl + (size_t)TCD * QD, WtBl, WtBl + (size_t)INNER * TCD, WtOl};
  int Ks[6] = {PD, QD, QD, TCD, TCD, INNER};
  int Ns[6] = {TCD, TCD, INNER, INNER, INNER, QD};
  int acc_blk = 0;
  for (int i = 0; i < 6; ++i) {
    tp.src[i] = srcs[i]; tp.dh[i] = dhs[i]; tp.dl[i] = dls[i];
    tp.K[i] = Ks[i]; tp.N[i] = Ns[i];
    tp.blk0[i] = acc_blk;
    acc_blk += (Ns[i] / 32) * (Ks[i] / 32);
  }
  tp.blk0[6] = acc_blk;
  transpose_pack6<<<acc_blk, 256, 0, stream>>>(tp);

  // ---- x @ [w_img | w_q] -> ctx planes (remap) + q planes (x SCALEL2);
  //      extra band: prompt @ w_prompt -> ctx rows 77..140 (both b) ----
  gemm_mfma<1><<<dim3((TCD + INNER) / 64, M / 128 + 1), 256, 0, stream>>>(
      xh, xl, WtAh, WtAl, cth, ctl, qhp, qlp, nullptr, nullptr,
      M, QD, TCD + INNER, prh, prl, WtPh, WtPl);
  // ---- ctx @ [w_k | w_v] -> K planes + V^T planes (direct transpose write) ----
  gemm_mfma<2><<<dim3((2 * INNER) / 64, 2 * (KVPAD / 128)), 256, 0, stream>>>(
      cth, ctl, WtBh, WtBl, khp, klp, vthp, vtlp, nullptr, nullptr,
      MJ, TCD, 2 * INNER, nullptr, nullptr, nullptr, nullptr);
  // ---- attention ----
  attn_mfma2<<<BB * HEADS * (NN / 64), 256, 0, stream>>>(
      qhp, qlp, khp, klp, vthp, vtlp, aoh, aol);
  // ---- out = ao @ w_out + b_out ----
  gemm_mfma<3><<<dim3(QD / 64, M / 128), 256, 0, stream>>>(
      aoh, aol, WtOh, WtOl, nullptr, nullptr, nullptr, nullptr, out, b_out,
      M, INNER, QD, nullptr, nullptr, nullptr, nullptr);
}

// Round 11
// 271.428 us; speedup vs baseline: 1.2209x; 1.0527x over previous
//
#include <hip/hip_runtime.h>
#include <hip/hip_bf16.h>
#include <math.h>

#define BB 2
#define NN 2048
#define QD 1024
#define CTX_LEN 77
#define TCD 768
#define NUM_PROMPT 64
#define PD 1024
#define HEADS 8
#define DIM_HEAD 64
#define INNER 512
#define JTOT (CTX_LEN + NUM_PROMPT + NN)   // 2189
#define SCALE 0.125f
#define SCALEL2 (0.125f * 1.44269504088896f)   // fold log2(e): softmax in exp2 domain
#define MTOT (BB * NN)                     // 4096
#define JPAD 2240                          // 35 * 64, attn j extent
#define KVPAD 2304                         // 18 * 128, K/V^T padded j extent (grid-friendly)
#define NT_J (JPAD / 64)                   // 35 j-tiles

typedef unsigned short u16;
typedef unsigned int u32;
typedef __attribute__((ext_vector_type(8))) short bf16x8;
typedef __attribute__((ext_vector_type(4))) float f32x4;

__device__ __forceinline__ u32 pack_split(float f) {   // interleaved: low16=hi, high16=lo
  u32 u = __builtin_bit_cast(u32, f);
  u32 hi = u & 0xffff0000u;
  float lo = f - __builtin_bit_cast(float, hi);
  u32 ul = __builtin_bit_cast(u32, lo);
  return __builtin_amdgcn_perm(ul, u, 0x07060302u);
}
__device__ __forceinline__ void split2(float f, u16& h, u16& l) {
  u32 u = __builtin_bit_cast(u32, f);
  u32 hm = u & 0xffff0000u;
  float lo = f - __builtin_bit_cast(float, hm);
  h = (u16)(u >> 16);
  l = (u16)(__builtin_bit_cast(u32, lo) >> 16);
}
__device__ __forceinline__ u16 rnd_bf16(float f) {   // RNE fp32 -> bf16
  u32 u = __builtin_bit_cast(u32, f);
  return (u16)((u + 0x7FFF + ((u >> 16) & 1)) >> 16);
}
__device__ __forceinline__ void pack4(const float4& f, ushort4& hh, ushort4& ll) {
  split2(f.x, hh.x, ll.x); split2(f.y, hh.y, ll.y);
  split2(f.z, hh.z, ll.z); split2(f.w, hh.w, ll.w);
}

// DPP lane move within 16-lane rows (ctrl must be ICE -> template)
template <int CTRL>
__device__ __forceinline__ float dpp_f(float x) {
  int i = __builtin_bit_cast(int, x);
  i = __builtin_amdgcn_update_dpp(0, i, CTRL, 0xF, 0xF, false);
  return __builtin_bit_cast(float, i);
}

// async global->LDS, 16B per lane; lds dest = base + lane*16
__device__ __forceinline__ void gload16(const u16* g, u32* l) {
  __builtin_amdgcn_global_load_lds(
      (const __attribute__((address_space(1))) u32*)(const void*)g,
      (__attribute__((address_space(3))) u32*)(void*)l, 16, 0, 0);
}

// ---------------- merged f32 -> hi/lo plane pack: x, prompt, text-ctx rows, V^T pad-zero ----------------
__global__ __launch_bounds__(256) void pack_planes4(
    const float* __restrict__ s0, u16* __restrict__ d0h, u16* __restrict__ d0l, int n0,
    const float* __restrict__ s1, u16* __restrict__ d1h, u16* __restrict__ d1l, int n1,
    const float* __restrict__ ctx, u16* __restrict__ ch, u16* __restrict__ cl, int n2,
    u16* __restrict__ zh, int n3) {
  int i = blockIdx.x * 256 + threadIdx.x;
  ushort4 hh, ll;
  if (i < n0) {
    pack4(((const float4*)s0)[i], hh, ll);
    ((ushort4*)d0h)[i] = hh; ((ushort4*)d0l)[i] = ll;
    return;
  }
  i -= n0;
  if (i < n1) {
    pack4(((const float4*)s1)[i], hh, ll);
    ((ushort4*)d1h)[i] = hh; ((ushort4*)d1l)[i] = ll;
    return;
  }
  i -= n1;
  if (i < n2) {
    // text context rows -> ctx planes rows [b*JTOT + r], r < CTX_LEN
    pack4(((const float4*)ctx)[i], hh, ll);
    int c4 = i % (TCD / 4);
    int rb = i / (TCD / 4);
    int r = rb % CTX_LEN, b = rb / CTX_LEN;
    size_t o = ((size_t)b * JTOT + r) * (TCD / 4) + c4;   // ushort4 units
    ((ushort4*)ch)[o] = hh; ((ushort4*)cl)[o] = ll;
    return;
  }
  i -= n2;
  if (i >= n3) return;
  // zero-fill V^T (hi plane only) j in [2176, 2240): 8 chunks of 8 u16 per (b,d) row
  int c = i & 7;
  int row = i >> 3;            // [b(2)][d(512)]
  int d = row & 511;
  int b = row >> 9;
  uint4 z = {0u, 0u, 0u, 0u};
  *(uint4*)&zh[((size_t)b * INNER + d) * KVPAD + 2176 + c * 8] = z;
}

// ---------------- merged weight transpose+pack: 6 sources, one launch ----------------
struct TP6 {
  const float* src[6];
  u16* dh[6];
  u16* dl[6];
  int K[6], N[6];
  int blk0[7];   // cumulative block offsets, blk0[6] = total blocks
};

__global__ __launch_bounds__(256) void transpose_pack6(TP6 P) {
  __shared__ u32 T[32][33];
  const int bid = blockIdx.x;
  int s = 0;
#pragma unroll
  for (int k = 1; k < 6; ++k) s += (bid >= P.blk0[k]);
  const int rel = bid - P.blk0[s];
  const int N = P.N[s], K = P.K[s];
  const int nbx = N >> 5;
  const int bx = rel % nbx, by = rel / nbx;
  const float* __restrict__ src = P.src[s];
  u16* __restrict__ dh = P.dh[s];
  u16* __restrict__ dl = P.dl[s];
  const int t = threadIdx.x;
  const int k0 = by * 32, n0 = bx * 32;
#pragma unroll
  for (int i = 0; i < 4; ++i) {
    int e = t + i * 256;
    int kr = e >> 5, nc = e & 31;
    T[kr][nc] = pack_split(src[(size_t)(k0 + kr) * N + n0 + nc]);
  }
  __syncthreads();
#pragma unroll
  for (int i = 0; i < 4; ++i) {
    int e = t + i * 256;
    int nr = e >> 5, kc = e & 31;
    u32 w = T[kc][nr];
    size_t idx = (size_t)(n0 + nr) * K + k0 + kc;
    dh[idx] = (u16)(w & 0xffff);
    dl[idx] = (u16)(w >> 16);
  }
}

// ---------------- split-bf16 MFMA GEMM, 128x64 tiles, BK=64, bijective XCD swizzle ----------------
// MODE 1: gn<TCD -> ctx planes (row remap); else q planes (x SCALEL2) -> O2h/O2l.
//         Extra grid band bm>=MTOT: prompt@w_prompt -> ctx rows 77..140 (both b).
// MODE 2: grid y = 36 (18 per batch, no batch straddle). gn<INNER -> K planes
//         [B][KVPAD][INNER]; else V^T hi plane [B][INNER][KVPAD] via LDS transpose (RNE).
// MODE 3: f32 out + bias
template <int MODE>
__global__ __launch_bounds__(256) void gemm_mfma(
    const u16* __restrict__ Agh, const u16* __restrict__ Agl,
    const u16* __restrict__ Bgh, const u16* __restrict__ Bgl,
    u16* __restrict__ O1h, u16* __restrict__ O1l,
    u16* __restrict__ O2h, u16* __restrict__ O2l,
    float* __restrict__ Of, const float* __restrict__ bias,
    int M, int K, int Ntot,
    const u16* __restrict__ A2h, const u16* __restrict__ A2l,
    const u16* __restrict__ B2h, const u16* __restrict__ B2l) {
  __shared__ __align__(16) u32 Ah_s[2][128 * 16];
  __shared__ __align__(16) u32 Al_s[2][128 * 16];
  __shared__ __align__(16) u32 Bh_s[2][64 * 16];
  __shared__ __align__(16) u32 Bl_s[2][64 * 16];

  // bijective chunked XCD swizzle (m204): each XCD owns a contiguous grid chunk
  int bxi = blockIdx.x, byi = blockIdx.y;
  {
    const int GX = gridDim.x;
    const int nwg = GX * gridDim.y;
    const int lid = byi * GX + bxi;
    const int qq = nwg >> 3, rr = nwg & 7;
    const int xcd = lid & 7, pos = lid >> 3;
    const int swz = (xcd < rr ? xcd * (qq + 1) : rr * (qq + 1) + (xcd - rr) * qq) + pos;
    bxi = swz % GX; byi = swz / GX;
  }
  const int bm = byi * 128, bn = bxi * 64;

  const bool pband = (MODE == 1) && (bm >= MTOT);
  if (pband && bn >= TCD) return;   // block-uniform: idle prompt-band columns

  int b2 = 0, jbase = 0;
  if (MODE == 2) { b2 = (byi >= 18); jbase = (byi - b2 * 18) * 128; }

  const int t = threadIdx.x;
  const int w = t >> 6, lane = t & 63;
  const int m16 = lane & 15, quad = lane >> 4;
  const int wm = w >> 1, wn = w & 1;

  const u16* Abh = Agh; const u16* Abl = Agl;
  const u16* Bbh = Bgh; const u16* Bbl = Bgl;
  int rowlim = M - 1;
  int bmA = bm;
  if (pband) { Abh = A2h; Abl = A2l; Bbh = B2h; Bbl = B2l; rowlim = NUM_PROMPT - 1; bmA = 0; }

  // DMA staging geometry: 4 lanes per 64B row, lane's 16B slot = (lane&3)*8 u16.
  // Wave w: A rows 32w..32w+31 (2 calls of 16 rows), B rows 16w..16w+15 (1 call).
  const int acol = (lane & 3) * 8;
  const int ar0 = 32 * w + (lane >> 2);
  const int ar1 = ar0 + 16;
  int ag0, ag1;
  if (MODE == 2) {
    ag0 = b2 * JTOT + min(jbase + ar0, JTOT - 1);   // clamp inside batch: no straddle
    ag1 = b2 * JTOT + min(jbase + ar1, JTOT - 1);
  } else {
    ag0 = min(bmA + ar0, rowlim);
    ag1 = min(bmA + ar1, rowlim);
  }
  const u16* a0h = Abh + (size_t)ag0 * K + acol;
  const u16* a1h = Abh + (size_t)ag1 * K + acol;
  const u16* a0l = Abl + (size_t)ag0 * K + acol;
  const u16* a1l = Abl + (size_t)ag1 * K + acol;
  const int br = 16 * w + (lane >> 2);
  const u16* b0h = Bbh + (size_t)(bn + br) * K + acol;
  const u16* b0l = Bbl + (size_t)(bn + br) * K + acol;

  f32x4 acc[4][2];
#pragma unroll
  for (int i = 0; i < 4; ++i)
#pragma unroll
    for (int j = 0; j < 2; ++j) acc[i][j] = (f32x4){0.f, 0.f, 0.f, 0.f};

  for (int k0 = 0; k0 < K; k0 += 64) {
    // ---- async stage both 32-col sub-tiles ----
#pragma unroll
    for (int s = 0; s < 2; ++s) {
      const int kc = k0 + s * 32;
      gload16(a0h + kc, &Ah_s[s][(2 * w) * 256]);
      gload16(a1h + kc, &Ah_s[s][(2 * w + 1) * 256]);
      gload16(a0l + kc, &Al_s[s][(2 * w) * 256]);
      gload16(a1l + kc, &Al_s[s][(2 * w + 1) * 256]);
      gload16(b0h + kc, &Bh_s[s][w * 256]);
      gload16(b0l + kc, &Bl_s[s][w * 256]);
    }
    __syncthreads();   // drains DMA (compiler emits vmcnt(0) before barrier)

#pragma unroll
    for (int s = 0; s < 2; ++s) {
      bf16x8 ah[4], al[4], bh[2], bl[2];
#pragma unroll
      for (int mt = 0; mt < 4; ++mt) {
        int off = (wm * 64 + mt * 16 + m16) * 16 + quad * 4;
        ah[mt] = *(const bf16x8*)&Ah_s[s][off];
        al[mt] = *(const bf16x8*)&Al_s[s][off];
      }
#pragma unroll
      for (int nt = 0; nt < 2; ++nt) {
        int off = (wn * 32 + nt * 16 + m16) * 16 + quad * 4;
        bh[nt] = *(const bf16x8*)&Bh_s[s][off];
        bl[nt] = *(const bf16x8*)&Bl_s[s][off];
      }
#pragma unroll
      for (int mt = 0; mt < 4; ++mt)
#pragma unroll
        for (int nt = 0; nt < 2; ++nt) {
          acc[mt][nt] = __builtin_amdgcn_mfma_f32_16x16x32_bf16(ah[mt], bh[nt], acc[mt][nt], 0, 0, 0);
          acc[mt][nt] = __builtin_amdgcn_mfma_f32_16x16x32_bf16(ah[mt], bl[nt], acc[mt][nt], 0, 0, 0);
          acc[mt][nt] = __builtin_amdgcn_mfma_f32_16x16x32_bf16(al[mt], bh[nt], acc[mt][nt], 0, 0, 0);
        }
    }
    __syncthreads();   // frag reads done before next DMA overwrites
  }

  if (MODE == 2 && bn >= INNER) {
    // ---- V^T direct write, hi plane only (RNE): LDS transpose + coalesced 16B stores ----
    u16* Th = (u16*)Ah_s;   // 16KB region: [64 d][128 j] u16, chunk-XOR layout
#pragma unroll
    for (int mt = 0; mt < 4; ++mt)
#pragma unroll
      for (int nt = 0; nt < 2; ++nt)
#pragma unroll
        for (int r = 0; r < 4; ++r) {
          int dl = wn * 32 + nt * 16 + m16;
          int jl = wm * 64 + mt * 16 + quad * 4 + r;
          int adr = dl * 128 + ((((jl >> 3) ^ (dl & 15)) << 3) | (jl & 7));
          Th[adr] = rnd_bf16(acc[mt][nt][r]);
        }
    __syncthreads();
#pragma unroll
    for (int i = 0; i < 4; ++i) {
      int chunk = t + i * 256;            // 1024 chunks = 64 d x 16 j-chunks
      int dl = chunk >> 4, jc = chunk & 15;
      int jg = jbase + jc * 8;
      int lofs = dl * 128 + ((jc ^ (dl & 15)) << 3);
      uint4 vh4 = *(const uint4*)&Th[lofs];
      size_t rowo = ((size_t)b2 * INNER + (bn - INNER) + dl) * KVPAD;
      if (jg + 8 <= JTOT) {
        *(uint4*)&O2h[rowo + jg] = vh4;
      } else if (jg < JTOT) {
        const u16* eh = (const u16*)&vh4;
#pragma unroll
        for (int e = 0; e < 8; ++e)
          if (jg + e < JTOT) O2h[rowo + jg + e] = eh[e];
      }   // jg >= JTOT: keep pre-zeroed pad
    }
    return;
  }

#pragma unroll
  for (int mt = 0; mt < 4; ++mt)
#pragma unroll
    for (int nt = 0; nt < 2; ++nt)
#pragma unroll
      for (int r = 0; r < 4; ++r) {
        int gm = bm + wm * 64 + mt * 16 + quad * 4 + r;
        int gn = bn + wn * 32 + nt * 16 + m16;
        float v = acc[mt][nt][r];
        u16 sh, sl;
        if (MODE == 1) {
          if (pband) {
            int pr = wm * 64 + mt * 16 + quad * 4 + r;
            if (pr < NUM_PROMPT && gn < TCD) {
              split2(v, sh, sl);
              size_t r0 = ((size_t)CTX_LEN + pr) * TCD + gn;          // b = 0
              size_t r1 = ((size_t)JTOT + CTX_LEN + pr) * TCD + gn;   // b = 1
              O1h[r0] = sh; O1l[r0] = sl;
              O1h[r1] = sh; O1l[r1] = sl;
            }
          } else if (gn < TCD) {
            split2(v, sh, sl);
            size_t row = (size_t)(gm >> 11) * JTOT + 141 + (gm & 2047);
            O1h[row * TCD + gn] = sh; O1l[row * TCD + gn] = sl;
          } else {
            split2(v * SCALEL2, sh, sl);
            size_t idx = (size_t)gm * INNER + (gn - TCD);
            O2h[idx] = sh; O2l[idx] = sl;
          }
        } else if (MODE == 2) {
          // K half: [B][KVPAD][INNER]; rows >= JTOT hold clamped dup data, masked in attn
          int jloc = jbase + wm * 64 + mt * 16 + quad * 4 + r;
          split2(v, sh, sl);
          size_t idx = ((size_t)b2 * KVPAD + jloc) * INNER + gn;
          O1h[idx] = sh; O1l[idx] = sl;
        } else if (MODE == 3) {
          Of[(size_t)gm * QD + gn] = v + bias[gn];
        }
      }
}

// ---------------- plane-format MFMA flash attention ----------------
// K hi/lo planes [B][KVPAD][INNER], V^T hi plane [B][INNER][KVPAD]; staged via
// global_load_lds with pre-swizzled source (XOR chunk swizzle) -> conflict-free
// ds_read_b128 fragments. QK^T keeps full 3-term split; P and V single rounded
// bf16 (flat-softmax precision budget: error ~ ||p||_2 * 2^-9 ~ 1e-4).
__global__ __launch_bounds__(256) void attn_mfma2(
    const u16* __restrict__ qhg, const u16* __restrict__ qlg,
    const u16* __restrict__ khg, const u16* __restrict__ klg,
    const u16* __restrict__ vtg_h,
    u16* __restrict__ aoh, u16* __restrict__ aol) {
  __shared__ __align__(16) u16 Kh_s[64 * 64];
  __shared__ __align__(16) u16 Kl_s[64 * 64];
  __shared__ __align__(16) u16 Vh_s[64 * 64];
  __shared__ __align__(16) u16 Ph_s[64 * 72];

  const int t = threadIdx.x;
  const int w = t >> 6, lane = t & 63;
  const int m16 = lane & 15, quad = lane >> 4;

  // XCD swizzle: 512 blocks = 8 * 64; each XCD gets 2 contiguous (b,h) groups
  const int id = blockIdx.x;
  const int swz = (id & 7) * 64 + (id >> 3);
  const int qt = swz & 31, bh = swz >> 5;
  const int b = bh >> 3, h = bh & 7;
  const int qrow0 = qt * 64;

  // Q fragments direct from global planes (A-frag: row=m16, k=ks*32+quad*8)
  bf16x8 qh[2], ql[2];
  {
    size_t qoff = ((size_t)(b * NN + qrow0 + w * 16 + m16)) * INNER + h * 64 + quad * 8;
#pragma unroll
    for (int ks = 0; ks < 2; ++ks) {
      qh[ks] = *(const bf16x8*)(qhg + qoff + ks * 32);
      ql[ks] = *(const bf16x8*)(qlg + qoff + ks * 32);
    }
  }

  // Staging: waves 0,1 -> Kh,Kl (8 chunks each); waves 2,3 -> Vh chunks 0-3 / 4-7.
  // Per chunk: 8 rows x 8 slots of 16B; dest linear, source slot = (lane&7)^(lane>>3)
  // so LDS (row, cc) holds logical chunk cc^(row&7)  (same layout as before).
  const int sr = lane >> 3;
  const int sc = (lane & 7) ^ sr;
  const u16* gp;
  u32* lp;
  size_t cstr, jstr;
  if (w < 2) {
    gp = ((w == 0) ? khg : klg) + ((size_t)b * KVPAD + sr) * INNER + h * 64 + sc * 8;
    lp = (u32*)((w == 0) ? Kh_s : Kl_s);
    cstr = (size_t)8 * INNER;
    jstr = (size_t)64 * INNER;
  } else {
    const int c0 = (w - 2) * 4;          // wave 2: chunks 0-3, wave 3: chunks 4-7
    gp = vtg_h + ((size_t)b * INNER + h * 64 + c0 * 8 + sr) * KVPAD + sc * 8;
    lp = (u32*)Vh_s + c0 * 256;
    cstr = (size_t)8 * KVPAD;
    jstr = 64;
  }

  f32x4 O[4] = {{0.f,0.f,0.f,0.f},{0.f,0.f,0.f,0.f},{0.f,0.f,0.f,0.f},{0.f,0.f,0.f,0.f}};
  float mrow[4], lrow[4];
#pragma unroll
  for (int r = 0; r < 4; ++r) { mrow[r] = -INFINITY; lrow[r] = 0.f; }

  for (int tile = 0; tile < NT_J; ++tile) {
    const int j0 = tile * 64;
    __syncthreads();                       // prior tile fully consumed
    if (w < 2) {
#pragma unroll
      for (int c = 0; c < 8; ++c) gload16(gp + (size_t)c * cstr, lp + c * 256);
    } else {
#pragma unroll
      for (int c = 0; c < 4; ++c) gload16(gp + (size_t)c * cstr, lp + c * 256);
    }
    gp += jstr;
    __syncthreads();                       // drain DMA (vmcnt(0) before barrier)

    // ---- QK^T (full 3-term split) ----
    f32x4 S[4];
    __builtin_amdgcn_s_setprio(1);
#pragma unroll
    for (int jt = 0; jt < 4; ++jt) {
      const int row = jt * 16 + m16;
      f32x4 acc = {0.f, 0.f, 0.f, 0.f};
#pragma unroll
      for (int ks = 0; ks < 2; ++ks) {
        const int cc = row * 64 + (((ks * 4 + quad) ^ (row & 7)) << 3);
        bf16x8 kh = *(const bf16x8*)&Kh_s[cc];
        bf16x8 kl = *(const bf16x8*)&Kl_s[cc];
        acc = __builtin_amdgcn_mfma_f32_16x16x32_bf16(qh[ks], kh, acc, 0, 0, 0);
        acc = __builtin_amdgcn_mfma_f32_16x16x32_bf16(qh[ks], kl, acc, 0, 0, 0);
        acc = __builtin_amdgcn_mfma_f32_16x16x32_bf16(ql[ks], kh, acc, 0, 0, 0);
      }
      S[jt] = acc;
    }
    __builtin_amdgcn_s_setprio(0);

    // mask tail columns (also covers K pad-row garbage)
#pragma unroll
    for (int jt = 0; jt < 4; ++jt) {
      int jc = j0 + jt * 16 + m16;
      if (jc >= JTOT)
#pragma unroll
        for (int r = 0; r < 4; ++r) S[jt][r] = -INFINITY;
    }

    // ---- online softmax (exp2 domain): DPP reductions over 16-lane rows ----
    float pj[4][4];
#pragma unroll
    for (int r = 0; r < 4; ++r) {
      float mx = fmaxf(fmaxf(S[0][r], S[1][r]), fmaxf(S[2][r], S[3][r]));
      mx = fmaxf(mx, dpp_f<0xB1>(mx));     // quad_perm [1,0,3,2] = xor1
      mx = fmaxf(mx, dpp_f<0x4E>(mx));     // quad_perm [2,3,0,1] = xor2
      mx = fmaxf(mx, dpp_f<0x124>(mx));    // row_ror:4
      mx = fmaxf(mx, dpp_f<0x128>(mx));    // row_ror:8
      float mnew = fmaxf(mrow[r], mx);
      float alpha = __builtin_amdgcn_exp2f(mrow[r] - mnew);
      mrow[r] = mnew;
      float rs = 0.f;
#pragma unroll
      for (int jt = 0; jt < 4; ++jt) {
        float pv = __builtin_amdgcn_exp2f(S[jt][r] - mnew);
        pj[jt][r] = pv;
        rs += pv;
      }
      rs += dpp_f<0xB1>(rs);
      rs += dpp_f<0x4E>(rs);
      rs += dpp_f<0x124>(rs);
      rs += dpp_f<0x128>(rs);
      lrow[r] = lrow[r] * alpha + rs;
#pragma unroll
      for (int nt = 0; nt < 4; ++nt) O[nt][r] *= alpha;
    }

    // ---- P -> LDS (single RNE bf16 plane; rows are wave-private: no barrier) ----
#pragma unroll
    for (int jt = 0; jt < 4; ++jt)
#pragma unroll
      for (int r = 0; r < 4; ++r) {
        int pq = (w * 16 + quad * 4 + r) * 72 + jt * 16 + m16;
        Ph_s[pq] = rnd_bf16(pj[jt][r]);
      }

    bf16x8 ph[2];
#pragma unroll
    for (int ks = 0; ks < 2; ++ks) {
      int po = (w * 16 + m16) * 72 + ks * 32 + quad * 8;
      ph[ks] = *(const bf16x8*)&Ph_s[po];
    }

    // ---- PV (single-plane P x single-plane V: 8 MFMA) ----
    __builtin_amdgcn_s_setprio(1);
#pragma unroll
    for (int nt = 0; nt < 4; ++nt) {
      const int row = nt * 16 + m16;
#pragma unroll
      for (int ks = 0; ks < 2; ++ks) {
        const int cc = row * 64 + (((ks * 4 + quad) ^ (row & 7)) << 3);
        bf16x8 vh = *(const bf16x8*)&Vh_s[cc];
        O[nt] = __builtin_amdgcn_mfma_f32_16x16x32_bf16(ph[ks], vh, O[nt], 0, 0, 0);
      }
    }
    __builtin_amdgcn_s_setprio(0);
  }

  float inv[4];
#pragma unroll
  for (int r = 0; r < 4; ++r) inv[r] = 1.f / lrow[r];
#pragma unroll
  for (int nt = 0; nt < 4; ++nt)
#pragma unroll
    for (int r = 0; r < 4; ++r) {
      size_t idx = ((size_t)(b * NN + qrow0 + w * 16 + quad * 4 + r)) * INNER +
                   h * 64 + nt * 16 + m16;
      u16 sh, sl;
      split2(O[nt][r] * inv[r], sh, sl);
      aoh[idx] = sh; aol[idx] = sl;
    }
}

// ---------------- launch ----------------
extern "C" void kernel_launch(void* const* d_in, const int* in_sizes, int n_in,
                              void* d_out, int out_size, void* d_ws, size_t ws_size,
                              hipStream_t stream) {
  const float* x        = (const float*)d_in[0];
  const float* context  = (const float*)d_in[1];
  const float* prompt   = (const float*)d_in[2];
  const float* w_prompt = (const float*)d_in[3];
  const float* w_img    = (const float*)d_in[4];
  const float* w_q      = (const float*)d_in[5];
  const float* w_k      = (const float*)d_in[6];
  const float* w_v      = (const float*)d_in[7];
  const float* w_out    = (const float*)d_in[8];
  const float* b_out    = (const float*)d_in[9];
  float* out = (float*)d_out;

  const int M = MTOT;             // 4096
  const int MJ = BB * JTOT;       // 4378

  u16* p = (u16*)d_ws;
  const size_t qN = (size_t)M * INNER;
  const size_t ctxN = (size_t)MJ * TCD;
  const size_t kN = (size_t)BB * KVPAD * INNER;  // K / V^T plane size
  u16* cth = p; p += ctxN; u16* ctl = p; p += ctxN;
  u16* aoh = p; p += qN;   u16* aol = p; p += qN;
  u16* xh  = p; p += (size_t)M * QD;   u16* xl  = p; p += (size_t)M * QD;
  u16* prh = p; p += (size_t)NUM_PROMPT * PD;
  u16* prl = p; p += (size_t)NUM_PROMPT * PD;
  u16* WtPh = p; p += (size_t)TCD * PD;            u16* WtPl = p; p += (size_t)TCD * PD;
  u16* WtAh = p; p += (size_t)(TCD + INNER) * QD;  u16* WtAl = p; p += (size_t)(TCD + INNER) * QD;
  u16* WtBh = p; p += (size_t)(2 * INNER) * TCD;   u16* WtBl = p; p += (size_t)(2 * INNER) * TCD;
  u16* WtOh = p; p += (size_t)QD * INNER;          u16* WtOl = p; p += (size_t)QD * INNER;
  u16* qhp = p; p += qN;  u16* qlp = p; p += qN;   // q planes (pre-scaled, exp2 domain)
  u16* khp = p; p += kN;  u16* klp = p; p += kN;   // K planes [B][KVPAD][INNER]
  u16* vthp = p; p += kN;                          // V^T hi plane [B][INNER][KVPAD]

  // ---- pack inputs + text ctx rows + V^T pad zero-fill (one launch) ----
  const int n4x = M * QD / 4, n4p = NUM_PROMPT * PD / 4;
  const int n4c = BB * CTX_LEN * TCD / 4;
  const int n4z = BB * INNER * 8;   // 8192 zero chunks of 16B (hi plane only)
  pack_planes4<<<(n4x + n4p + n4c + n4z + 255) / 256, 256, 0, stream>>>(
      x, xh, xl, n4x, prompt, prh, prl, n4p, context, cth, ctl, n4c,
      vthp, n4z);

  // ---- transpose+pack all 6 weights (one launch) ----
  TP6 tp;
  const float* srcs[6] = {w_prompt, w_img, w_q, w_k, w_v, w_out};
  u16* dhs[6] = {WtPh, WtAh, WtAh + (size_t)TCD * QD, WtBh, WtBh + (size_t)INNER * TCD, WtOh};
  u16* dls[6] = {WtPl, WtAl, WtAl + (size_t)TCD * QD, WtBl, WtBl + (size_t)INNER * TCD, WtOl};
  int Ks[6] = {PD, QD, QD, TCD, TCD, INNER};
  int Ns[6] = {TCD, TCD, INNER, INNER, INNER, QD};
  int acc_blk = 0;
  for (int i = 0; i < 6; ++i) {
    tp.src[i] = srcs[i]; tp.dh[i] = dhs[i]; tp.dl[i] = dls[i];
    tp.K[i] = Ks[i]; tp.N[i] = Ns[i];
    tp.blk0[i] = acc_blk;
    acc_blk += (Ns[i] / 32) * (Ks[i] / 32);
  }
  tp.blk0[6] = acc_blk;
  transpose_pack6<<<acc_blk, 256, 0, stream>>>(tp);

  // ---- x @ [w_img | w_q] -> ctx planes (remap) + q planes (x SCALEL2);
  //      extra band: prompt @ w_prompt -> ctx rows 77..140 (both b) ----
  gemm_mfma<1><<<dim3((TCD + INNER) / 64, M / 128 + 1), 256, 0, stream>>>(
      xh, xl, WtAh, WtAl, cth, ctl, qhp, qlp, nullptr, nullptr,
      M, QD, TCD + INNER, prh, prl, WtPh, WtPl);
  // ---- ctx @ [w_k | w_v] -> K planes + V^T hi plane (direct transpose write) ----
  gemm_mfma<2><<<dim3((2 * INNER) / 64, 2 * (KVPAD / 128)), 256, 0, stream>>>(
      cth, ctl, WtBh, WtBl, khp, klp, vthp, nullptr, nullptr, nullptr,
      MJ, TCD, 2 * INNER, nullptr, nullptr, nullptr, nullptr);
  // ---- attention ----
  attn_mfma2<<<BB * HEADS * (NN / 64), 256, 0, stream>>>(
      qhp, qlp, khp, klp, vthp, aoh, aol);
  // ---- out = ao @ w_out + b_out ----
  gemm_mfma<3><<<dim3(QD / 64, M / 128), 256, 0, stream>>>(
      aoh, aol, WtOh, WtOl, nullptr, nullptr, nullptr, nullptr, out, b_out,
      M, INNER, QD, nullptr, nullptr, nullptr, nullptr);
}

// Round 12
// 239.419 us; speedup vs baseline: 1.3841x; 1.1337x over previous
//
#include <hip/hip_runtime.h>
#include <hip/hip_bf16.h>
#include <math.h>

#define BB 2
#define NN 2048
#define QD 1024
#define CTX_LEN 77
#define TCD 768
#define NUM_PROMPT 64
#define PD 1024
#define HEADS 8
#define DIM_HEAD 64
#define INNER 512
#define JTOT (CTX_LEN + NUM_PROMPT + NN)   // 2189
#define SCALE 0.125f
#define SCALEL2 (0.125f * 1.44269504088896f)   // fold log2(e): softmax in exp2 domain
#define MTOT (BB * NN)                     // 4096
#define JPAD 2240                          // 35 * 64, attn j extent
#define KVPAD 2304                         // 18 * 128, K/V^T padded j extent (grid-friendly)
#define NT_J (JPAD / 64)                   // 35 j-tiles

typedef unsigned short u16;
typedef unsigned int u32;
typedef __attribute__((ext_vector_type(8))) short bf16x8;
typedef __attribute__((ext_vector_type(4))) float f32x4;

__device__ __forceinline__ u32 pack_split(float f) {   // interleaved: low16=hi, high16=lo
  u32 u = __builtin_bit_cast(u32, f);
  u32 hi = u & 0xffff0000u;
  float lo = f - __builtin_bit_cast(float, hi);
  u32 ul = __builtin_bit_cast(u32, lo);
  return __builtin_amdgcn_perm(ul, u, 0x07060302u);
}
__device__ __forceinline__ void split2(float f, u16& h, u16& l) {
  u32 u = __builtin_bit_cast(u32, f);
  u32 hm = u & 0xffff0000u;
  float lo = f - __builtin_bit_cast(float, hm);
  h = (u16)(u >> 16);
  l = (u16)(__builtin_bit_cast(u32, lo) >> 16);
}
__device__ __forceinline__ u16 rnd_bf16(float f) {   // RNE fp32 -> bf16
  u32 u = __builtin_bit_cast(u32, f);
  return (u16)((u + 0x7FFF + ((u >> 16) & 1)) >> 16);
}
__device__ __forceinline__ void pack4(const float4& f, ushort4& hh, ushort4& ll) {
  split2(f.x, hh.x, ll.x); split2(f.y, hh.y, ll.y);
  split2(f.z, hh.z, ll.z); split2(f.w, hh.w, ll.w);
}
__device__ __forceinline__ ushort4 pack4r(const float4& f) {   // RNE x4
  ushort4 r;
  r.x = rnd_bf16(f.x); r.y = rnd_bf16(f.y);
  r.z = rnd_bf16(f.z); r.w = rnd_bf16(f.w);
  return r;
}

// DPP lane move within 16-lane rows (ctrl must be ICE -> template)
template <int CTRL>
__device__ __forceinline__ float dpp_f(float x) {
  int i = __builtin_bit_cast(int, x);
  i = __builtin_amdgcn_update_dpp(0, i, CTRL, 0xF, 0xF, false);
  return __builtin_bit_cast(float, i);
}

// async global->LDS, 16B per lane; lds dest = base + lane*16
__device__ __forceinline__ void gload16(const u16* g, u32* l) {
  __builtin_amdgcn_global_load_lds(
      (const __attribute__((address_space(1))) u32*)(const void*)g,
      (__attribute__((address_space(3))) u32*)(void*)l, 16, 0, 0);
}

// ---------------- merged f32 -> plane pack: x, prompt (split), text-ctx (RNE), V^T pad-zero ----------------
__global__ __launch_bounds__(256) void pack_planes4(
    const float* __restrict__ s0, u16* __restrict__ d0h, u16* __restrict__ d0l, int n0,
    const float* __restrict__ s1, u16* __restrict__ d1h, u16* __restrict__ d1l, int n1,
    const float* __restrict__ ctx, u16* __restrict__ ch, int n2,
    u16* __restrict__ zh, int n3) {
  int i = blockIdx.x * 256 + threadIdx.x;
  ushort4 hh, ll;
  if (i < n0) {
    pack4(((const float4*)s0)[i], hh, ll);
    ((ushort4*)d0h)[i] = hh; ((ushort4*)d0l)[i] = ll;
    return;
  }
  i -= n0;
  if (i < n1) {
    pack4(((const float4*)s1)[i], hh, ll);
    ((ushort4*)d1h)[i] = hh; ((ushort4*)d1l)[i] = ll;
    return;
  }
  i -= n1;
  if (i < n2) {
    // text context rows -> ctx plane (single RNE bf16) rows [b*JTOT + r], r < CTX_LEN
    ushort4 rr = pack4r(((const float4*)ctx)[i]);
    int c4 = i % (TCD / 4);
    int rb = i / (TCD / 4);
    int r = rb % CTX_LEN, b = rb / CTX_LEN;
    size_t o = ((size_t)b * JTOT + r) * (TCD / 4) + c4;   // ushort4 units
    ((ushort4*)ch)[o] = rr;
    return;
  }
  i -= n2;
  if (i >= n3) return;
  // zero-fill V^T (hi plane only) j in [2176, 2240): 8 chunks of 8 u16 per (b,d) row
  int c = i & 7;
  int row = i >> 3;            // [b(2)][d(512)]
  int d = row & 511;
  int b = row >> 9;
  uint4 z = {0u, 0u, 0u, 0u};
  *(uint4*)&zh[((size_t)b * INNER + d) * KVPAD + 2176 + c * 8] = z;
}

// ---------------- merged weight transpose+pack: 6 sources, one launch ----------------
struct TP6 {
  const float* src[6];
  u16* dh[6];
  u16* dl[6];
  int K[6], N[6];
  int blk0[7];   // cumulative block offsets, blk0[6] = total blocks
};

__global__ __launch_bounds__(256) void transpose_pack6(TP6 P) {
  __shared__ u32 T[32][33];
  const int bid = blockIdx.x;
  int s = 0;
#pragma unroll
  for (int k = 1; k < 6; ++k) s += (bid >= P.blk0[k]);
  const int rel = bid - P.blk0[s];
  const int N = P.N[s], K = P.K[s];
  const int nbx = N >> 5;
  const int bx = rel % nbx, by = rel / nbx;
  const float* __restrict__ src = P.src[s];
  u16* __restrict__ dh = P.dh[s];
  u16* __restrict__ dl = P.dl[s];
  const int t = threadIdx.x;
  const int k0 = by * 32, n0 = bx * 32;
#pragma unroll
  for (int i = 0; i < 4; ++i) {
    int e = t + i * 256;
    int kr = e >> 5, nc = e & 31;
    T[kr][nc] = pack_split(src[(size_t)(k0 + kr) * N + n0 + nc]);
  }
  __syncthreads();
#pragma unroll
  for (int i = 0; i < 4; ++i) {
    int e = t + i * 256;
    int nr = e >> 5, kc = e & 31;
    u32 w = T[kc][nr];
    size_t idx = (size_t)(n0 + nr) * K + k0 + kc;
    dh[idx] = (u16)(w & 0xffff);
    dl[idx] = (u16)(w >> 16);
  }
}

// ---------------- split-bf16 MFMA GEMM, 128x64 tiles, BK=64, bijective XCD swizzle ----------------
// MODE 1 (3-term): gn<TCD -> ctx single RNE plane (row remap); else q single RNE plane
//         (x SCALEL2). Extra band bm>=MTOT: prompt@w_prompt -> ctx rows 77..140 (both b).
// MODE 2 (1-term, single-plane operands): grid y = 36 (18/batch). gn<INNER -> K single
//         RNE plane [B][KVPAD][INNER]; else V^T RNE plane [B][INNER][KVPAD] via LDS transpose.
// MODE 3 (3-term): f32 out + bias
template <int MODE>
__global__ __launch_bounds__(256) void gemm_mfma(
    const u16* __restrict__ Agh, const u16* __restrict__ Agl,
    const u16* __restrict__ Bgh, const u16* __restrict__ Bgl,
    u16* __restrict__ O1h,
    u16* __restrict__ O2h,
    float* __restrict__ Of, const float* __restrict__ bias,
    int M, int K, int Ntot,
    const u16* __restrict__ A2h, const u16* __restrict__ A2l,
    const u16* __restrict__ B2h, const u16* __restrict__ B2l) {
  constexpr bool ONET = (MODE == 2);   // single-term, single-plane operands
  __shared__ __align__(16) u32 Ah_s[2][128 * 16];
  __shared__ __align__(16) u32 Al_s[2][128 * 16];
  __shared__ __align__(16) u32 Bh_s[2][64 * 16];
  __shared__ __align__(16) u32 Bl_s[2][64 * 16];

  // bijective chunked XCD swizzle (m204): each XCD owns a contiguous grid chunk
  int bxi = blockIdx.x, byi = blockIdx.y;
  {
    const int GX = gridDim.x;
    const int nwg = GX * gridDim.y;
    const int lid = byi * GX + bxi;
    const int qq = nwg >> 3, rr = nwg & 7;
    const int xcd = lid & 7, pos = lid >> 3;
    const int swz = (xcd < rr ? xcd * (qq + 1) : rr * (qq + 1) + (xcd - rr) * qq) + pos;
    bxi = swz % GX; byi = swz / GX;
  }
  const int bm = byi * 128, bn = bxi * 64;

  const bool pband = (MODE == 1) && (bm >= MTOT);
  if (pband && bn >= TCD) return;   // block-uniform: idle prompt-band columns

  int b2 = 0, jbase = 0;
  if (MODE == 2) { b2 = (byi >= 18); jbase = (byi - b2 * 18) * 128; }

  const int t = threadIdx.x;
  const int w = t >> 6, lane = t & 63;
  const int m16 = lane & 15, quad = lane >> 4;
  const int wm = w >> 1, wn = w & 1;

  const u16* Abh = Agh; const u16* Abl = Agl;
  const u16* Bbh = Bgh; const u16* Bbl = Bgl;
  int rowlim = M - 1;
  int bmA = bm;
  if (pband) { Abh = A2h; Abl = A2l; Bbh = B2h; Bbl = B2l; rowlim = NUM_PROMPT - 1; bmA = 0; }

  // DMA staging geometry: 4 lanes per 64B row, lane's 16B slot = (lane&3)*8 u16.
  // Wave w: A rows 32w..32w+31 (2 calls of 16 rows), B rows 16w..16w+15 (1 call).
  const int acol = (lane & 3) * 8;
  const int ar0 = 32 * w + (lane >> 2);
  const int ar1 = ar0 + 16;
  int ag0, ag1;
  if (MODE == 2) {
    ag0 = b2 * JTOT + min(jbase + ar0, JTOT - 1);   // clamp inside batch: no straddle
    ag1 = b2 * JTOT + min(jbase + ar1, JTOT - 1);
  } else {
    ag0 = min(bmA + ar0, rowlim);
    ag1 = min(bmA + ar1, rowlim);
  }
  const u16* a0h = Abh + (size_t)ag0 * K + acol;
  const u16* a1h = Abh + (size_t)ag1 * K + acol;
  const u16* a0l = ONET ? nullptr : Abl + (size_t)ag0 * K + acol;
  const u16* a1l = ONET ? nullptr : Abl + (size_t)ag1 * K + acol;
  const int br = 16 * w + (lane >> 2);
  const u16* b0h = Bbh + (size_t)(bn + br) * K + acol;
  const u16* b0l = ONET ? nullptr : Bbl + (size_t)(bn + br) * K + acol;

  f32x4 acc[4][2];
#pragma unroll
  for (int i = 0; i < 4; ++i)
#pragma unroll
    for (int j = 0; j < 2; ++j) acc[i][j] = (f32x4){0.f, 0.f, 0.f, 0.f};

  for (int k0 = 0; k0 < K; k0 += 64) {
    // ---- async stage both 32-col sub-tiles ----
#pragma unroll
    for (int s = 0; s < 2; ++s) {
      const int kc = k0 + s * 32;
      gload16(a0h + kc, &Ah_s[s][(2 * w) * 256]);
      gload16(a1h + kc, &Ah_s[s][(2 * w + 1) * 256]);
      gload16(b0h + kc, &Bh_s[s][w * 256]);
      if (!ONET) {
        gload16(a0l + kc, &Al_s[s][(2 * w) * 256]);
        gload16(a1l + kc, &Al_s[s][(2 * w + 1) * 256]);
        gload16(b0l + kc, &Bl_s[s][w * 256]);
      }
    }
    __syncthreads();   // drains DMA (compiler emits vmcnt(0) before barrier)

#pragma unroll
    for (int s = 0; s < 2; ++s) {
      bf16x8 ah[4], al[4], bh[2], bl[2];
#pragma unroll
      for (int mt = 0; mt < 4; ++mt) {
        int off = (wm * 64 + mt * 16 + m16) * 16 + quad * 4;
        ah[mt] = *(const bf16x8*)&Ah_s[s][off];
        if (!ONET) al[mt] = *(const bf16x8*)&Al_s[s][off];
      }
#pragma unroll
      for (int nt = 0; nt < 2; ++nt) {
        int off = (wn * 32 + nt * 16 + m16) * 16 + quad * 4;
        bh[nt] = *(const bf16x8*)&Bh_s[s][off];
        if (!ONET) bl[nt] = *(const bf16x8*)&Bl_s[s][off];
      }
#pragma unroll
      for (int mt = 0; mt < 4; ++mt)
#pragma unroll
        for (int nt = 0; nt < 2; ++nt) {
          acc[mt][nt] = __builtin_amdgcn_mfma_f32_16x16x32_bf16(ah[mt], bh[nt], acc[mt][nt], 0, 0, 0);
          if (!ONET) {
            acc[mt][nt] = __builtin_amdgcn_mfma_f32_16x16x32_bf16(ah[mt], bl[nt], acc[mt][nt], 0, 0, 0);
            acc[mt][nt] = __builtin_amdgcn_mfma_f32_16x16x32_bf16(al[mt], bh[nt], acc[mt][nt], 0, 0, 0);
          }
        }
    }
    __syncthreads();   // frag reads done before next DMA overwrites
  }

  if (MODE == 2 && bn >= INNER) {
    // ---- V^T direct write, single RNE plane: LDS transpose + coalesced 16B stores ----
    u16* Th = (u16*)Ah_s;   // 16KB region: [64 d][128 j] u16, chunk-XOR layout
#pragma unroll
    for (int mt = 0; mt < 4; ++mt)
#pragma unroll
      for (int nt = 0; nt < 2; ++nt)
#pragma unroll
        for (int r = 0; r < 4; ++r) {
          int dl = wn * 32 + nt * 16 + m16;
          int jl = wm * 64 + mt * 16 + quad * 4 + r;
          int adr = dl * 128 + ((((jl >> 3) ^ (dl & 15)) << 3) | (jl & 7));
          Th[adr] = rnd_bf16(acc[mt][nt][r]);
        }
    __syncthreads();
#pragma unroll
    for (int i = 0; i < 4; ++i) {
      int chunk = t + i * 256;            // 1024 chunks = 64 d x 16 j-chunks
      int dl = chunk >> 4, jc = chunk & 15;
      int jg = jbase + jc * 8;
      int lofs = dl * 128 + ((jc ^ (dl & 15)) << 3);
      uint4 vh4 = *(const uint4*)&Th[lofs];
      size_t rowo = ((size_t)b2 * INNER + (bn - INNER) + dl) * KVPAD;
      if (jg + 8 <= JTOT) {
        *(uint4*)&O2h[rowo + jg] = vh4;
      } else if (jg < JTOT) {
        const u16* eh = (const u16*)&vh4;
#pragma unroll
        for (int e = 0; e < 8; ++e)
          if (jg + e < JTOT) O2h[rowo + jg + e] = eh[e];
      }   // jg >= JTOT: keep pre-zeroed pad
    }
    return;
  }

#pragma unroll
  for (int mt = 0; mt < 4; ++mt)
#pragma unroll
    for (int nt = 0; nt < 2; ++nt)
#pragma unroll
      for (int r = 0; r < 4; ++r) {
        int gm = bm + wm * 64 + mt * 16 + quad * 4 + r;
        int gn = bn + wn * 32 + nt * 16 + m16;
        float v = acc[mt][nt][r];
        if (MODE == 1) {
          if (pband) {
            int pr = wm * 64 + mt * 16 + quad * 4 + r;
            if (pr < NUM_PROMPT && gn < TCD) {
              u16 rv = rnd_bf16(v);
              O1h[((size_t)CTX_LEN + pr) * TCD + gn] = rv;           // b = 0
              O1h[((size_t)JTOT + CTX_LEN + pr) * TCD + gn] = rv;    // b = 1
            }
          } else if (gn < TCD) {
            size_t row = (size_t)(gm >> 11) * JTOT + 141 + (gm & 2047);
            O1h[row * TCD + gn] = rnd_bf16(v);
          } else {
            O2h[(size_t)gm * INNER + (gn - TCD)] = rnd_bf16(v * SCALEL2);
          }
        } else if (MODE == 2) {
          // K half: single RNE plane [B][KVPAD][INNER]; rows >= JTOT masked in attn
          int jloc = jbase + wm * 64 + mt * 16 + quad * 4 + r;
          O1h[((size_t)b2 * KVPAD + jloc) * INNER + gn] = rnd_bf16(v);
        } else if (MODE == 3) {
          Of[(size_t)gm * QD + gn] = v + bias[gn];
        }
      }
}

// ---------------- plane-format MFMA flash attention (all operands single RNE bf16) ----------------
// K plane [B][KVPAD][INNER], V^T plane [B][INNER][KVPAD]; staged via global_load_lds
// with pre-swizzled source (XOR chunk swizzle) -> conflict-free ds_read_b128 fragments.
// Precision budget (flat softmax over 2189 keys): Q/K rounding -> logit err ~0.004 in
// exp2 domain -> p rel err ~0.3% -> output err ~1e-4, below the 0.00195 bf16 floor.
__global__ __launch_bounds__(256) void attn_mfma2(
    const u16* __restrict__ qhg,
    const u16* __restrict__ khg,
    const u16* __restrict__ vtg_h,
    u16* __restrict__ aoh, u16* __restrict__ aol) {
  __shared__ __align__(16) u16 Kh_s[64 * 64];
  __shared__ __align__(16) u16 Vh_s[64 * 64];
  __shared__ __align__(16) u16 Ph_s[64 * 72];

  const int t = threadIdx.x;
  const int w = t >> 6, lane = t & 63;
  const int m16 = lane & 15, quad = lane >> 4;

  // XCD swizzle: 512 blocks = 8 * 64; each XCD gets 2 contiguous (b,h) groups
  const int id = blockIdx.x;
  const int swz = (id & 7) * 64 + (id >> 3);
  const int qt = swz & 31, bh = swz >> 5;
  const int b = bh >> 3, h = bh & 7;
  const int qrow0 = qt * 64;

  // Q fragments direct from global plane (A-frag: row=m16, k=ks*32+quad*8)
  bf16x8 qh[2];
  {
    size_t qoff = ((size_t)(b * NN + qrow0 + w * 16 + m16)) * INNER + h * 64 + quad * 8;
#pragma unroll
    for (int ks = 0; ks < 2; ++ks)
      qh[ks] = *(const bf16x8*)(qhg + qoff + ks * 32);
  }

  // Staging: waves 0,1 -> K chunks 0-3/4-7; waves 2,3 -> V^T chunks 0-3/4-7.
  // Per chunk: 8 rows x 8 slots of 16B; dest linear, source slot = (lane&7)^(lane>>3)
  // so LDS (row, cc) holds logical chunk cc^(row&7)  (same layout as before).
  const int sr = lane >> 3;
  const int sc = (lane & 7) ^ sr;
  const int c0 = (w & 1) * 4;
  const u16* gp;
  u32* lp;
  size_t cstr, jstr;
  if (w < 2) {
    gp = khg + ((size_t)b * KVPAD + c0 * 8 + sr) * INNER + h * 64 + sc * 8;
    lp = (u32*)Kh_s + c0 * 256;
    cstr = (size_t)8 * INNER;
    jstr = (size_t)64 * INNER;
  } else {
    gp = vtg_h + ((size_t)b * INNER + h * 64 + c0 * 8 + sr) * KVPAD + sc * 8;
    lp = (u32*)Vh_s + c0 * 256;
    cstr = (size_t)8 * KVPAD;
    jstr = 64;
  }

  f32x4 O[4] = {{0.f,0.f,0.f,0.f},{0.f,0.f,0.f,0.f},{0.f,0.f,0.f,0.f},{0.f,0.f,0.f,0.f}};
  float mrow[4], lrow[4];
#pragma unroll
  for (int r = 0; r < 4; ++r) { mrow[r] = -INFINITY; lrow[r] = 0.f; }

  for (int tile = 0; tile < NT_J; ++tile) {
    const int j0 = tile * 64;
    __syncthreads();                       // prior tile fully consumed
#pragma unroll
    for (int c = 0; c < 4; ++c) gload16(gp + (size_t)c * cstr, lp + c * 256);
    gp += jstr;
    __syncthreads();                       // drain DMA (vmcnt(0) before barrier)

    // ---- QK^T (single-plane: 8 MFMA) ----
    f32x4 S[4];
    __builtin_amdgcn_s_setprio(1);
#pragma unroll
    for (int jt = 0; jt < 4; ++jt) {
      const int row = jt * 16 + m16;
      f32x4 acc = {0.f, 0.f, 0.f, 0.f};
#pragma unroll
      for (int ks = 0; ks < 2; ++ks) {
        const int cc = row * 64 + (((ks * 4 + quad) ^ (row & 7)) << 3);
        bf16x8 kh = *(const bf16x8*)&Kh_s[cc];
        acc = __builtin_amdgcn_mfma_f32_16x16x32_bf16(qh[ks], kh, acc, 0, 0, 0);
      }
      S[jt] = acc;
    }
    __builtin_amdgcn_s_setprio(0);

    // mask tail columns (also covers K pad-row garbage)
#pragma unroll
    for (int jt = 0; jt < 4; ++jt) {
      int jc = j0 + jt * 16 + m16;
      if (jc >= JTOT)
#pragma unroll
        for (int r = 0; r < 4; ++r) S[jt][r] = -INFINITY;
    }

    // ---- online softmax (exp2 domain): DPP reductions over 16-lane rows ----
    float pj[4][4];
#pragma unroll
    for (int r = 0; r < 4; ++r) {
      float mx = fmaxf(fmaxf(S[0][r], S[1][r]), fmaxf(S[2][r], S[3][r]));
      mx = fmaxf(mx, dpp_f<0xB1>(mx));     // quad_perm [1,0,3,2] = xor1
      mx = fmaxf(mx, dpp_f<0x4E>(mx));     // quad_perm [2,3,0,1] = xor2
      mx = fmaxf(mx, dpp_f<0x124>(mx));    // row_ror:4
      mx = fmaxf(mx, dpp_f<0x128>(mx));    // row_ror:8
      float mnew = fmaxf(mrow[r], mx);
      float alpha = __builtin_amdgcn_exp2f(mrow[r] - mnew);
      mrow[r] = mnew;
      float rs = 0.f;
#pragma unroll
      for (int jt = 0; jt < 4; ++jt) {
        float pv = __builtin_amdgcn_exp2f(S[jt][r] - mnew);
        pj[jt][r] = pv;
        rs += pv;
      }
      rs += dpp_f<0xB1>(rs);
      rs += dpp_f<0x4E>(rs);
      rs += dpp_f<0x124>(rs);
      rs += dpp_f<0x128>(rs);
      lrow[r] = lrow[r] * alpha + rs;
#pragma unroll
      for (int nt = 0; nt < 4; ++nt) O[nt][r] *= alpha;
    }

    // ---- P -> LDS (single RNE bf16 plane; rows are wave-private: no barrier) ----
#pragma unroll
    for (int jt = 0; jt < 4; ++jt)
#pragma unroll
      for (int r = 0; r < 4; ++r) {
        int pq = (w * 16 + quad * 4 + r) * 72 + jt * 16 + m16;
        Ph_s[pq] = rnd_bf16(pj[jt][r]);
      }

    bf16x8 ph[2];
#pragma unroll
    for (int ks = 0; ks < 2; ++ks) {
      int po = (w * 16 + m16) * 72 + ks * 32 + quad * 8;
      ph[ks] = *(const bf16x8*)&Ph_s[po];
    }

    // ---- PV (single-plane: 8 MFMA) ----
    __builtin_amdgcn_s_setprio(1);
#pragma unroll
    for (int nt = 0; nt < 4; ++nt) {
      const int row = nt * 16 + m16;
#pragma unroll
      for (int ks = 0; ks < 2; ++ks) {
        const int cc = row * 64 + (((ks * 4 + quad) ^ (row & 7)) << 3);
        bf16x8 vh = *(const bf16x8*)&Vh_s[cc];
        O[nt] = __builtin_amdgcn_mfma_f32_16x16x32_bf16(ph[ks], vh, O[nt], 0, 0, 0);
      }
    }
    __builtin_amdgcn_s_setprio(0);
  }

  float inv[4];
#pragma unroll
  for (int r = 0; r < 4; ++r) inv[r] = 1.f / lrow[r];
#pragma unroll
  for (int nt = 0; nt < 4; ++nt)
#pragma unroll
    for (int r = 0; r < 4; ++r) {
      size_t idx = ((size_t)(b * NN + qrow0 + w * 16 + quad * 4 + r)) * INNER +
                   h * 64 + nt * 16 + m16;
      u16 sh, sl;
      split2(O[nt][r] * inv[r], sh, sl);
      aoh[idx] = sh; aol[idx] = sl;
    }
}

// ---------------- launch ----------------
extern "C" void kernel_launch(void* const* d_in, const int* in_sizes, int n_in,
                              void* d_out, int out_size, void* d_ws, size_t ws_size,
                              hipStream_t stream) {
  const float* x        = (const float*)d_in[0];
  const float* context  = (const float*)d_in[1];
  const float* prompt   = (const float*)d_in[2];
  const float* w_prompt = (const float*)d_in[3];
  const float* w_img    = (const float*)d_in[4];
  const float* w_q      = (const float*)d_in[5];
  const float* w_k      = (const float*)d_in[6];
  const float* w_v      = (const float*)d_in[7];
  const float* w_out    = (const float*)d_in[8];
  const float* b_out    = (const float*)d_in[9];
  float* out = (float*)d_out;

  const int M = MTOT;             // 4096
  const int MJ = BB * JTOT;       // 4378

  u16* p = (u16*)d_ws;
  const size_t qN = (size_t)M * INNER;
  const size_t ctxN = (size_t)MJ * TCD;
  const size_t kN = (size_t)BB * KVPAD * INNER;  // K / V^T plane size
  u16* cth = p; p += ctxN;                          // ctx single RNE plane
  u16* aoh = p; p += qN;   u16* aol = p; p += qN;
  u16* xh  = p; p += (size_t)M * QD;   u16* xl  = p; p += (size_t)M * QD;
  u16* prh = p; p += (size_t)NUM_PROMPT * PD;
  u16* prl = p; p += (size_t)NUM_PROMPT * PD;
  u16* WtPh = p; p += (size_t)TCD * PD;            u16* WtPl = p; p += (size_t)TCD * PD;
  u16* WtAh = p; p += (size_t)(TCD + INNER) * QD;  u16* WtAl = p; p += (size_t)(TCD + INNER) * QD;
  u16* WtBh = p; p += (size_t)(2 * INNER) * TCD;   u16* WtBl = p; p += (size_t)(2 * INNER) * TCD;
  u16* WtOh = p; p += (size_t)QD * INNER;          u16* WtOl = p; p += (size_t)QD * INNER;
  u16* qhp = p; p += qN;                           // q single RNE plane (exp2 domain)
  u16* khp = p; p += kN;                           // K single RNE plane [B][KVPAD][INNER]
  u16* vthp = p; p += kN;                          // V^T single RNE plane [B][INNER][KVPAD]

  // ---- pack inputs + text ctx rows + V^T pad zero-fill (one launch) ----
  const int n4x = M * QD / 4, n4p = NUM_PROMPT * PD / 4;
  const int n4c = BB * CTX_LEN * TCD / 4;
  const int n4z = BB * INNER * 8;   // 8192 zero chunks of 16B
  pack_planes4<<<(n4x + n4p + n4c + n4z + 255) / 256, 256, 0, stream>>>(
      x, xh, xl, n4x, prompt, prh, prl, n4p, context, cth, n4c,
      vthp, n4z);

  // ---- transpose+pack all 6 weights (one launch) ----
  TP6 tp;
  const float* srcs[6] = {w_prompt, w_img, w_q, w_k, w_v, w_out};
  u16* dhs[6] = {WtPh, WtAh, WtAh + (size_t)TCD * QD, WtBh, WtBh + (size_t)INNER * TCD, WtOh};
  u16* dls[6] = {WtPl, WtAl, WtAl + (size_t)TCD * QD, WtBl, WtBl + (size_t)INNER * TCD, WtOl};
  int Ks[6] = {PD, QD, QD, TCD, TCD, INNER};
  int Ns[6] = {TCD, TCD, INNER, INNER, INNER, QD};
  int acc_blk = 0;
  for (int i = 0; i < 6; ++i) {
    tp.src[i] = srcs[i]; tp.dh[i] = dhs[i]; tp.dl[i] = dls[i];
    tp.K[i] = Ks[i]; tp.N[i] = Ns[i];
    tp.blk0[i] = acc_blk;
    acc_blk += (Ns[i] / 32) * (Ks[i] / 32);
  }
  tp.blk0[6] = acc_blk;
  transpose_pack6<<<acc_blk, 256, 0, stream>>>(tp);

  // ---- x @ [w_img | w_q] -> ctx plane (remap, RNE) + q plane (x SCALEL2, RNE);
  //      extra band: prompt @ w_prompt -> ctx rows 77..140 (both b) ----
  gemm_mfma<1><<<dim3((TCD + INNER) / 64, M / 128 + 1), 256, 0, stream>>>(
      xh, xl, WtAh, WtAl, cth, qhp, nullptr, nullptr,
      M, QD, TCD + INNER, prh, prl, WtPh, WtPl);
  // ---- ctx @ [w_k | w_v] (1-term single-plane) -> K plane + V^T plane ----
  gemm_mfma<2><<<dim3((2 * INNER) / 64, 2 * (KVPAD / 128)), 256, 0, stream>>>(
      cth, nullptr, WtBh, nullptr, khp, vthp, nullptr, nullptr,
      MJ, TCD, 2 * INNER, nullptr, nullptr, nullptr, nullptr);
  // ---- attention ----
  attn_mfma2<<<BB * HEADS * (NN / 64), 256, 0, stream>>>(
      qhp, khp, vthp, aoh, aol);
  // ---- out = ao @ w_out + b_out ----
  gemm_mfma<3><<<dim3(QD / 64, M / 128), 256, 0, stream>>>(
      aoh, aol, WtOh, WtOl, nullptr, nullptr, out, b_out,
      M, INNER, QD, nullptr, nullptr, nullptr, nullptr);
}

// Round 13
// 222.774 us; speedup vs baseline: 1.4875x; 1.0747x over previous
//
#include <hip/hip_runtime.h>
#include <hip/hip_bf16.h>
#include <math.h>

#define BB 2
#define NN 2048
#define QD 1024
#define CTX_LEN 77
#define TCD 768
#define NUM_PROMPT 64
#define PD 1024
#define HEADS 8
#define DIM_HEAD 64
#define INNER 512
#define JTOT (CTX_LEN + NUM_PROMPT + NN)   // 2189
#define SCALE 0.125f
#define SCALEL2 (0.125f * 1.44269504088896f)   // fold log2(e): softmax in exp2 domain
#define MTOT (BB * NN)                     // 4096
#define JPAD 2240                          // 35 * 64, attn j extent
#define KVPAD 2304                         // 18 * 128, K/V^T padded j extent (grid-friendly)
#define NT_J (JPAD / 64)                   // 35 j-tiles

typedef unsigned short u16;
typedef unsigned int u32;
typedef __attribute__((ext_vector_type(8))) short bf16x8;
typedef __attribute__((ext_vector_type(4))) float f32x4;

__device__ __forceinline__ u32 pack_split(float f) {   // interleaved: low16=hi, high16=lo
  u32 u = __builtin_bit_cast(u32, f);
  u32 hi = u & 0xffff0000u;
  float lo = f - __builtin_bit_cast(float, hi);
  u32 ul = __builtin_bit_cast(u32, lo);
  return __builtin_amdgcn_perm(ul, u, 0x07060302u);
}
__device__ __forceinline__ void split2(float f, u16& h, u16& l) {
  u32 u = __builtin_bit_cast(u32, f);
  u32 hm = u & 0xffff0000u;
  float lo = f - __builtin_bit_cast(float, hm);
  h = (u16)(u >> 16);
  l = (u16)(__builtin_bit_cast(u32, lo) >> 16);
}
__device__ __forceinline__ u16 rnd_bf16(float f) {   // RNE fp32 -> bf16
  u32 u = __builtin_bit_cast(u32, f);
  return (u16)((u + 0x7FFF + ((u >> 16) & 1)) >> 16);
}
__device__ __forceinline__ void pack4(const float4& f, ushort4& hh, ushort4& ll) {
  split2(f.x, hh.x, ll.x); split2(f.y, hh.y, ll.y);
  split2(f.z, hh.z, ll.z); split2(f.w, hh.w, ll.w);
}
__device__ __forceinline__ ushort4 pack4r(const float4& f) {   // RNE x4
  ushort4 r;
  r.x = rnd_bf16(f.x); r.y = rnd_bf16(f.y);
  r.z = rnd_bf16(f.z); r.w = rnd_bf16(f.w);
  return r;
}

// DPP lane move within 16-lane rows (ctrl must be ICE -> template)
template <int CTRL>
__device__ __forceinline__ float dpp_f(float x) {
  int i = __builtin_bit_cast(int, x);
  i = __builtin_amdgcn_update_dpp(0, i, CTRL, 0xF, 0xF, false);
  return __builtin_bit_cast(float, i);
}

// async global->LDS, 16B per lane; lds dest = base + lane*16
__device__ __forceinline__ void gload16(const u16* g, u32* l) {
  __builtin_amdgcn_global_load_lds(
      (const __attribute__((address_space(1))) u32*)(const void*)g,
      (__attribute__((address_space(3))) u32*)(void*)l, 16, 0, 0);
}

// ---------------- merged f32 -> plane pack: x, prompt (split), text-ctx (RNE), V^T pad-zero ----------------
__global__ __launch_bounds__(256) void pack_planes4(
    const float* __restrict__ s0, u16* __restrict__ d0h, u16* __restrict__ d0l, int n0,
    const float* __restrict__ s1, u16* __restrict__ d1h, u16* __restrict__ d1l, int n1,
    const float* __restrict__ ctx, u16* __restrict__ ch, int n2,
    u16* __restrict__ zh, int n3) {
  int i = blockIdx.x * 256 + threadIdx.x;
  ushort4 hh, ll;
  if (i < n0) {
    pack4(((const float4*)s0)[i], hh, ll);
    ((ushort4*)d0h)[i] = hh; ((ushort4*)d0l)[i] = ll;
    return;
  }
  i -= n0;
  if (i < n1) {
    pack4(((const float4*)s1)[i], hh, ll);
    ((ushort4*)d1h)[i] = hh; ((ushort4*)d1l)[i] = ll;
    return;
  }
  i -= n1;
  if (i < n2) {
    // text context rows -> ctx plane (single RNE bf16) rows [b*JTOT + r], r < CTX_LEN
    ushort4 rr = pack4r(((const float4*)ctx)[i]);
    int c4 = i % (TCD / 4);
    int rb = i / (TCD / 4);
    int r = rb % CTX_LEN, b = rb / CTX_LEN;
    size_t o = ((size_t)b * JTOT + r) * (TCD / 4) + c4;   // ushort4 units
    ((ushort4*)ch)[o] = rr;
    return;
  }
  i -= n2;
  if (i >= n3) return;
  // zero-fill V^T (hi plane only) j in [2176, 2240): 8 chunks of 8 u16 per (b,d) row
  int c = i & 7;
  int row = i >> 3;            // [b(2)][d(512)]
  int d = row & 511;
  int b = row >> 9;
  uint4 z = {0u, 0u, 0u, 0u};
  *(uint4*)&zh[((size_t)b * INNER + d) * KVPAD + 2176 + c * 8] = z;
}

// ---------------- merged weight transpose+pack: 6 sources, one launch ----------------
struct TP6 {
  const float* src[6];
  u16* dh[6];
  u16* dl[6];
  int K[6], N[6];
  int blk0[7];   // cumulative block offsets, blk0[6] = total blocks
};

__global__ __launch_bounds__(256) void transpose_pack6(TP6 P) {
  __shared__ u32 T[32][33];
  const int bid = blockIdx.x;
  int s = 0;
#pragma unroll
  for (int k = 1; k < 6; ++k) s += (bid >= P.blk0[k]);
  const int rel = bid - P.blk0[s];
  const int N = P.N[s], K = P.K[s];
  const int nbx = N >> 5;
  const int bx = rel % nbx, by = rel / nbx;
  const float* __restrict__ src = P.src[s];
  u16* __restrict__ dh = P.dh[s];
  u16* __restrict__ dl = P.dl[s];
  const int t = threadIdx.x;
  const int k0 = by * 32, n0 = bx * 32;
#pragma unroll
  for (int i = 0; i < 4; ++i) {
    int e = t + i * 256;
    int kr = e >> 5, nc = e & 31;
    T[kr][nc] = pack_split(src[(size_t)(k0 + kr) * N + n0 + nc]);
  }
  __syncthreads();
#pragma unroll
  for (int i = 0; i < 4; ++i) {
    int e = t + i * 256;
    int nr = e >> 5, kc = e & 31;
    u32 w = T[kc][nr];
    size_t idx = (size_t)(n0 + nr) * K + k0 + kc;
    dh[idx] = (u16)(w & 0xffff);
    dl[idx] = (u16)(w >> 16);
  }
}

// ---------------- split-bf16 MFMA GEMM, 128x64 tiles, BK=64, bijective XCD swizzle ----------------
// MODE 1 (3-term): gn<TCD -> ctx single RNE plane (row remap); else q single RNE plane
//         (x SCALEL2). Extra band bm>=MTOT: prompt@w_prompt -> ctx rows 77..140 (both b).
// MODE 2 (1-term, single-plane operands): grid y = 36 (18/batch). gn<INNER -> K single
//         RNE plane [B][KVPAD][INNER]; else V^T RNE plane [B][INNER][KVPAD] via LDS transpose.
// MODE 3 (3-term): f32 out + bias
template <int MODE>
__global__ __launch_bounds__(256) void gemm_mfma(
    const u16* __restrict__ Agh, const u16* __restrict__ Agl,
    const u16* __restrict__ Bgh, const u16* __restrict__ Bgl,
    u16* __restrict__ O1h,
    u16* __restrict__ O2h,
    float* __restrict__ Of, const float* __restrict__ bias,
    int M, int K, int Ntot,
    const u16* __restrict__ A2h, const u16* __restrict__ A2l,
    const u16* __restrict__ B2h, const u16* __restrict__ B2l) {
  constexpr bool ONET = (MODE == 2);   // single-term, single-plane operands
  __shared__ __align__(16) u32 Ah_s[2][128 * 16];
  __shared__ __align__(16) u32 Al_s[2][128 * 16];
  __shared__ __align__(16) u32 Bh_s[2][64 * 16];
  __shared__ __align__(16) u32 Bl_s[2][64 * 16];

  // bijective chunked XCD swizzle (m204): each XCD owns a contiguous grid chunk
  int bxi = blockIdx.x, byi = blockIdx.y;
  {
    const int GX = gridDim.x;
    const int nwg = GX * gridDim.y;
    const int lid = byi * GX + bxi;
    const int qq = nwg >> 3, rr = nwg & 7;
    const int xcd = lid & 7, pos = lid >> 3;
    const int swz = (xcd < rr ? xcd * (qq + 1) : rr * (qq + 1) + (xcd - rr) * qq) + pos;
    bxi = swz % GX; byi = swz / GX;
  }
  const int bm = byi * 128, bn = bxi * 64;

  const bool pband = (MODE == 1) && (bm >= MTOT);
  if (pband && bn >= TCD) return;   // block-uniform: idle prompt-band columns

  int b2 = 0, jbase = 0;
  if (MODE == 2) { b2 = (byi >= 18); jbase = (byi - b2 * 18) * 128; }

  const int t = threadIdx.x;
  const int w = t >> 6, lane = t & 63;
  const int m16 = lane & 15, quad = lane >> 4;
  const int wm = w >> 1, wn = w & 1;

  const u16* Abh = Agh; const u16* Abl = Agl;
  const u16* Bbh = Bgh; const u16* Bbl = Bgl;
  int rowlim = M - 1;
  int bmA = bm;
  if (pband) { Abh = A2h; Abl = A2l; Bbh = B2h; Bbl = B2l; rowlim = NUM_PROMPT - 1; bmA = 0; }

  // DMA staging geometry: 4 lanes per 64B row, lane's 16B slot = (lane&3)*8 u16.
  // Wave w: A rows 32w..32w+31 (2 calls of 16 rows), B rows 16w..16w+15 (1 call).
  const int acol = (lane & 3) * 8;
  const int ar0 = 32 * w + (lane >> 2);
  const int ar1 = ar0 + 16;
  int ag0, ag1;
  if (MODE == 2) {
    ag0 = b2 * JTOT + min(jbase + ar0, JTOT - 1);   // clamp inside batch: no straddle
    ag1 = b2 * JTOT + min(jbase + ar1, JTOT - 1);
  } else {
    ag0 = min(bmA + ar0, rowlim);
    ag1 = min(bmA + ar1, rowlim);
  }
  const u16* a0h = Abh + (size_t)ag0 * K + acol;
  const u16* a1h = Abh + (size_t)ag1 * K + acol;
  const u16* a0l = ONET ? nullptr : Abl + (size_t)ag0 * K + acol;
  const u16* a1l = ONET ? nullptr : Abl + (size_t)ag1 * K + acol;
  const int br = 16 * w + (lane >> 2);
  const u16* b0h = Bbh + (size_t)(bn + br) * K + acol;
  const u16* b0l = ONET ? nullptr : Bbl + (size_t)(bn + br) * K + acol;

  f32x4 acc[4][2];
#pragma unroll
  for (int i = 0; i < 4; ++i)
#pragma unroll
    for (int j = 0; j < 2; ++j) acc[i][j] = (f32x4){0.f, 0.f, 0.f, 0.f};

  for (int k0 = 0; k0 < K; k0 += 64) {
    // ---- async stage both 32-col sub-tiles ----
#pragma unroll
    for (int s = 0; s < 2; ++s) {
      const int kc = k0 + s * 32;
      gload16(a0h + kc, &Ah_s[s][(2 * w) * 256]);
      gload16(a1h + kc, &Ah_s[s][(2 * w + 1) * 256]);
      gload16(b0h + kc, &Bh_s[s][w * 256]);
      if (!ONET) {
        gload16(a0l + kc, &Al_s[s][(2 * w) * 256]);
        gload16(a1l + kc, &Al_s[s][(2 * w + 1) * 256]);
        gload16(b0l + kc, &Bl_s[s][w * 256]);
      }
    }
    __syncthreads();   // drains DMA (compiler emits vmcnt(0) before barrier)

#pragma unroll
    for (int s = 0; s < 2; ++s) {
      bf16x8 ah[4], al[4], bh[2], bl[2];
#pragma unroll
      for (int mt = 0; mt < 4; ++mt) {
        int off = (wm * 64 + mt * 16 + m16) * 16 + quad * 4;
        ah[mt] = *(const bf16x8*)&Ah_s[s][off];
        if (!ONET) al[mt] = *(const bf16x8*)&Al_s[s][off];
      }
#pragma unroll
      for (int nt = 0; nt < 2; ++nt) {
        int off = (wn * 32 + nt * 16 + m16) * 16 + quad * 4;
        bh[nt] = *(const bf16x8*)&Bh_s[s][off];
        if (!ONET) bl[nt] = *(const bf16x8*)&Bl_s[s][off];
      }
#pragma unroll
      for (int mt = 0; mt < 4; ++mt)
#pragma unroll
        for (int nt = 0; nt < 2; ++nt) {
          acc[mt][nt] = __builtin_amdgcn_mfma_f32_16x16x32_bf16(ah[mt], bh[nt], acc[mt][nt], 0, 0, 0);
          if (!ONET) {
            acc[mt][nt] = __builtin_amdgcn_mfma_f32_16x16x32_bf16(ah[mt], bl[nt], acc[mt][nt], 0, 0, 0);
            acc[mt][nt] = __builtin_amdgcn_mfma_f32_16x16x32_bf16(al[mt], bh[nt], acc[mt][nt], 0, 0, 0);
          }
        }
    }
    __syncthreads();   // frag reads done before next DMA overwrites
  }

  if (MODE == 2 && bn >= INNER) {
    // ---- V^T direct write, single RNE plane: LDS transpose + coalesced 16B stores ----
    u16* Th = (u16*)Ah_s;   // 16KB region: [64 d][128 j] u16, chunk-XOR layout
#pragma unroll
    for (int mt = 0; mt < 4; ++mt)
#pragma unroll
      for (int nt = 0; nt < 2; ++nt)
#pragma unroll
        for (int r = 0; r < 4; ++r) {
          int dl = wn * 32 + nt * 16 + m16;
          int jl = wm * 64 + mt * 16 + quad * 4 + r;
          int adr = dl * 128 + ((((jl >> 3) ^ (dl & 15)) << 3) | (jl & 7));
          Th[adr] = rnd_bf16(acc[mt][nt][r]);
        }
    __syncthreads();
#pragma unroll
    for (int i = 0; i < 4; ++i) {
      int chunk = t + i * 256;            // 1024 chunks = 64 d x 16 j-chunks
      int dl = chunk >> 4, jc = chunk & 15;
      int jg = jbase + jc * 8;
      int lofs = dl * 128 + ((jc ^ (dl & 15)) << 3);
      uint4 vh4 = *(const uint4*)&Th[lofs];
      size_t rowo = ((size_t)b2 * INNER + (bn - INNER) + dl) * KVPAD;
      if (jg + 8 <= JTOT) {
        *(uint4*)&O2h[rowo + jg] = vh4;
      } else if (jg < JTOT) {
        const u16* eh = (const u16*)&vh4;
#pragma unroll
        for (int e = 0; e < 8; ++e)
          if (jg + e < JTOT) O2h[rowo + jg + e] = eh[e];
      }   // jg >= JTOT: keep pre-zeroed pad
    }
    return;
  }

#pragma unroll
  for (int mt = 0; mt < 4; ++mt)
#pragma unroll
    for (int nt = 0; nt < 2; ++nt)
#pragma unroll
      for (int r = 0; r < 4; ++r) {
        int gm = bm + wm * 64 + mt * 16 + quad * 4 + r;
        int gn = bn + wn * 32 + nt * 16 + m16;
        float v = acc[mt][nt][r];
        if (MODE == 1) {
          if (pband) {
            int pr = wm * 64 + mt * 16 + quad * 4 + r;
            if (pr < NUM_PROMPT && gn < TCD) {
              u16 rv = rnd_bf16(v);
              O1h[((size_t)CTX_LEN + pr) * TCD + gn] = rv;           // b = 0
              O1h[((size_t)JTOT + CTX_LEN + pr) * TCD + gn] = rv;    // b = 1
            }
          } else if (gn < TCD) {
            size_t row = (size_t)(gm >> 11) * JTOT + 141 + (gm & 2047);
            O1h[row * TCD + gn] = rnd_bf16(v);
          } else {
            O2h[(size_t)gm * INNER + (gn - TCD)] = rnd_bf16(v * SCALEL2);
          }
        } else if (MODE == 2) {
          // K half: single RNE plane [B][KVPAD][INNER]; rows >= JTOT masked in attn
          int jloc = jbase + wm * 64 + mt * 16 + quad * 4 + r;
          O1h[((size_t)b2 * KVPAD + jloc) * INNER + gn] = rnd_bf16(v);
        } else if (MODE == 3) {
          Of[(size_t)gm * QD + gn] = v + bias[gn];
        }
      }
}

// ---------------- plane-format MFMA flash attention, fixed-max exp2 softmax ----------------
// K plane [B][KVPAD][INNER], V^T plane [B][INNER][KVPAD]; staged via global_load_lds
// with pre-swizzled source (XOR chunk swizzle) -> conflict-free ds_read_b128 fragments.
// Fixed-max: p = 2^(S-8). Exact power-of-2 rescale (cancels in O/l); logits ~N(0,1.2^2)
// over 2189 keys (max ~6) -> no overflow/denormals. Removes running-max DPP chain,
// alpha, O-rescale; l-reduction deferred to once per block (order-free sum).
__global__ __launch_bounds__(256) void attn_mfma2(
    const u16* __restrict__ qhg,
    const u16* __restrict__ khg,
    const u16* __restrict__ vtg_h,
    u16* __restrict__ aoh, u16* __restrict__ aol) {
  __shared__ __align__(16) u16 Kh_s[64 * 64];
  __shared__ __align__(16) u16 Vh_s[64 * 64];
  __shared__ __align__(16) u16 Ph_s[64 * 72];

  const int t = threadIdx.x;
  const int w = t >> 6, lane = t & 63;
  const int m16 = lane & 15, quad = lane >> 4;

  // XCD swizzle: 512 blocks = 8 * 64; each XCD gets 2 contiguous (b,h) groups
  const int id = blockIdx.x;
  const int swz = (id & 7) * 64 + (id >> 3);
  const int qt = swz & 31, bh = swz >> 5;
  const int b = bh >> 3, h = bh & 7;
  const int qrow0 = qt * 64;

  // Q fragments direct from global plane (A-frag: row=m16, k=ks*32+quad*8)
  bf16x8 qh[2];
  {
    size_t qoff = ((size_t)(b * NN + qrow0 + w * 16 + m16)) * INNER + h * 64 + quad * 8;
#pragma unroll
    for (int ks = 0; ks < 2; ++ks)
      qh[ks] = *(const bf16x8*)(qhg + qoff + ks * 32);
  }

  // Staging: waves 0,1 -> K chunks 0-3/4-7; waves 2,3 -> V^T chunks 0-3/4-7.
  // Per chunk: 8 rows x 8 slots of 16B; dest linear, source slot = (lane&7)^(lane>>3)
  // so LDS (row, cc) holds logical chunk cc^(row&7)  (same layout as before).
  const int sr = lane >> 3;
  const int sc = (lane & 7) ^ sr;
  const int c0 = (w & 1) * 4;
  const u16* gp;
  u32* lp;
  size_t cstr, jstr;
  if (w < 2) {
    gp = khg + ((size_t)b * KVPAD + c0 * 8 + sr) * INNER + h * 64 + sc * 8;
    lp = (u32*)Kh_s + c0 * 256;
    cstr = (size_t)8 * INNER;
    jstr = (size_t)64 * INNER;
  } else {
    gp = vtg_h + ((size_t)b * INNER + h * 64 + c0 * 8 + sr) * KVPAD + sc * 8;
    lp = (u32*)Vh_s + c0 * 256;
    cstr = (size_t)8 * KVPAD;
    jstr = 64;
  }

  f32x4 O[4] = {{0.f,0.f,0.f,0.f},{0.f,0.f,0.f,0.f},{0.f,0.f,0.f,0.f},{0.f,0.f,0.f,0.f}};
  float lpart[4];
#pragma unroll
  for (int r = 0; r < 4; ++r) lpart[r] = 0.f;

  for (int tile = 0; tile < NT_J; ++tile) {
    const int j0 = tile * 64;
    __syncthreads();                       // prior tile fully consumed
#pragma unroll
    for (int c = 0; c < 4; ++c) gload16(gp + (size_t)c * cstr, lp + c * 256);
    gp += jstr;
    __syncthreads();                       // drain DMA (vmcnt(0) before barrier)

    // ---- QK^T (single-plane: 8 MFMA) ----
    f32x4 S[4];
    __builtin_amdgcn_s_setprio(1);
#pragma unroll
    for (int jt = 0; jt < 4; ++jt) {
      const int row = jt * 16 + m16;
      f32x4 acc = {0.f, 0.f, 0.f, 0.f};
#pragma unroll
      for (int ks = 0; ks < 2; ++ks) {
        const int cc = row * 64 + (((ks * 4 + quad) ^ (row & 7)) << 3);
        bf16x8 kh = *(const bf16x8*)&Kh_s[cc];
        acc = __builtin_amdgcn_mfma_f32_16x16x32_bf16(qh[ks], kh, acc, 0, 0, 0);
      }
      S[jt] = acc;
    }
    __builtin_amdgcn_s_setprio(0);

    // mask tail columns (also covers K pad-row garbage); exp2(-inf) = 0 exactly
#pragma unroll
    for (int jt = 0; jt < 4; ++jt) {
      int jc = j0 + jt * 16 + m16;
      if (jc >= JTOT)
#pragma unroll
        for (int r = 0; r < 4; ++r) S[jt][r] = -INFINITY;
    }

    // ---- fixed-max softmax: p = 2^(S-8); accumulate per-lane l partials ----
    float pj[4][4];
#pragma unroll
    for (int jt = 0; jt < 4; ++jt)
#pragma unroll
      for (int r = 0; r < 4; ++r) {
        float pv = __builtin_amdgcn_exp2f(S[jt][r] - 8.f);
        pj[jt][r] = pv;
        lpart[r] += pv;
      }

    // ---- P -> LDS (single RNE bf16 plane; rows are wave-private: no barrier) ----
#pragma unroll
    for (int jt = 0; jt < 4; ++jt)
#pragma unroll
      for (int r = 0; r < 4; ++r) {
        int pq = (w * 16 + quad * 4 + r) * 72 + jt * 16 + m16;
        Ph_s[pq] = rnd_bf16(pj[jt][r]);
      }

    bf16x8 ph[2];
#pragma unroll
    for (int ks = 0; ks < 2; ++ks) {
      int po = (w * 16 + m16) * 72 + ks * 32 + quad * 8;
      ph[ks] = *(const bf16x8*)&Ph_s[po];
    }

    // ---- PV (single-plane: 8 MFMA) ----
    __builtin_amdgcn_s_setprio(1);
#pragma unroll
    for (int nt = 0; nt < 4; ++nt) {
      const int row = nt * 16 + m16;
#pragma unroll
      for (int ks = 0; ks < 2; ++ks) {
        const int cc = row * 64 + (((ks * 4 + quad) ^ (row & 7)) << 3);
        bf16x8 vh = *(const bf16x8*)&Vh_s[cc];
        O[nt] = __builtin_amdgcn_mfma_f32_16x16x32_bf16(ph[ks], vh, O[nt], 0, 0, 0);
      }
    }
    __builtin_amdgcn_s_setprio(0);
  }

  // deferred l reduction: sum per-lane partials across the 16 j-columns
  float inv[4];
#pragma unroll
  for (int r = 0; r < 4; ++r) {
    float rs = lpart[r];
    rs += dpp_f<0xB1>(rs);     // quad_perm xor1
    rs += dpp_f<0x4E>(rs);     // quad_perm xor2
    rs += dpp_f<0x124>(rs);    // row_ror:4
    rs += dpp_f<0x128>(rs);    // row_ror:8
    inv[r] = 1.f / rs;
  }
#pragma unroll
  for (int nt = 0; nt < 4; ++nt)
#pragma unroll
    for (int r = 0; r < 4; ++r) {
      size_t idx = ((size_t)(b * NN + qrow0 + w * 16 + quad * 4 + r)) * INNER +
                   h * 64 + nt * 16 + m16;
      u16 sh, sl;
      split2(O[nt][r] * inv[r], sh, sl);
      aoh[idx] = sh; aol[idx] = sl;
    }
}

// ---------------- launch ----------------
extern "C" void kernel_launch(void* const* d_in, const int* in_sizes, int n_in,
                              void* d_out, int out_size, void* d_ws, size_t ws_size,
                              hipStream_t stream) {
  const float* x        = (const float*)d_in[0];
  const float* context  = (const float*)d_in[1];
  const float* prompt   = (const float*)d_in[2];
  const float* w_prompt = (const float*)d_in[3];
  const float* w_img    = (const float*)d_in[4];
  const float* w_q      = (const float*)d_in[5];
  const float* w_k      = (const float*)d_in[6];
  const float* w_v      = (const float*)d_in[7];
  const float* w_out    = (const float*)d_in[8];
  const float* b_out    = (const float*)d_in[9];
  float* out = (float*)d_out;

  const int M = MTOT;             // 4096
  const int MJ = BB * JTOT;       // 4378

  u16* p = (u16*)d_ws;
  const size_t qN = (size_t)M * INNER;
  const size_t ctxN = (size_t)MJ * TCD;
  const size_t kN = (size_t)BB * KVPAD * INNER;  // K / V^T plane size
  u16* cth = p; p += ctxN;                          // ctx single RNE plane
  u16* aoh = p; p += qN;   u16* aol = p; p += qN;
  u16* xh  = p; p += (size_t)M * QD;   u16* xl  = p; p += (size_t)M * QD;
  u16* prh = p; p += (size_t)NUM_PROMPT * PD;
  u16* prl = p; p += (size_t)NUM_PROMPT * PD;
  u16* WtPh = p; p += (size_t)TCD * PD;            u16* WtPl = p; p += (size_t)TCD * PD;
  u16* WtAh = p; p += (size_t)(TCD + INNER) * QD;  u16* WtAl = p; p += (size_t)(TCD + INNER) * QD;
  u16* WtBh = p; p += (size_t)(2 * INNER) * TCD;   u16* WtBl = p; p += (size_t)(2 * INNER) * TCD;
  u16* WtOh = p; p += (size_t)QD * INNER;          u16* WtOl = p; p += (size_t)QD * INNER;
  u16* qhp = p; p += qN;                           // q single RNE plane (exp2 domain)
  u16* khp = p; p += kN;                           // K single RNE plane [B][KVPAD][INNER]
  u16* vthp = p; p += kN;                          // V^T single RNE plane [B][INNER][KVPAD]

  // ---- pack inputs + text ctx rows + V^T pad zero-fill (one launch) ----
  const int n4x = M * QD / 4, n4p = NUM_PROMPT * PD / 4;
  const int n4c = BB * CTX_LEN * TCD / 4;
  const int n4z = BB * INNER * 8;   // 8192 zero chunks of 16B
  pack_planes4<<<(n4x + n4p + n4c + n4z + 255) / 256, 256, 0, stream>>>(
      x, xh, xl, n4x, prompt, prh, prl, n4p, context, cth, n4c,
      vthp, n4z);

  // ---- transpose+pack all 6 weights (one launch) ----
  TP6 tp;
  const float* srcs[6] = {w_prompt, w_img, w_q, w_k, w_v, w_out};
  u16* dhs[6] = {WtPh, WtAh, WtAh + (size_t)TCD * QD, WtBh, WtBh + (size_t)INNER * TCD, WtOh};
  u16* dls[6] = {WtPl, WtAl, WtAl + (size_t)TCD * QD, WtBl, WtBl + (size_t)INNER * TCD, WtOl};
  int Ks[6] = {PD, QD, QD, TCD, TCD, INNER};
  int Ns[6] = {TCD, TCD, INNER, INNER, INNER, QD};
  int acc_blk = 0;
  for (int i = 0; i < 6; ++i) {
    tp.src[i] = srcs[i]; tp.dh[i] = dhs[i]; tp.dl[i] = dls[i];
    tp.K[i] = Ks[i]; tp.N[i] = Ns[i];
    tp.blk0[i] = acc_blk;
    acc_blk += (Ns[i] / 32) * (Ks[i] / 32);
  }
  tp.blk0[6] = acc_blk;
  transpose_pack6<<<acc_blk, 256, 0, stream>>>(tp);

  // ---- x @ [w_img | w_q] -> ctx plane (remap, RNE) + q plane (x SCALEL2, RNE);
  //      extra band: prompt @ w_prompt -> ctx rows 77..140 (both b) ----
  gemm_mfma<1><<<dim3((TCD + INNER) / 64, M / 128 + 1), 256, 0, stream>>>(
      xh, xl, WtAh, WtAl, cth, qhp, nullptr, nullptr,
      M, QD, TCD + INNER, prh, prl, WtPh, WtPl);
  // ---- ctx @ [w_k | w_v] (1-term single-plane) -> K plane + V^T plane ----
  gemm_mfma<2><<<dim3((2 * INNER) / 64, 2 * (KVPAD / 128)), 256, 0, stream>>>(
      cth, nullptr, WtBh, nullptr, khp, vthp, nullptr, nullptr,
      MJ, TCD, 2 * INNER, nullptr, nullptr, nullptr, nullptr);
  // ---- attention ----
  attn_mfma2<<<BB * HEADS * (NN / 64), 256, 0, stream>>>(
      qhp, khp, vthp, aoh, aol);
  // ---- out = ao @ w_out + b_out ----
  gemm_mfma<3><<<dim3(QD / 64, M / 128), 256, 0, stream>>>(
      aoh, aol, WtOh, WtOl, nullptr, nullptr, out, b_out,
      M, INNER, QD, nullptr, nullptr, nullptr, nullptr);
}

// Round 14
// 198.946 us; speedup vs baseline: 1.6656x; 1.1198x over previous
//
#include <hip/hip_runtime.h>
#include <hip/hip_bf16.h>
#include <math.h>

#define BB 2
#define NN 2048
#define QD 1024
#define CTX_LEN 77
#define TCD 768
#define NUM_PROMPT 64
#define PD 1024
#define HEADS 8
#define DIM_HEAD 64
#define INNER 512
#define JTOT (CTX_LEN + NUM_PROMPT + NN)   // 2189
#define SCALE 0.125f
#define SCALEL2 (0.125f * 1.44269504088896f)   // fold log2(e): softmax in exp2 domain
#define MTOT (BB * NN)                     // 4096
#define JPAD 2240                          // 35 * 64, attn j extent
#define KVPAD 2304                         // 18 * 128, K/V^T padded j extent (grid-friendly)
#define NT_J (JPAD / 64)                   // 35 j-tiles

typedef unsigned short u16;
typedef unsigned int u32;
typedef __attribute__((ext_vector_type(8))) short bf16x8;
typedef __attribute__((ext_vector_type(4))) float f32x4;

__device__ __forceinline__ u32 pack_split(float f) {   // interleaved: low16=hi, high16=lo
  u32 u = __builtin_bit_cast(u32, f);
  u32 hi = u & 0xffff0000u;
  float lo = f - __builtin_bit_cast(float, hi);
  u32 ul = __builtin_bit_cast(u32, lo);
  return __builtin_amdgcn_perm(ul, u, 0x07060302u);
}
__device__ __forceinline__ void split2(float f, u16& h, u16& l) {
  u32 u = __builtin_bit_cast(u32, f);
  u32 hm = u & 0xffff0000u;
  float lo = f - __builtin_bit_cast(float, hm);
  h = (u16)(u >> 16);
  l = (u16)(__builtin_bit_cast(u32, lo) >> 16);
}
__device__ __forceinline__ u16 rnd_bf16(float f) {   // RNE fp32 -> bf16
  u32 u = __builtin_bit_cast(u32, f);
  return (u16)((u + 0x7FFF + ((u >> 16) & 1)) >> 16);
}
__device__ __forceinline__ ushort4 pack4r(const float4& f) {   // RNE x4
  ushort4 r;
  r.x = rnd_bf16(f.x); r.y = rnd_bf16(f.y);
  r.z = rnd_bf16(f.z); r.w = rnd_bf16(f.w);
  return r;
}

// DPP lane move within 16-lane rows (ctrl must be ICE -> template)
template <int CTRL>
__device__ __forceinline__ float dpp_f(float x) {
  int i = __builtin_bit_cast(int, x);
  i = __builtin_amdgcn_update_dpp(0, i, CTRL, 0xF, 0xF, false);
  return __builtin_bit_cast(float, i);
}

// async global->LDS, 16B per lane; lds dest = base + lane*16
__device__ __forceinline__ void gload16(const u16* g, u32* l) {
  __builtin_amdgcn_global_load_lds(
      (const __attribute__((address_space(1))) u32*)(const void*)g,
      (__attribute__((address_space(3))) u32*)(void*)l, 16, 0, 0);
}

// ---------------- merged f32 -> plane pack: x (RNE), prompt (RNE), text-ctx (RNE), V^T pad-zero ----------------
__global__ __launch_bounds__(256) void pack_planes4(
    const float* __restrict__ s0, u16* __restrict__ d0, int n0,
    const float* __restrict__ s1, u16* __restrict__ d1, int n1,
    const float* __restrict__ ctx, u16* __restrict__ ch, int n2,
    u16* __restrict__ zh, int n3) {
  int i = blockIdx.x * 256 + threadIdx.x;
  if (i < n0) {
    ((ushort4*)d0)[i] = pack4r(((const float4*)s0)[i]);
    return;
  }
  i -= n0;
  if (i < n1) {
    ((ushort4*)d1)[i] = pack4r(((const float4*)s1)[i]);
    return;
  }
  i -= n1;
  if (i < n2) {
    // text context rows -> ctx plane (single RNE bf16) rows [b*JTOT + r], r < CTX_LEN
    ushort4 rr = pack4r(((const float4*)ctx)[i]);
    int c4 = i % (TCD / 4);
    int rb = i / (TCD / 4);
    int r = rb % CTX_LEN, b = rb / CTX_LEN;
    size_t o = ((size_t)b * JTOT + r) * (TCD / 4) + c4;   // ushort4 units
    ((ushort4*)ch)[o] = rr;
    return;
  }
  i -= n2;
  if (i >= n3) return;
  // zero-fill V^T j in [2176, 2240): 8 chunks of 8 u16 per (b,d) row
  int c = i & 7;
  int row = i >> 3;            // [b(2)][d(512)]
  int d = row & 511;
  int b = row >> 9;
  uint4 z = {0u, 0u, 0u, 0u};
  *(uint4*)&zh[((size_t)b * INNER + d) * KVPAD + 2176 + c * 8] = z;
}

// ---------------- merged weight transpose+pack: 6 sources, one launch ----------------
// dl[i] == nullptr: hi plane only (consumer is 1-term)
struct TP6 {
  const float* src[6];
  u16* dh[6];
  u16* dl[6];
  int K[6], N[6];
  int blk0[7];   // cumulative block offsets, blk0[6] = total blocks
};

__global__ __launch_bounds__(256) void transpose_pack6(TP6 P) {
  __shared__ u32 T[32][33];
  const int bid = blockIdx.x;
  int s = 0;
#pragma unroll
  for (int k = 1; k < 6; ++k) s += (bid >= P.blk0[k]);
  const int rel = bid - P.blk0[s];
  const int N = P.N[s], K = P.K[s];
  const int nbx = N >> 5;
  const int bx = rel % nbx, by = rel / nbx;
  const float* __restrict__ src = P.src[s];
  u16* __restrict__ dh = P.dh[s];
  u16* __restrict__ dl = P.dl[s];
  const int t = threadIdx.x;
  const int k0 = by * 32, n0 = bx * 32;
#pragma unroll
  for (int i = 0; i < 4; ++i) {
    int e = t + i * 256;
    int kr = e >> 5, nc = e & 31;
    T[kr][nc] = pack_split(src[(size_t)(k0 + kr) * N + n0 + nc]);
  }
  __syncthreads();
#pragma unroll
  for (int i = 0; i < 4; ++i) {
    int e = t + i * 256;
    int nr = e >> 5, kc = e & 31;
    u32 w = T[kc][nr];
    size_t idx = (size_t)(n0 + nr) * K + k0 + kc;
    // hi plane: RNE (1-term consumers); when lo kept, store truncated hi + lo (split)
    if (dl) {
      dh[idx] = (u16)(w & 0xffff);
      dl[idx] = (u16)(w >> 16);
    } else {
      dh[idx] = (u16)(w & 0xffff);   // pack_split low16 = truncated hi
    }
  }
}

// ---------------- split/plane bf16 MFMA GEMM, 128x64 tiles, BK=64, bijective XCD swizzle ----------------
// MODE 1 (1-term): gn<TCD -> ctx RNE plane (row remap); else q RNE plane (x SCALEL2).
//         Extra band bm>=MTOT: prompt@w_prompt -> ctx rows 77..140 (both b).
// MODE 2 (1-term): grid y = 36 (18/batch). gn<INNER -> K RNE plane [B][KVPAD][INNER];
//         else V^T RNE plane [B][INNER][KVPAD] via LDS transpose.
// MODE 3 (3-term split): f32 out + bias
template <int MODE>
__global__ __launch_bounds__(256) void gemm_mfma(
    const u16* __restrict__ Agh, const u16* __restrict__ Agl,
    const u16* __restrict__ Bgh, const u16* __restrict__ Bgl,
    u16* __restrict__ O1h,
    u16* __restrict__ O2h,
    float* __restrict__ Of, const float* __restrict__ bias,
    int M, int K, int Ntot,
    const u16* __restrict__ A2h, const u16* __restrict__ B2h) {
  constexpr bool ONET = (MODE == 1 || MODE == 2);   // single-term, single-plane operands
  constexpr int ALSZ = ONET ? 4 : 2 * 128 * 16;
  constexpr int BLSZ = ONET ? 4 : 2 * 64 * 16;
  __shared__ __align__(16) u32 Ah_s[2][128 * 16];
  __shared__ __align__(16) u32 Al_s[ALSZ];
  __shared__ __align__(16) u32 Bh_s[2][64 * 16];
  __shared__ __align__(16) u32 Bl_s[BLSZ];

  // bijective chunked XCD swizzle (m204): each XCD owns a contiguous grid chunk
  int bxi = blockIdx.x, byi = blockIdx.y;
  {
    const int GX = gridDim.x;
    const int nwg = GX * gridDim.y;
    const int lid = byi * GX + bxi;
    const int qq = nwg >> 3, rr = nwg & 7;
    const int xcd = lid & 7, pos = lid >> 3;
    const int swz = (xcd < rr ? xcd * (qq + 1) : rr * (qq + 1) + (xcd - rr) * qq) + pos;
    bxi = swz % GX; byi = swz / GX;
  }
  const int bm = byi * 128, bn = bxi * 64;

  const bool pband = (MODE == 1) && (bm >= MTOT);
  if (pband && bn >= TCD) return;   // block-uniform: idle prompt-band columns

  int b2 = 0, jbase = 0;
  if (MODE == 2) { b2 = (byi >= 18); jbase = (byi - b2 * 18) * 128; }

  const int t = threadIdx.x;
  const int w = t >> 6, lane = t & 63;
  const int m16 = lane & 15, quad = lane >> 4;
  const int wm = w >> 1, wn = w & 1;

  const u16* Abh = Agh; const u16* Abl = Agl;
  const u16* Bbh = Bgh; const u16* Bbl = Bgl;
  int rowlim = M - 1;
  int bmA = bm;
  if (pband) { Abh = A2h; Bbh = B2h; rowlim = NUM_PROMPT - 1; bmA = 0; }

  // DMA staging geometry: 4 lanes per 64B row, lane's 16B slot = (lane&3)*8 u16.
  // Wave w: A rows 32w..32w+31 (2 calls of 16 rows), B rows 16w..16w+15 (1 call).
  const int acol = (lane & 3) * 8;
  const int ar0 = 32 * w + (lane >> 2);
  const int ar1 = ar0 + 16;
  int ag0, ag1;
  if (MODE == 2) {
    ag0 = b2 * JTOT + min(jbase + ar0, JTOT - 1);   // clamp inside batch: no straddle
    ag1 = b2 * JTOT + min(jbase + ar1, JTOT - 1);
  } else {
    ag0 = min(bmA + ar0, rowlim);
    ag1 = min(bmA + ar1, rowlim);
  }
  const u16* a0h = Abh + (size_t)ag0 * K + acol;
  const u16* a1h = Abh + (size_t)ag1 * K + acol;
  const u16* a0l = ONET ? nullptr : Abl + (size_t)ag0 * K + acol;
  const u16* a1l = ONET ? nullptr : Abl + (size_t)ag1 * K + acol;
  const int br = 16 * w + (lane >> 2);
  const u16* b0h = Bbh + (size_t)(bn + br) * K + acol;
  const u16* b0l = ONET ? nullptr : Bbl + (size_t)(bn + br) * K + acol;

  f32x4 acc[4][2];
#pragma unroll
  for (int i = 0; i < 4; ++i)
#pragma unroll
    for (int j = 0; j < 2; ++j) acc[i][j] = (f32x4){0.f, 0.f, 0.f, 0.f};

  for (int k0 = 0; k0 < K; k0 += 64) {
    // ---- async stage both 32-col sub-tiles ----
#pragma unroll
    for (int s = 0; s < 2; ++s) {
      const int kc = k0 + s * 32;
      gload16(a0h + kc, &Ah_s[s][(2 * w) * 256]);
      gload16(a1h + kc, &Ah_s[s][(2 * w + 1) * 256]);
      gload16(b0h + kc, &Bh_s[s][w * 256]);
      if constexpr (!ONET) {
        gload16(a0l + kc, &Al_s[s * 2048 + (2 * w) * 256]);
        gload16(a1l + kc, &Al_s[s * 2048 + (2 * w + 1) * 256]);
        gload16(b0l + kc, &Bl_s[s * 1024 + w * 256]);
      }
    }
    __syncthreads();   // drains DMA (compiler emits vmcnt(0) before barrier)

#pragma unroll
    for (int s = 0; s < 2; ++s) {
      bf16x8 ah[4], al[4], bh[2], bl[2];
#pragma unroll
      for (int mt = 0; mt < 4; ++mt) {
        int off = (wm * 64 + mt * 16 + m16) * 16 + quad * 4;
        ah[mt] = *(const bf16x8*)&Ah_s[s][off];
        if constexpr (!ONET) al[mt] = *(const bf16x8*)&Al_s[s * 2048 + off];
      }
#pragma unroll
      for (int nt = 0; nt < 2; ++nt) {
        int off = (wn * 32 + nt * 16 + m16) * 16 + quad * 4;
        bh[nt] = *(const bf16x8*)&Bh_s[s][off];
        if constexpr (!ONET) bl[nt] = *(const bf16x8*)&Bl_s[s * 1024 + off];
      }
#pragma unroll
      for (int mt = 0; mt < 4; ++mt)
#pragma unroll
        for (int nt = 0; nt < 2; ++nt) {
          acc[mt][nt] = __builtin_amdgcn_mfma_f32_16x16x32_bf16(ah[mt], bh[nt], acc[mt][nt], 0, 0, 0);
          if constexpr (!ONET) {
            acc[mt][nt] = __builtin_amdgcn_mfma_f32_16x16x32_bf16(ah[mt], bl[nt], acc[mt][nt], 0, 0, 0);
            acc[mt][nt] = __builtin_amdgcn_mfma_f32_16x16x32_bf16(al[mt], bh[nt], acc[mt][nt], 0, 0, 0);
          }
        }
    }
    __syncthreads();   // frag reads done before next DMA overwrites
  }

  if (MODE == 2 && bn >= INNER) {
    // ---- V^T direct write, single RNE plane: LDS transpose + coalesced 16B stores ----
    u16* Th = (u16*)Ah_s;   // 16KB region: [64 d][128 j] u16, chunk-XOR layout
#pragma unroll
    for (int mt = 0; mt < 4; ++mt)
#pragma unroll
      for (int nt = 0; nt < 2; ++nt)
#pragma unroll
        for (int r = 0; r < 4; ++r) {
          int dl = wn * 32 + nt * 16 + m16;
          int jl = wm * 64 + mt * 16 + quad * 4 + r;
          int adr = dl * 128 + ((((jl >> 3) ^ (dl & 15)) << 3) | (jl & 7));
          Th[adr] = rnd_bf16(acc[mt][nt][r]);
        }
    __syncthreads();
#pragma unroll
    for (int i = 0; i < 4; ++i) {
      int chunk = t + i * 256;            // 1024 chunks = 64 d x 16 j-chunks
      int dl = chunk >> 4, jc = chunk & 15;
      int jg = jbase + jc * 8;
      int lofs = dl * 128 + ((jc ^ (dl & 15)) << 3);
      uint4 vh4 = *(const uint4*)&Th[lofs];
      size_t rowo = ((size_t)b2 * INNER + (bn - INNER) + dl) * KVPAD;
      if (jg + 8 <= JTOT) {
        *(uint4*)&O2h[rowo + jg] = vh4;
      } else if (jg < JTOT) {
        const u16* eh = (const u16*)&vh4;
#pragma unroll
        for (int e = 0; e < 8; ++e)
          if (jg + e < JTOT) O2h[rowo + jg + e] = eh[e];
      }   // jg >= JTOT: keep pre-zeroed pad
    }
    return;
  }

#pragma unroll
  for (int mt = 0; mt < 4; ++mt)
#pragma unroll
    for (int nt = 0; nt < 2; ++nt)
#pragma unroll
      for (int r = 0; r < 4; ++r) {
        int gm = bm + wm * 64 + mt * 16 + quad * 4 + r;
        int gn = bn + wn * 32 + nt * 16 + m16;
        float v = acc[mt][nt][r];
        if (MODE == 1) {
          if (pband) {
            int pr = wm * 64 + mt * 16 + quad * 4 + r;
            if (pr < NUM_PROMPT && gn < TCD) {
              u16 rv = rnd_bf16(v);
              O1h[((size_t)CTX_LEN + pr) * TCD + gn] = rv;           // b = 0
              O1h[((size_t)JTOT + CTX_LEN + pr) * TCD + gn] = rv;    // b = 1
            }
          } else if (gn < TCD) {
            size_t row = (size_t)(gm >> 11) * JTOT + 141 + (gm & 2047);
            O1h[row * TCD + gn] = rnd_bf16(v);
          } else {
            O2h[(size_t)gm * INNER + (gn - TCD)] = rnd_bf16(v * SCALEL2);
          }
        } else if (MODE == 2) {
          // K half: single RNE plane [B][KVPAD][INNER]; rows >= JTOT masked in attn
          int jloc = jbase + wm * 64 + mt * 16 + quad * 4 + r;
          O1h[((size_t)b2 * KVPAD + jloc) * INNER + gn] = rnd_bf16(v);
        } else if (MODE == 3) {
          Of[(size_t)gm * QD + gn] = v + bias[gn];
        }
      }
}

// ---------------- plane-format MFMA flash attention, fixed-max exp2 softmax ----------------
// K plane [B][KVPAD][INNER], V^T plane [B][INNER][KVPAD]; staged via global_load_lds
// with pre-swizzled source (XOR chunk swizzle) -> conflict-free ds_read_b128 fragments.
// Fixed-max: p = 2^(S-8). Exact power-of-2 rescale (cancels in O/l); logits ~N(0,1.2^2)
// over 2189 keys (max ~6) -> no overflow/denormals.
__global__ __launch_bounds__(256) void attn_mfma2(
    const u16* __restrict__ qhg,
    const u16* __restrict__ khg,
    const u16* __restrict__ vtg_h,
    u16* __restrict__ aoh, u16* __restrict__ aol) {
  __shared__ __align__(16) u16 Kh_s[64 * 64];
  __shared__ __align__(16) u16 Vh_s[64 * 64];
  __shared__ __align__(16) u16 Ph_s[64 * 72];

  const int t = threadIdx.x;
  const int w = t >> 6, lane = t & 63;
  const int m16 = lane & 15, quad = lane >> 4;

  // XCD swizzle: 512 blocks = 8 * 64; each XCD gets 2 contiguous (b,h) groups
  const int id = blockIdx.x;
  const int swz = (id & 7) * 64 + (id >> 3);
  const int qt = swz & 31, bh = swz >> 5;
  const int b = bh >> 3, h = bh & 7;
  const int qrow0 = qt * 64;

  // Q fragments direct from global plane (A-frag: row=m16, k=ks*32+quad*8)
  bf16x8 qh[2];
  {
    size_t qoff = ((size_t)(b * NN + qrow0 + w * 16 + m16)) * INNER + h * 64 + quad * 8;
#pragma unroll
    for (int ks = 0; ks < 2; ++ks)
      qh[ks] = *(const bf16x8*)(qhg + qoff + ks * 32);
  }

  // Staging: waves 0,1 -> K chunks 0-3/4-7; waves 2,3 -> V^T chunks 0-3/4-7.
  // Per chunk: 8 rows x 8 slots of 16B; dest linear, source slot = (lane&7)^(lane>>3)
  // so LDS (row, cc) holds logical chunk cc^(row&7)  (same layout as before).
  const int sr = lane >> 3;
  const int sc = (lane & 7) ^ sr;
  const int c0 = (w & 1) * 4;
  const u16* gp;
  u32* lp;
  size_t cstr, jstr;
  if (w < 2) {
    gp = khg + ((size_t)b * KVPAD + c0 * 8 + sr) * INNER + h * 64 + sc * 8;
    lp = (u32*)Kh_s + c0 * 256;
    cstr = (size_t)8 * INNER;
    jstr = (size_t)64 * INNER;
  } else {
    gp = vtg_h + ((size_t)b * INNER + h * 64 + c0 * 8 + sr) * KVPAD + sc * 8;
    lp = (u32*)Vh_s + c0 * 256;
    cstr = (size_t)8 * KVPAD;
    jstr = 64;
  }

  f32x4 O[4] = {{0.f,0.f,0.f,0.f},{0.f,0.f,0.f,0.f},{0.f,0.f,0.f,0.f},{0.f,0.f,0.f,0.f}};
  float lpart[4];
#pragma unroll
  for (int r = 0; r < 4; ++r) lpart[r] = 0.f;

  for (int tile = 0; tile < NT_J; ++tile) {
    const int j0 = tile * 64;
    __syncthreads();                       // prior tile fully consumed
#pragma unroll
    for (int c = 0; c < 4; ++c) gload16(gp + (size_t)c * cstr, lp + c * 256);
    gp += jstr;
    __syncthreads();                       // drain DMA (vmcnt(0) before barrier)

    // ---- QK^T (single-plane: 8 MFMA) ----
    f32x4 S[4];
    __builtin_amdgcn_s_setprio(1);
#pragma unroll
    for (int jt = 0; jt < 4; ++jt) {
      const int row = jt * 16 + m16;
      f32x4 acc = {0.f, 0.f, 0.f, 0.f};
#pragma unroll
      for (int ks = 0; ks < 2; ++ks) {
        const int cc = row * 64 + (((ks * 4 + quad) ^ (row & 7)) << 3);
        bf16x8 kh = *(const bf16x8*)&Kh_s[cc];
        acc = __builtin_amdgcn_mfma_f32_16x16x32_bf16(qh[ks], kh, acc, 0, 0, 0);
      }
      S[jt] = acc;
    }
    __builtin_amdgcn_s_setprio(0);

    // mask tail columns (also covers K pad-row garbage); exp2(-inf) = 0 exactly
#pragma unroll
    for (int jt = 0; jt < 4; ++jt) {
      int jc = j0 + jt * 16 + m16;
      if (jc >= JTOT)
#pragma unroll
        for (int r = 0; r < 4; ++r) S[jt][r] = -INFINITY;
    }

    // ---- fixed-max softmax: p = 2^(S-8); accumulate per-lane l partials ----
    float pj[4][4];
#pragma unroll
    for (int jt = 0; jt < 4; ++jt)
#pragma unroll
      for (int r = 0; r < 4; ++r) {
        float pv = __builtin_amdgcn_exp2f(S[jt][r] - 8.f);
        pj[jt][r] = pv;
        lpart[r] += pv;
      }

    // ---- P -> LDS (single RNE bf16 plane; rows are wave-private: no barrier) ----
#pragma unroll
    for (int jt = 0; jt < 4; ++jt)
#pragma unroll
      for (int r = 0; r < 4; ++r) {
        int pq = (w * 16 + quad * 4 + r) * 72 + jt * 16 + m16;
        Ph_s[pq] = rnd_bf16(pj[jt][r]);
      }

    bf16x8 ph[2];
#pragma unroll
    for (int ks = 0; ks < 2; ++ks) {
      int po = (w * 16 + m16) * 72 + ks * 32 + quad * 8;
      ph[ks] = *(const bf16x8*)&Ph_s[po];
    }

    // ---- PV (single-plane: 8 MFMA) ----
    __builtin_amdgcn_s_setprio(1);
#pragma unroll
    for (int nt = 0; nt < 4; ++nt) {
      const int row = nt * 16 + m16;
#pragma unroll
      for (int ks = 0; ks < 2; ++ks) {
        const int cc = row * 64 + (((ks * 4 + quad) ^ (row & 7)) << 3);
        bf16x8 vh = *(const bf16x8*)&Vh_s[cc];
        O[nt] = __builtin_amdgcn_mfma_f32_16x16x32_bf16(ph[ks], vh, O[nt], 0, 0, 0);
      }
    }
    __builtin_amdgcn_s_setprio(0);
  }

  // deferred l reduction: sum per-lane partials across the 16 j-columns
  float inv[4];
#pragma unroll
  for (int r = 0; r < 4; ++r) {
    float rs = lpart[r];
    rs += dpp_f<0xB1>(rs);     // quad_perm xor1
    rs += dpp_f<0x4E>(rs);     // quad_perm xor2
    rs += dpp_f<0x124>(rs);    // row_ror:4
    rs += dpp_f<0x128>(rs);    // row_ror:8
    inv[r] = 1.f / rs;
  }
#pragma unroll
  for (int nt = 0; nt < 4; ++nt)
#pragma unroll
    for (int r = 0; r < 4; ++r) {
      size_t idx = ((size_t)(b * NN + qrow0 + w * 16 + quad * 4 + r)) * INNER +
                   h * 64 + nt * 16 + m16;
      u16 sh, sl;
      split2(O[nt][r] * inv[r], sh, sl);
      aoh[idx] = sh; aol[idx] = sl;
    }
}

// ---------------- launch ----------------
extern "C" void kernel_launch(void* const* d_in, const int* in_sizes, int n_in,
                              void* d_out, int out_size, void* d_ws, size_t ws_size,
                              hipStream_t stream) {
  const float* x        = (const float*)d_in[0];
  const float* context  = (const float*)d_in[1];
  const float* prompt   = (const float*)d_in[2];
  const float* w_prompt = (const float*)d_in[3];
  const float* w_img    = (const float*)d_in[4];
  const float* w_q      = (const float*)d_in[5];
  const float* w_k      = (const float*)d_in[6];
  const float* w_v      = (const float*)d_in[7];
  const float* w_out    = (const float*)d_in[8];
  const float* b_out    = (const float*)d_in[9];
  float* out = (float*)d_out;

  const int M = MTOT;             // 4096
  const int MJ = BB * JTOT;       // 4378

  u16* p = (u16*)d_ws;
  const size_t qN = (size_t)M * INNER;
  const size_t ctxN = (size_t)MJ * TCD;
  const size_t kN = (size_t)BB * KVPAD * INNER;  // K / V^T plane size
  u16* cth = p; p += ctxN;                          // ctx single RNE plane
  u16* aoh = p; p += qN;   u16* aol = p; p += qN;
  u16* xh  = p; p += (size_t)M * QD;                // x single RNE plane
  u16* prh = p; p += (size_t)NUM_PROMPT * PD;       // prompt single RNE plane
  u16* WtPh = p; p += (size_t)TCD * PD;
  u16* WtAh = p; p += (size_t)(TCD + INNER) * QD;
  u16* WtBh = p; p += (size_t)(2 * INNER) * TCD;
  u16* WtOh = p; p += (size_t)QD * INNER;          u16* WtOl = p; p += (size_t)QD * INNER;
  u16* qhp = p; p += qN;                           // q single RNE plane (exp2 domain)
  u16* khp = p; p += kN;                           // K single RNE plane [B][KVPAD][INNER]
  u16* vthp = p; p += kN;                          // V^T single RNE plane [B][INNER][KVPAD]

  // ---- pack inputs + text ctx rows + V^T pad zero-fill (one launch) ----
  const int n4x = M * QD / 4, n4p = NUM_PROMPT * PD / 4;
  const int n4c = BB * CTX_LEN * TCD / 4;
  const int n4z = BB * INNER * 8;   // 8192 zero chunks of 16B
  pack_planes4<<<(n4x + n4p + n4c + n4z + 255) / 256, 256, 0, stream>>>(
      x, xh, n4x, prompt, prh, n4p, context, cth, n4c, vthp, n4z);

  // ---- transpose+pack all 6 weights (one launch); lo plane only for w_out ----
  TP6 tp;
  const float* srcs[6] = {w_prompt, w_img, w_q, w_k, w_v, w_out};
  u16* dhs[6] = {WtPh, WtAh, WtAh + (size_t)TCD * QD, WtBh, WtBh + (size_t)INNER * TCD, WtOh};
  u16* dls[6] = {nullptr, nullptr, nullptr, nullptr, nullptr, WtOl};
  int Ks[6] = {PD, QD, QD, TCD, TCD, INNER};
  int Ns[6] = {TCD, TCD, INNER, INNER, INNER, QD};
  int acc_blk = 0;
  for (int i = 0; i < 6; ++i) {
    tp.src[i] = srcs[i]; tp.dh[i] = dhs[i]; tp.dl[i] = dls[i];
    tp.K[i] = Ks[i]; tp.N[i] = Ns[i];
    tp.blk0[i] = acc_blk;
    acc_blk += (Ns[i] / 32) * (Ks[i] / 32);
  }
  tp.blk0[6] = acc_blk;
  transpose_pack6<<<acc_blk, 256, 0, stream>>>(tp);

  // ---- x @ [w_img | w_q] (1-term) -> ctx plane (remap, RNE) + q plane (x SCALEL2, RNE);
  //      extra band: prompt @ w_prompt -> ctx rows 77..140 (both b) ----
  gemm_mfma<1><<<dim3((TCD + INNER) / 64, M / 128 + 1), 256, 0, stream>>>(
      xh, nullptr, WtAh, nullptr, cth, qhp, nullptr, nullptr,
      M, QD, TCD + INNER, prh, WtPh);
  // ---- ctx @ [w_k | w_v] (1-term) -> K plane + V^T plane ----
  gemm_mfma<2><<<dim3((2 * INNER) / 64, 2 * (KVPAD / 128)), 256, 0, stream>>>(
      cth, nullptr, WtBh, nullptr, khp, vthp, nullptr, nullptr,
      MJ, TCD, 2 * INNER, nullptr, nullptr);
  // ---- attention ----
  attn_mfma2<<<BB * HEADS * (NN / 64), 256, 0, stream>>>(
      qhp, khp, vthp, aoh, aol);
  // ---- out = ao @ w_out + b_out (3-term, full accuracy) ----
  gemm_mfma<3><<<dim3(QD / 64, M / 128), 256, 0, stream>>>(
      aoh, aol, WtOh, WtOl, nullptr, nullptr, out, b_out,
      M, INNER, QD, nullptr, nullptr);
}

// Round 15
// 195.794 us; speedup vs baseline: 1.6925x; 1.0161x over previous
//
#include <hip/hip_runtime.h>
#include <hip/hip_bf16.h>
#include <math.h>

#define BB 2
#define NN 2048
#define QD 1024
#define CTX_LEN 77
#define TCD 768
#define NUM_PROMPT 64
#define PD 1024
#define HEADS 8
#define DIM_HEAD 64
#define INNER 512
#define JTOT (CTX_LEN + NUM_PROMPT + NN)   // 2189
#define SCALE 0.125f
#define SCALEL2 (0.125f * 1.44269504088896f)   // fold log2(e): softmax in exp2 domain
#define MTOT (BB * NN)                     // 4096
#define JPAD 2240                          // 35 * 64, attn j extent
#define KVPAD 2304                         // 18 * 128, K/V^T padded j extent (1 spare tile)
#define NT_J (JPAD / 64)                   // 35 j-tiles

typedef unsigned short u16;
typedef unsigned int u32;
typedef __attribute__((ext_vector_type(8))) short bf16x8;
typedef __attribute__((ext_vector_type(4))) float f32x4;

__device__ __forceinline__ u32 pack_split(float f) {   // interleaved: low16=hi, high16=lo
  u32 u = __builtin_bit_cast(u32, f);
  u32 hi = u & 0xffff0000u;
  float lo = f - __builtin_bit_cast(float, hi);
  u32 ul = __builtin_bit_cast(u32, lo);
  return __builtin_amdgcn_perm(ul, u, 0x07060302u);
}
__device__ __forceinline__ void split2(float f, u16& h, u16& l) {
  u32 u = __builtin_bit_cast(u32, f);
  u32 hm = u & 0xffff0000u;
  float lo = f - __builtin_bit_cast(float, hm);
  h = (u16)(u >> 16);
  l = (u16)(__builtin_bit_cast(u32, lo) >> 16);
}
__device__ __forceinline__ u16 rnd_bf16(float f) {   // RNE fp32 -> bf16
  u32 u = __builtin_bit_cast(u32, f);
  return (u16)((u + 0x7FFF + ((u >> 16) & 1)) >> 16);
}
__device__ __forceinline__ ushort4 pack4r(const float4& f) {   // RNE x4
  ushort4 r;
  r.x = rnd_bf16(f.x); r.y = rnd_bf16(f.y);
  r.z = rnd_bf16(f.z); r.w = rnd_bf16(f.w);
  return r;
}

// DPP lane move within 16-lane rows (ctrl must be ICE -> template)
template <int CTRL>
__device__ __forceinline__ float dpp_f(float x) {
  int i = __builtin_bit_cast(int, x);
  i = __builtin_amdgcn_update_dpp(0, i, CTRL, 0xF, 0xF, false);
  return __builtin_bit_cast(float, i);
}

// async global->LDS, 16B per lane; lds dest = base + lane*16
__device__ __forceinline__ void gload16(const u16* g, u32* l) {
  __builtin_amdgcn_global_load_lds(
      (const __attribute__((address_space(1))) u32*)(const void*)g,
      (__attribute__((address_space(3))) u32*)(void*)l, 16, 0, 0);
}

// ---------------- merged f32 -> plane pack: x (RNE), prompt (RNE), text-ctx (RNE), V^T pad-zero ----------------
__global__ __launch_bounds__(256) void pack_planes4(
    const float* __restrict__ s0, u16* __restrict__ d0, int n0,
    const float* __restrict__ s1, u16* __restrict__ d1, int n1,
    const float* __restrict__ ctx, u16* __restrict__ ch, int n2,
    u16* __restrict__ zh, int n3) {
  int i = blockIdx.x * 256 + threadIdx.x;
  if (i < n0) {
    ((ushort4*)d0)[i] = pack4r(((const float4*)s0)[i]);
    return;
  }
  i -= n0;
  if (i < n1) {
    ((ushort4*)d1)[i] = pack4r(((const float4*)s1)[i]);
    return;
  }
  i -= n1;
  if (i < n2) {
    // text context rows -> ctx plane (single RNE bf16) rows [b*JTOT + r], r < CTX_LEN
    ushort4 rr = pack4r(((const float4*)ctx)[i]);
    int c4 = i % (TCD / 4);
    int rb = i / (TCD / 4);
    int r = rb % CTX_LEN, b = rb / CTX_LEN;
    size_t o = ((size_t)b * JTOT + r) * (TCD / 4) + c4;   // ushort4 units
    ((ushort4*)ch)[o] = rr;
    return;
  }
  i -= n2;
  if (i >= n3) return;
  // zero-fill V^T j in [2176, 2240): 8 chunks of 8 u16 per (b,d) row
  int c = i & 7;
  int row = i >> 3;            // [b(2)][d(512)]
  int d = row & 511;
  int b = row >> 9;
  uint4 z = {0u, 0u, 0u, 0u};
  *(uint4*)&zh[((size_t)b * INNER + d) * KVPAD + 2176 + c * 8] = z;
}

// ---------------- merged weight transpose+pack: 6 sources, one launch ----------------
// dl[i] == nullptr: hi plane only (consumer is 1-term)
struct TP6 {
  const float* src[6];
  u16* dh[6];
  u16* dl[6];
  int K[6], N[6];
  int blk0[7];   // cumulative block offsets, blk0[6] = total blocks
};

__global__ __launch_bounds__(256) void transpose_pack6(TP6 P) {
  __shared__ u32 T[32][33];
  const int bid = blockIdx.x;
  int s = 0;
#pragma unroll
  for (int k = 1; k < 6; ++k) s += (bid >= P.blk0[k]);
  const int rel = bid - P.blk0[s];
  const int N = P.N[s], K = P.K[s];
  const int nbx = N >> 5;
  const int bx = rel % nbx, by = rel / nbx;
  const float* __restrict__ src = P.src[s];
  u16* __restrict__ dh = P.dh[s];
  u16* __restrict__ dl = P.dl[s];
  const int t = threadIdx.x;
  const int k0 = by * 32, n0 = bx * 32;
#pragma unroll
  for (int i = 0; i < 4; ++i) {
    int e = t + i * 256;
    int kr = e >> 5, nc = e & 31;
    T[kr][nc] = pack_split(src[(size_t)(k0 + kr) * N + n0 + nc]);
  }
  __syncthreads();
#pragma unroll
  for (int i = 0; i < 4; ++i) {
    int e = t + i * 256;
    int nr = e >> 5, kc = e & 31;
    u32 w = T[kc][nr];
    size_t idx = (size_t)(n0 + nr) * K + k0 + kc;
    // hi plane: RNE (1-term consumers); when lo kept, store truncated hi + lo (split)
    if (dl) {
      dh[idx] = (u16)(w & 0xffff);
      dl[idx] = (u16)(w >> 16);
    } else {
      dh[idx] = (u16)(w & 0xffff);   // pack_split low16 = truncated hi
    }
  }
}

// ---------------- split/plane bf16 MFMA GEMM, 128x64 tiles, BK=64, bijective XCD swizzle ----------------
// MODE 1 (1-term): gn<TCD -> ctx RNE plane (row remap); else q RNE plane (x SCALEL2).
//         Extra band bm>=MTOT: prompt@w_prompt -> ctx rows 77..140 (both b).
// MODE 2 (1-term): grid y = 36 (18/batch). gn<INNER -> K RNE plane [B][KVPAD][INNER];
//         else V^T RNE plane [B][INNER][KVPAD] via LDS transpose.
// MODE 3 (3-term split): f32 out + bias
template <int MODE>
__global__ __launch_bounds__(256) void gemm_mfma(
    const u16* __restrict__ Agh, const u16* __restrict__ Agl,
    const u16* __restrict__ Bgh, const u16* __restrict__ Bgl,
    u16* __restrict__ O1h,
    u16* __restrict__ O2h,
    float* __restrict__ Of, const float* __restrict__ bias,
    int M, int K, int Ntot,
    const u16* __restrict__ A2h, const u16* __restrict__ B2h) {
  constexpr bool ONET = (MODE == 1 || MODE == 2);   // single-term, single-plane operands
  constexpr int ALSZ = ONET ? 4 : 2 * 128 * 16;
  constexpr int BLSZ = ONET ? 4 : 2 * 64 * 16;
  __shared__ __align__(16) u32 Ah_s[2][128 * 16];
  __shared__ __align__(16) u32 Al_s[ALSZ];
  __shared__ __align__(16) u32 Bh_s[2][64 * 16];
  __shared__ __align__(16) u32 Bl_s[BLSZ];

  // bijective chunked XCD swizzle (m204): each XCD owns a contiguous grid chunk
  int bxi = blockIdx.x, byi = blockIdx.y;
  {
    const int GX = gridDim.x;
    const int nwg = GX * gridDim.y;
    const int lid = byi * GX + bxi;
    const int qq = nwg >> 3, rr = nwg & 7;
    const int xcd = lid & 7, pos = lid >> 3;
    const int swz = (xcd < rr ? xcd * (qq + 1) : rr * (qq + 1) + (xcd - rr) * qq) + pos;
    bxi = swz % GX; byi = swz / GX;
  }
  const int bm = byi * 128, bn = bxi * 64;

  const bool pband = (MODE == 1) && (bm >= MTOT);
  if (pband && bn >= TCD) return;   // block-uniform: idle prompt-band columns

  int b2 = 0, jbase = 0;
  if (MODE == 2) { b2 = (byi >= 18); jbase = (byi - b2 * 18) * 128; }

  const int t = threadIdx.x;
  const int w = t >> 6, lane = t & 63;
  const int m16 = lane & 15, quad = lane >> 4;
  const int wm = w >> 1, wn = w & 1;

  const u16* Abh = Agh; const u16* Abl = Agl;
  const u16* Bbh = Bgh; const u16* Bbl = Bgl;
  int rowlim = M - 1;
  int bmA = bm;
  if (pband) { Abh = A2h; Bbh = B2h; rowlim = NUM_PROMPT - 1; bmA = 0; }

  // DMA staging geometry: 4 lanes per 64B row, lane's 16B slot = (lane&3)*8 u16.
  // Wave w: A rows 32w..32w+31 (2 calls of 16 rows), B rows 16w..16w+15 (1 call).
  const int acol = (lane & 3) * 8;
  const int ar0 = 32 * w + (lane >> 2);
  const int ar1 = ar0 + 16;
  int ag0, ag1;
  if (MODE == 2) {
    ag0 = b2 * JTOT + min(jbase + ar0, JTOT - 1);   // clamp inside batch: no straddle
    ag1 = b2 * JTOT + min(jbase + ar1, JTOT - 1);
  } else {
    ag0 = min(bmA + ar0, rowlim);
    ag1 = min(bmA + ar1, rowlim);
  }
  const u16* a0h = Abh + (size_t)ag0 * K + acol;
  const u16* a1h = Abh + (size_t)ag1 * K + acol;
  const u16* a0l = ONET ? nullptr : Abl + (size_t)ag0 * K + acol;
  const u16* a1l = ONET ? nullptr : Abl + (size_t)ag1 * K + acol;
  const int br = 16 * w + (lane >> 2);
  const u16* b0h = Bbh + (size_t)(bn + br) * K + acol;
  const u16* b0l = ONET ? nullptr : Bbl + (size_t)(bn + br) * K + acol;

  f32x4 acc[4][2];
#pragma unroll
  for (int i = 0; i < 4; ++i)
#pragma unroll
    for (int j = 0; j < 2; ++j) acc[i][j] = (f32x4){0.f, 0.f, 0.f, 0.f};

  for (int k0 = 0; k0 < K; k0 += 64) {
    // ---- async stage both 32-col sub-tiles ----
#pragma unroll
    for (int s = 0; s < 2; ++s) {
      const int kc = k0 + s * 32;
      gload16(a0h + kc, &Ah_s[s][(2 * w) * 256]);
      gload16(a1h + kc, &Ah_s[s][(2 * w + 1) * 256]);
      gload16(b0h + kc, &Bh_s[s][w * 256]);
      if constexpr (!ONET) {
        gload16(a0l + kc, &Al_s[s * 2048 + (2 * w) * 256]);
        gload16(a1l + kc, &Al_s[s * 2048 + (2 * w + 1) * 256]);
        gload16(b0l + kc, &Bl_s[s * 1024 + w * 256]);
      }
    }
    __syncthreads();   // drains DMA (compiler emits vmcnt(0) before barrier)

#pragma unroll
    for (int s = 0; s < 2; ++s) {
      bf16x8 ah[4], al[4], bh[2], bl[2];
#pragma unroll
      for (int mt = 0; mt < 4; ++mt) {
        int off = (wm * 64 + mt * 16 + m16) * 16 + quad * 4;
        ah[mt] = *(const bf16x8*)&Ah_s[s][off];
        if constexpr (!ONET) al[mt] = *(const bf16x8*)&Al_s[s * 2048 + off];
      }
#pragma unroll
      for (int nt = 0; nt < 2; ++nt) {
        int off = (wn * 32 + nt * 16 + m16) * 16 + quad * 4;
        bh[nt] = *(const bf16x8*)&Bh_s[s][off];
        if constexpr (!ONET) bl[nt] = *(const bf16x8*)&Bl_s[s * 1024 + off];
      }
#pragma unroll
      for (int mt = 0; mt < 4; ++mt)
#pragma unroll
        for (int nt = 0; nt < 2; ++nt) {
          acc[mt][nt] = __builtin_amdgcn_mfma_f32_16x16x32_bf16(ah[mt], bh[nt], acc[mt][nt], 0, 0, 0);
          if constexpr (!ONET) {
            acc[mt][nt] = __builtin_amdgcn_mfma_f32_16x16x32_bf16(ah[mt], bl[nt], acc[mt][nt], 0, 0, 0);
            acc[mt][nt] = __builtin_amdgcn_mfma_f32_16x16x32_bf16(al[mt], bh[nt], acc[mt][nt], 0, 0, 0);
          }
        }
    }
    __syncthreads();   // frag reads done before next DMA overwrites
  }

  if (MODE == 2 && bn >= INNER) {
    // ---- V^T direct write, single RNE plane: LDS transpose + coalesced 16B stores ----
    u16* Th = (u16*)Ah_s;   // 16KB region: [64 d][128 j] u16, chunk-XOR layout
#pragma unroll
    for (int mt = 0; mt < 4; ++mt)
#pragma unroll
      for (int nt = 0; nt < 2; ++nt)
#pragma unroll
        for (int r = 0; r < 4; ++r) {
          int dl = wn * 32 + nt * 16 + m16;
          int jl = wm * 64 + mt * 16 + quad * 4 + r;
          int adr = dl * 128 + ((((jl >> 3) ^ (dl & 15)) << 3) | (jl & 7));
          Th[adr] = rnd_bf16(acc[mt][nt][r]);
        }
    __syncthreads();
#pragma unroll
    for (int i = 0; i < 4; ++i) {
      int chunk = t + i * 256;            // 1024 chunks = 64 d x 16 j-chunks
      int dl = chunk >> 4, jc = chunk & 15;
      int jg = jbase + jc * 8;
      int lofs = dl * 128 + ((jc ^ (dl & 15)) << 3);
      uint4 vh4 = *(const uint4*)&Th[lofs];
      size_t rowo = ((size_t)b2 * INNER + (bn - INNER) + dl) * KVPAD;
      if (jg + 8 <= JTOT) {
        *(uint4*)&O2h[rowo + jg] = vh4;
      } else if (jg < JTOT) {
        const u16* eh = (const u16*)&vh4;
#pragma unroll
        for (int e = 0; e < 8; ++e)
          if (jg + e < JTOT) O2h[rowo + jg + e] = eh[e];
      }   // jg >= JTOT: keep pre-zeroed pad
    }
    return;
  }

#pragma unroll
  for (int mt = 0; mt < 4; ++mt)
#pragma unroll
    for (int nt = 0; nt < 2; ++nt)
#pragma unroll
      for (int r = 0; r < 4; ++r) {
        int gm = bm + wm * 64 + mt * 16 + quad * 4 + r;
        int gn = bn + wn * 32 + nt * 16 + m16;
        float v = acc[mt][nt][r];
        if (MODE == 1) {
          if (pband) {
            int pr = wm * 64 + mt * 16 + quad * 4 + r;
            if (pr < NUM_PROMPT && gn < TCD) {
              u16 rv = rnd_bf16(v);
              O1h[((size_t)CTX_LEN + pr) * TCD + gn] = rv;           // b = 0
              O1h[((size_t)JTOT + CTX_LEN + pr) * TCD + gn] = rv;    // b = 1
            }
          } else if (gn < TCD) {
            size_t row = (size_t)(gm >> 11) * JTOT + 141 + (gm & 2047);
            O1h[row * TCD + gn] = rnd_bf16(v);
          } else {
            O2h[(size_t)gm * INNER + (gn - TCD)] = rnd_bf16(v * SCALEL2);
          }
        } else if (MODE == 2) {
          // K half: single RNE plane [B][KVPAD][INNER]; rows >= JTOT masked in attn
          int jloc = jbase + wm * 64 + mt * 16 + quad * 4 + r;
          O1h[((size_t)b2 * KVPAD + jloc) * INNER + gn] = rnd_bf16(v);
        } else if (MODE == 3) {
          Of[(size_t)gm * QD + gn] = v + bias[gn];
        }
      }
}

// ---------------- plane-format MFMA flash attention, fixed-max exp2 softmax ----------------
// K plane [B][KVPAD][INNER], V^T plane [B][INNER][KVPAD]; K/V double-buffered in LDS
// with counted vmcnt(4): tile t+1's 4 loads/wave issued before tile t's wait, so the
// prefetch hides under compute (2 barriers/tile, same count as the drain version).
// KVPAD has one spare 64-row tile -> unconditional t+1 prefetch stays in-bounds.
// Fixed-max: p = 2^(S-8) (exact power-of-2 rescale, cancels in O/l).
__global__ __launch_bounds__(256) void attn_mfma2(
    const u16* __restrict__ qhg,
    const u16* __restrict__ khg,
    const u16* __restrict__ vtg_h,
    u16* __restrict__ aoh, u16* __restrict__ aol) {
  __shared__ __align__(16) u16 Kh_s[2][64 * 64];
  __shared__ __align__(16) u16 Vh_s[2][64 * 64];
  __shared__ __align__(16) u16 Ph_s[64 * 72];

  const int t = threadIdx.x;
  const int w = t >> 6, lane = t & 63;
  const int m16 = lane & 15, quad = lane >> 4;

  // XCD swizzle: 512 blocks = 8 * 64; each XCD gets 2 contiguous (b,h) groups
  const int id = blockIdx.x;
  const int swz = (id & 7) * 64 + (id >> 3);
  const int qt = swz & 31, bh = swz >> 5;
  const int b = bh >> 3, h = bh & 7;
  const int qrow0 = qt * 64;

  // Q fragments direct from global plane (A-frag: row=m16, k=ks*32+quad*8)
  bf16x8 qh[2];
  {
    size_t qoff = ((size_t)(b * NN + qrow0 + w * 16 + m16)) * INNER + h * 64 + quad * 8;
#pragma unroll
    for (int ks = 0; ks < 2; ++ks)
      qh[ks] = *(const bf16x8*)(qhg + qoff + ks * 32);
  }

  // Staging: waves 0,1 -> K chunks 0-3/4-7; waves 2,3 -> V^T chunks 0-3/4-7.
  // Per chunk: 8 rows x 8 slots of 16B; dest linear, source slot = (lane&7)^(lane>>3)
  // so LDS (row, cc) holds logical chunk cc^(row&7). Buffer select: +cur*2048 u32.
  const int sr = lane >> 3;
  const int sc = (lane & 7) ^ sr;
  const int c0 = (w & 1) * 4;
  const u16* gp;
  u32* lp0;
  size_t cstr, jstr;
  if (w < 2) {
    gp = khg + ((size_t)b * KVPAD + c0 * 8 + sr) * INNER + h * 64 + sc * 8;
    lp0 = (u32*)Kh_s + c0 * 256;
    cstr = (size_t)8 * INNER;
    jstr = (size_t)64 * INNER;
  } else {
    gp = vtg_h + ((size_t)b * INNER + h * 64 + c0 * 8 + sr) * KVPAD + sc * 8;
    lp0 = (u32*)Vh_s + c0 * 256;
    cstr = (size_t)8 * KVPAD;
    jstr = 64;
  }

  f32x4 O[4] = {{0.f,0.f,0.f,0.f},{0.f,0.f,0.f,0.f},{0.f,0.f,0.f,0.f},{0.f,0.f,0.f,0.f}};
  float lpart[4];
#pragma unroll
  for (int r = 0; r < 4; ++r) lpart[r] = 0.f;

  // prologue: tile 0 into buffer 0
#pragma unroll
  for (int c = 0; c < 4; ++c) gload16(gp + (size_t)c * cstr, lp0 + c * 256);
  gp += jstr;

  for (int tile = 0; tile < NT_J; ++tile) {
    const int j0 = tile * 64;
    const int cur = tile & 1;
    // prefetch tile+1 into the other buffer (freed by the previous end-of-iter barrier)
    {
      u32* dst = lp0 + (cur ^ 1) * 2048;
#pragma unroll
      for (int c = 0; c < 4; ++c) gload16(gp + (size_t)c * cstr, dst + c * 256);
      gp += jstr;
    }
    // wait own tile-t loads (4 issued before the 4 prefetches; in-order retirement)
    asm volatile("s_waitcnt vmcnt(4)" ::: "memory");
    __builtin_amdgcn_s_barrier();          // tile t's K/V visible to all waves
    const u16* Kc = Kh_s[cur];
    const u16* Vc = Vh_s[cur];

    // ---- QK^T (single-plane: 8 MFMA) ----
    f32x4 S[4];
    __builtin_amdgcn_s_setprio(1);
#pragma unroll
    for (int jt = 0; jt < 4; ++jt) {
      const int row = jt * 16 + m16;
      f32x4 acc = {0.f, 0.f, 0.f, 0.f};
#pragma unroll
      for (int ks = 0; ks < 2; ++ks) {
        const int cc = row * 64 + (((ks * 4 + quad) ^ (row & 7)) << 3);
        bf16x8 kh = *(const bf16x8*)&Kc[cc];
        acc = __builtin_amdgcn_mfma_f32_16x16x32_bf16(qh[ks], kh, acc, 0, 0, 0);
      }
      S[jt] = acc;
    }
    __builtin_amdgcn_s_setprio(0);

    // mask tail columns (only last computed tile straddles JTOT); exp2(-inf) = 0
    if (j0 + 64 > JTOT) {
#pragma unroll
      for (int jt = 0; jt < 4; ++jt) {
        int jc = j0 + jt * 16 + m16;
        if (jc >= JTOT)
#pragma unroll
          for (int r = 0; r < 4; ++r) S[jt][r] = -INFINITY;
      }
    }

    // ---- fixed-max softmax: p = 2^(S-8); accumulate per-lane l partials ----
    float pj[4][4];
#pragma unroll
    for (int jt = 0; jt < 4; ++jt)
#pragma unroll
      for (int r = 0; r < 4; ++r) {
        float pv = __builtin_amdgcn_exp2f(S[jt][r] - 8.f);
        pj[jt][r] = pv;
        lpart[r] += pv;
      }

    // ---- P -> LDS (single RNE bf16 plane; rows are wave-private: no barrier) ----
#pragma unroll
    for (int jt = 0; jt < 4; ++jt)
#pragma unroll
      for (int r = 0; r < 4; ++r) {
        int pq = (w * 16 + quad * 4 + r) * 72 + jt * 16 + m16;
        Ph_s[pq] = rnd_bf16(pj[jt][r]);
      }

    bf16x8 ph[2];
#pragma unroll
    for (int ks = 0; ks < 2; ++ks) {
      int po = (w * 16 + m16) * 72 + ks * 32 + quad * 8;
      ph[ks] = *(const bf16x8*)&Ph_s[po];
    }

    // ---- PV (single-plane: 8 MFMA) ----
    __builtin_amdgcn_s_setprio(1);
#pragma unroll
    for (int nt = 0; nt < 4; ++nt) {
      const int row = nt * 16 + m16;
#pragma unroll
      for (int ks = 0; ks < 2; ++ks) {
        const int cc = row * 64 + (((ks * 4 + quad) ^ (row & 7)) << 3);
        bf16x8 vh = *(const bf16x8*)&Vc[cc];
        O[nt] = __builtin_amdgcn_mfma_f32_16x16x32_bf16(ph[ks], vh, O[nt], 0, 0, 0);
      }
    }
    __builtin_amdgcn_s_setprio(0);
    __builtin_amdgcn_s_barrier();          // all reads of buf[cur] done -> reusable
  }

  // drain the dangling final prefetch before the block can retire
  asm volatile("s_waitcnt vmcnt(0)" ::: "memory");

  // deferred l reduction: sum per-lane partials across the 16 j-columns
  float inv[4];
#pragma unroll
  for (int r = 0; r < 4; ++r) {
    float rs = lpart[r];
    rs += dpp_f<0xB1>(rs);     // quad_perm xor1
    rs += dpp_f<0x4E>(rs);     // quad_perm xor2
    rs += dpp_f<0x124>(rs);    // row_ror:4
    rs += dpp_f<0x128>(rs);    // row_ror:8
    inv[r] = 1.f / rs;
  }
#pragma unroll
  for (int nt = 0; nt < 4; ++nt)
#pragma unroll
    for (int r = 0; r < 4; ++r) {
      size_t idx = ((size_t)(b * NN + qrow0 + w * 16 + quad * 4 + r)) * INNER +
                   h * 64 + nt * 16 + m16;
      u16 sh, sl;
      split2(O[nt][r] * inv[r], sh, sl);
      aoh[idx] = sh; aol[idx] = sl;
    }
}

// ---------------- launch ----------------
extern "C" void kernel_launch(void* const* d_in, const int* in_sizes, int n_in,
                              void* d_out, int out_size, void* d_ws, size_t ws_size,
                              hipStream_t stream) {
  const float* x        = (const float*)d_in[0];
  const float* context  = (const float*)d_in[1];
  const float* prompt   = (const float*)d_in[2];
  const float* w_prompt = (const float*)d_in[3];
  const float* w_img    = (const float*)d_in[4];
  const float* w_q      = (const float*)d_in[5];
  const float* w_k      = (const float*)d_in[6];
  const float* w_v      = (const float*)d_in[7];
  const float* w_out    = (const float*)d_in[8];
  const float* b_out    = (const float*)d_in[9];
  float* out = (float*)d_out;

  const int M = MTOT;             // 4096
  const int MJ = BB * JTOT;       // 4378

  u16* p = (u16*)d_ws;
  const size_t qN = (size_t)M * INNER;
  const size_t ctxN = (size_t)MJ * TCD;
  const size_t kN = (size_t)BB * KVPAD * INNER;  // K / V^T plane size
  u16* cth = p; p += ctxN;                          // ctx single RNE plane
  u16* aoh = p; p += qN;   u16* aol = p; p += qN;
  u16* xh  = p; p += (size_t)M * QD;                // x single RNE plane
  u16* prh = p; p += (size_t)NUM_PROMPT * PD;       // prompt single RNE plane
  u16* WtPh = p; p += (size_t)TCD * PD;
  u16* WtAh = p; p += (size_t)(TCD + INNER) * QD;
  u16* WtBh = p; p += (size_t)(2 * INNER) * TCD;
  u16* WtOh = p; p += (size_t)QD * INNER;          u16* WtOl = p; p += (size_t)QD * INNER;
  u16* qhp = p; p += qN;                           // q single RNE plane (exp2 domain)
  u16* khp = p; p += kN;                           // K single RNE plane [B][KVPAD][INNER]
  u16* vthp = p; p += kN;                          // V^T single RNE plane [B][INNER][KVPAD]

  // ---- pack inputs + text ctx rows + V^T pad zero-fill (one launch) ----
  const int n4x = M * QD / 4, n4p = NUM_PROMPT * PD / 4;
  const int n4c = BB * CTX_LEN * TCD / 4;
  const int n4z = BB * INNER * 8;   // 8192 zero chunks of 16B
  pack_planes4<<<(n4x + n4p + n4c + n4z + 255) / 256, 256, 0, stream>>>(
      x, xh, n4x, prompt, prh, n4p, context, cth, n4c, vthp, n4z);

  // ---- transpose+pack all 6 weights (one launch); lo plane only for w_out ----
  TP6 tp;
  const float* srcs[6] = {w_prompt, w_img, w_q, w_k, w_v, w_out};
  u16* dhs[6] = {WtPh, WtAh, WtAh + (size_t)TCD * QD, WtBh, WtBh + (size_t)INNER * TCD, WtOh};
  u16* dls[6] = {nullptr, nullptr, nullptr, nullptr, nullptr, WtOl};
  int Ks[6] = {PD, QD, QD, TCD, TCD, INNER};
  int Ns[6] = {TCD, TCD, INNER, INNER, INNER, QD};
  int acc_blk = 0;
  for (int i = 0; i < 6; ++i) {
    tp.src[i] = srcs[i]; tp.dh[i] = dhs[i]; tp.dl[i] = dls[i];
    tp.K[i] = Ks[i]; tp.N[i] = Ns[i];
    tp.blk0[i] = acc_blk;
    acc_blk += (Ns[i] / 32) * (Ks[i] / 32);
  }
  tp.blk0[6] = acc_blk;
  transpose_pack6<<<acc_blk, 256, 0, stream>>>(tp);

  // ---- x @ [w_img | w_q] (1-term) -> ctx plane (remap, RNE) + q plane (x SCALEL2, RNE);
  //      extra band: prompt @ w_prompt -> ctx rows 77..140 (both b) ----
  gemm_mfma<1><<<dim3((TCD + INNER) / 64, M / 128 + 1), 256, 0, stream>>>(
      xh, nullptr, WtAh, nullptr, cth, qhp, nullptr, nullptr,
      M, QD, TCD + INNER, prh, WtPh);
  // ---- ctx @ [w_k | w_v] (1-term) -> K plane + V^T plane ----
  gemm_mfma<2><<<dim3((2 * INNER) / 64, 2 * (KVPAD / 128)), 256, 0, stream>>>(
      cth, nullptr, WtBh, nullptr, khp, vthp, nullptr, nullptr,
      MJ, TCD, 2 * INNER, nullptr, nullptr);
  // ---- attention ----
  attn_mfma2<<<BB * HEADS * (NN / 64), 256, 0, stream>>>(
      qhp, khp, vthp, aoh, aol);
  // ---- out = ao @ w_out + b_out (3-term, full accuracy) ----
  gemm_mfma<3><<<dim3(QD / 64, M / 128), 256, 0, stream>>>(
      aoh, aol, WtOh, WtOl, nullptr, nullptr, out, b_out,
      M, INNER, QD, nullptr, nullptr);
}

// Round 16
// 194.783 us; speedup vs baseline: 1.7012x; 1.0052x over previous
//
#include <hip/hip_runtime.h>
#include <hip/hip_bf16.h>
#include <math.h>

#define BB 2
#define NN 2048
#define QD 1024
#define CTX_LEN 77
#define TCD 768
#define NUM_PROMPT 64
#define PD 1024
#define HEADS 8
#define DIM_HEAD 64
#define INNER 512
#define JTOT (CTX_LEN + NUM_PROMPT + NN)   // 2189
#define SCALE 0.125f
#define SCALEL2 (0.125f * 1.44269504088896f)   // fold log2(e): softmax in exp2 domain
#define MTOT (BB * NN)                     // 4096
#define JPAD 2240                          // 35 * 64, attn j extent
#define KVPAD 2304                         // 18 * 128, K/V^T padded j extent
#define NT_J (JPAD / 64)                   // 35 j-tiles
#define NT_SPLIT 18                        // j-half boundary: [0,18) / [18,35)

typedef unsigned short u16;
typedef unsigned int u32;
typedef __attribute__((ext_vector_type(8))) short bf16x8;
typedef __attribute__((ext_vector_type(4))) float f32x4;

__device__ __forceinline__ u32 pack_split(float f) {   // interleaved: low16=hi, high16=lo
  u32 u = __builtin_bit_cast(u32, f);
  u32 hi = u & 0xffff0000u;
  float lo = f - __builtin_bit_cast(float, hi);
  u32 ul = __builtin_bit_cast(u32, lo);
  return __builtin_amdgcn_perm(ul, u, 0x07060302u);
}
__device__ __forceinline__ void split2(float f, u16& h, u16& l) {
  u32 u = __builtin_bit_cast(u32, f);
  u32 hm = u & 0xffff0000u;
  float lo = f - __builtin_bit_cast(float, hm);
  h = (u16)(u >> 16);
  l = (u16)(__builtin_bit_cast(u32, lo) >> 16);
}
__device__ __forceinline__ u16 rnd_bf16(float f) {   // RNE fp32 -> bf16
  u32 u = __builtin_bit_cast(u32, f);
  return (u16)((u + 0x7FFF + ((u >> 16) & 1)) >> 16);
}
__device__ __forceinline__ ushort4 pack4r(const float4& f) {   // RNE x4
  ushort4 r;
  r.x = rnd_bf16(f.x); r.y = rnd_bf16(f.y);
  r.z = rnd_bf16(f.z); r.w = rnd_bf16(f.w);
  return r;
}

// DPP lane move within 16-lane rows (ctrl must be ICE -> template)
template <int CTRL>
__device__ __forceinline__ float dpp_f(float x) {
  int i = __builtin_bit_cast(int, x);
  i = __builtin_amdgcn_update_dpp(0, i, CTRL, 0xF, 0xF, false);
  return __builtin_bit_cast(float, i);
}

// async global->LDS, 16B per lane; lds dest = base + lane*16
__device__ __forceinline__ void gload16(const u16* g, u32* l) {
  __builtin_amdgcn_global_load_lds(
      (const __attribute__((address_space(1))) u32*)(const void*)g,
      (__attribute__((address_space(3))) u32*)(void*)l, 16, 0, 0);
}

// ---------------- merged f32 -> plane pack: x (RNE), prompt (RNE), text-ctx (RNE), V^T pad-zero ----------------
__global__ __launch_bounds__(256) void pack_planes4(
    const float* __restrict__ s0, u16* __restrict__ d0, int n0,
    const float* __restrict__ s1, u16* __restrict__ d1, int n1,
    const float* __restrict__ ctx, u16* __restrict__ ch, int n2,
    u16* __restrict__ zh, int n3) {
  int i = blockIdx.x * 256 + threadIdx.x;
  if (i < n0) {
    ((ushort4*)d0)[i] = pack4r(((const float4*)s0)[i]);
    return;
  }
  i -= n0;
  if (i < n1) {
    ((ushort4*)d1)[i] = pack4r(((const float4*)s1)[i]);
    return;
  }
  i -= n1;
  if (i < n2) {
    // text context rows -> ctx plane (single RNE bf16) rows [b*JTOT + r], r < CTX_LEN
    ushort4 rr = pack4r(((const float4*)ctx)[i]);
    int c4 = i % (TCD / 4);
    int rb = i / (TCD / 4);
    int r = rb % CTX_LEN, b = rb / CTX_LEN;
    size_t o = ((size_t)b * JTOT + r) * (TCD / 4) + c4;   // ushort4 units
    ((ushort4*)ch)[o] = rr;
    return;
  }
  i -= n2;
  if (i >= n3) return;
  // zero-fill V^T j in [2176, 2240): 8 chunks of 8 u16 per (b,d) row
  int c = i & 7;
  int row = i >> 3;            // [b(2)][d(512)]
  int d = row & 511;
  int b = row >> 9;
  uint4 z = {0u, 0u, 0u, 0u};
  *(uint4*)&zh[((size_t)b * INNER + d) * KVPAD + 2176 + c * 8] = z;
}

// ---------------- merged weight transpose+pack: 6 sources, one launch ----------------
// dl[i] == nullptr: hi plane only (consumer is 1-term)
struct TP6 {
  const float* src[6];
  u16* dh[6];
  u16* dl[6];
  int K[6], N[6];
  int blk0[7];   // cumulative block offsets, blk0[6] = total blocks
};

__global__ __launch_bounds__(256) void transpose_pack6(TP6 P) {
  __shared__ u32 T[32][33];
  const int bid = blockIdx.x;
  int s = 0;
#pragma unroll
  for (int k = 1; k < 6; ++k) s += (bid >= P.blk0[k]);
  const int rel = bid - P.blk0[s];
  const int N = P.N[s], K = P.K[s];
  const int nbx = N >> 5;
  const int bx = rel % nbx, by = rel / nbx;
  const float* __restrict__ src = P.src[s];
  u16* __restrict__ dh = P.dh[s];
  u16* __restrict__ dl = P.dl[s];
  const int t = threadIdx.x;
  const int k0 = by * 32, n0 = bx * 32;
#pragma unroll
  for (int i = 0; i < 4; ++i) {
    int e = t + i * 256;
    int kr = e >> 5, nc = e & 31;
    T[kr][nc] = pack_split(src[(size_t)(k0 + kr) * N + n0 + nc]);
  }
  __syncthreads();
#pragma unroll
  for (int i = 0; i < 4; ++i) {
    int e = t + i * 256;
    int nr = e >> 5, kc = e & 31;
    u32 w = T[kc][nr];
    size_t idx = (size_t)(n0 + nr) * K + k0 + kc;
    // hi plane: RNE (1-term consumers); when lo kept, store truncated hi + lo (split)
    if (dl) {
      dh[idx] = (u16)(w & 0xffff);
      dl[idx] = (u16)(w >> 16);
    } else {
      dh[idx] = (u16)(w & 0xffff);   // pack_split low16 = truncated hi
    }
  }
}

// ---------------- split/plane bf16 MFMA GEMM, 128x64 tiles, BK=64, bijective XCD swizzle ----------------
// MODE 1 (1-term): gn<TCD -> ctx RNE plane (row remap); else q RNE plane (x SCALEL2).
//         Extra band bm>=MTOT: prompt@w_prompt -> ctx rows 77..140 (both b).
// MODE 2 (1-term): grid y = 36 (18/batch). gn<INNER -> K RNE plane [B][KVPAD][INNER];
//         else V^T RNE plane [B][INNER][KVPAD] via LDS transpose.
// MODE 3 (3-term split): f32 out + bias
template <int MODE>
__global__ __launch_bounds__(256) void gemm_mfma(
    const u16* __restrict__ Agh, const u16* __restrict__ Agl,
    const u16* __restrict__ Bgh, const u16* __restrict__ Bgl,
    u16* __restrict__ O1h,
    u16* __restrict__ O2h,
    float* __restrict__ Of, const float* __restrict__ bias,
    int M, int K, int Ntot,
    const u16* __restrict__ A2h, const u16* __restrict__ B2h) {
  constexpr bool ONET = (MODE == 1 || MODE == 2);   // single-term, single-plane operands
  constexpr int ALSZ = ONET ? 4 : 2 * 128 * 16;
  constexpr int BLSZ = ONET ? 4 : 2 * 64 * 16;
  __shared__ __align__(16) u32 Ah_s[2][128 * 16];
  __shared__ __align__(16) u32 Al_s[ALSZ];
  __shared__ __align__(16) u32 Bh_s[2][64 * 16];
  __shared__ __align__(16) u32 Bl_s[BLSZ];

  // bijective chunked XCD swizzle (m204): each XCD owns a contiguous grid chunk
  int bxi = blockIdx.x, byi = blockIdx.y;
  {
    const int GX = gridDim.x;
    const int nwg = GX * gridDim.y;
    const int lid = byi * GX + bxi;
    const int qq = nwg >> 3, rr = nwg & 7;
    const int xcd = lid & 7, pos = lid >> 3;
    const int swz = (xcd < rr ? xcd * (qq + 1) : rr * (qq + 1) + (xcd - rr) * qq) + pos;
    bxi = swz % GX; byi = swz / GX;
  }
  const int bm = byi * 128, bn = bxi * 64;

  const bool pband = (MODE == 1) && (bm >= MTOT);
  if (pband && bn >= TCD) return;   // block-uniform: idle prompt-band columns

  int b2 = 0, jbase = 0;
  if (MODE == 2) { b2 = (byi >= 18); jbase = (byi - b2 * 18) * 128; }

  const int t = threadIdx.x;
  const int w = t >> 6, lane = t & 63;
  const int m16 = lane & 15, quad = lane >> 4;
  const int wm = w >> 1, wn = w & 1;

  const u16* Abh = Agh; const u16* Abl = Agl;
  const u16* Bbh = Bgh; const u16* Bbl = Bgl;
  int rowlim = M - 1;
  int bmA = bm;
  if (pband) { Abh = A2h; Bbh = B2h; rowlim = NUM_PROMPT - 1; bmA = 0; }

  // DMA staging geometry: 4 lanes per 64B row, lane's 16B slot = (lane&3)*8 u16.
  // Wave w: A rows 32w..32w+31 (2 calls of 16 rows), B rows 16w..16w+15 (1 call).
  const int acol = (lane & 3) * 8;
  const int ar0 = 32 * w + (lane >> 2);
  const int ar1 = ar0 + 16;
  int ag0, ag1;
  if (MODE == 2) {
    ag0 = b2 * JTOT + min(jbase + ar0, JTOT - 1);   // clamp inside batch: no straddle
    ag1 = b2 * JTOT + min(jbase + ar1, JTOT - 1);
  } else {
    ag0 = min(bmA + ar0, rowlim);
    ag1 = min(bmA + ar1, rowlim);
  }
  const u16* a0h = Abh + (size_t)ag0 * K + acol;
  const u16* a1h = Abh + (size_t)ag1 * K + acol;
  const u16* a0l = ONET ? nullptr : Abl + (size_t)ag0 * K + acol;
  const u16* a1l = ONET ? nullptr : Abl + (size_t)ag1 * K + acol;
  const int br = 16 * w + (lane >> 2);
  const u16* b0h = Bbh + (size_t)(bn + br) * K + acol;
  const u16* b0l = ONET ? nullptr : Bbl + (size_t)(bn + br) * K + acol;

  f32x4 acc[4][2];
#pragma unroll
  for (int i = 0; i < 4; ++i)
#pragma unroll
    for (int j = 0; j < 2; ++j) acc[i][j] = (f32x4){0.f, 0.f, 0.f, 0.f};

  for (int k0 = 0; k0 < K; k0 += 64) {
    // ---- async stage both 32-col sub-tiles ----
#pragma unroll
    for (int s = 0; s < 2; ++s) {
      const int kc = k0 + s * 32;
      gload16(a0h + kc, &Ah_s[s][(2 * w) * 256]);
      gload16(a1h + kc, &Ah_s[s][(2 * w + 1) * 256]);
      gload16(b0h + kc, &Bh_s[s][w * 256]);
      if constexpr (!ONET) {
        gload16(a0l + kc, &Al_s[s * 2048 + (2 * w) * 256]);
        gload16(a1l + kc, &Al_s[s * 2048 + (2 * w + 1) * 256]);
        gload16(b0l + kc, &Bl_s[s * 1024 + w * 256]);
      }
    }
    __syncthreads();   // drains DMA (compiler emits vmcnt(0) before barrier)

#pragma unroll
    for (int s = 0; s < 2; ++s) {
      bf16x8 ah[4], al[4], bh[2], bl[2];
#pragma unroll
      for (int mt = 0; mt < 4; ++mt) {
        int off = (wm * 64 + mt * 16 + m16) * 16 + quad * 4;
        ah[mt] = *(const bf16x8*)&Ah_s[s][off];
        if constexpr (!ONET) al[mt] = *(const bf16x8*)&Al_s[s * 2048 + off];
      }
#pragma unroll
      for (int nt = 0; nt < 2; ++nt) {
        int off = (wn * 32 + nt * 16 + m16) * 16 + quad * 4;
        bh[nt] = *(const bf16x8*)&Bh_s[s][off];
        if constexpr (!ONET) bl[nt] = *(const bf16x8*)&Bl_s[s * 1024 + off];
      }
#pragma unroll
      for (int mt = 0; mt < 4; ++mt)
#pragma unroll
        for (int nt = 0; nt < 2; ++nt) {
          acc[mt][nt] = __builtin_amdgcn_mfma_f32_16x16x32_bf16(ah[mt], bh[nt], acc[mt][nt], 0, 0, 0);
          if constexpr (!ONET) {
            acc[mt][nt] = __builtin_amdgcn_mfma_f32_16x16x32_bf16(ah[mt], bl[nt], acc[mt][nt], 0, 0, 0);
            acc[mt][nt] = __builtin_amdgcn_mfma_f32_16x16x32_bf16(al[mt], bh[nt], acc[mt][nt], 0, 0, 0);
          }
        }
    }
    __syncthreads();   // frag reads done before next DMA overwrites
  }

  if (MODE == 2 && bn >= INNER) {
    // ---- V^T direct write, single RNE plane: LDS transpose + coalesced 16B stores ----
    u16* Th = (u16*)Ah_s;   // 16KB region: [64 d][128 j] u16, chunk-XOR layout
#pragma unroll
    for (int mt = 0; mt < 4; ++mt)
#pragma unroll
      for (int nt = 0; nt < 2; ++nt)
#pragma unroll
        for (int r = 0; r < 4; ++r) {
          int dl = wn * 32 + nt * 16 + m16;
          int jl = wm * 64 + mt * 16 + quad * 4 + r;
          int adr = dl * 128 + ((((jl >> 3) ^ (dl & 15)) << 3) | (jl & 7));
          Th[adr] = rnd_bf16(acc[mt][nt][r]);
        }
    __syncthreads();
#pragma unroll
    for (int i = 0; i < 4; ++i) {
      int chunk = t + i * 256;            // 1024 chunks = 64 d x 16 j-chunks
      int dl = chunk >> 4, jc = chunk & 15;
      int jg = jbase + jc * 8;
      int lofs = dl * 128 + ((jc ^ (dl & 15)) << 3);
      uint4 vh4 = *(const uint4*)&Th[lofs];
      size_t rowo = ((size_t)b2 * INNER + (bn - INNER) + dl) * KVPAD;
      if (jg + 8 <= JTOT) {
        *(uint4*)&O2h[rowo + jg] = vh4;
      } else if (jg < JTOT) {
        const u16* eh = (const u16*)&vh4;
#pragma unroll
        for (int e = 0; e < 8; ++e)
          if (jg + e < JTOT) O2h[rowo + jg + e] = eh[e];
      }   // jg >= JTOT: keep pre-zeroed pad
    }
    return;
  }

#pragma unroll
  for (int mt = 0; mt < 4; ++mt)
#pragma unroll
    for (int nt = 0; nt < 2; ++nt)
#pragma unroll
      for (int r = 0; r < 4; ++r) {
        int gm = bm + wm * 64 + mt * 16 + quad * 4 + r;
        int gn = bn + wn * 32 + nt * 16 + m16;
        float v = acc[mt][nt][r];
        if (MODE == 1) {
          if (pband) {
            int pr = wm * 64 + mt * 16 + quad * 4 + r;
            if (pr < NUM_PROMPT && gn < TCD) {
              u16 rv = rnd_bf16(v);
              O1h[((size_t)CTX_LEN + pr) * TCD + gn] = rv;           // b = 0
              O1h[((size_t)JTOT + CTX_LEN + pr) * TCD + gn] = rv;    // b = 1
            }
          } else if (gn < TCD) {
            size_t row = (size_t)(gm >> 11) * JTOT + 141 + (gm & 2047);
            O1h[row * TCD + gn] = rnd_bf16(v);
          } else {
            O2h[(size_t)gm * INNER + (gn - TCD)] = rnd_bf16(v * SCALEL2);
          }
        } else if (MODE == 2) {
          // K half: single RNE plane [B][KVPAD][INNER]; rows >= JTOT masked in attn
          int jloc = jbase + wm * 64 + mt * 16 + quad * 4 + r;
          O1h[((size_t)b2 * KVPAD + jloc) * INNER + gn] = rnd_bf16(v);
        } else if (MODE == 3) {
          Of[(size_t)gm * QD + gn] = v + bias[gn];
        }
      }
}

// ---------------- j-split MFMA flash attention, fixed-max exp2 softmax ----------------
// Grid 1024: (b,h,qtile) x 2 j-halves. Each block computes UN-NORMALIZED partial
// O (f32) and l over its j-range; fixed-max p=2^(S-8) makes partials exactly additive.
// Single-buffered staging (25.6 KB LDS) -> 4 blocks/CU resident, TLP hides the drain.
__global__ __launch_bounds__(256) void attn_mfma2(
    const u16* __restrict__ qhg,
    const u16* __restrict__ khg,
    const u16* __restrict__ vtg_h,
    float* __restrict__ Opart, float* __restrict__ lsum) {
  __shared__ __align__(16) u16 Kh_s[64 * 64];
  __shared__ __align__(16) u16 Vh_s[64 * 64];
  __shared__ __align__(16) u16 Ph_s[64 * 72];

  const int t = threadIdx.x;
  const int w = t >> 6, lane = t & 63;
  const int m16 = lane & 15, quad = lane >> 4;

  // XCD swizzle: 1024 blocks = 8 * 128; each XCD gets 2 (b,h) groups x 32 qt x 2 jh
  const int id = blockIdx.x;
  const int swz = (id & 7) * 128 + (id >> 3);
  const int jh = swz & 1;
  const int qt = (swz >> 1) & 31;
  const int bh = swz >> 6;
  const int b = bh >> 3, h = bh & 7;
  const int qrow0 = qt * 64;
  const int t0 = jh ? NT_SPLIT : 0;
  const int t1 = jh ? NT_J : NT_SPLIT;

  // Q fragments direct from global plane (A-frag: row=m16, k=ks*32+quad*8)
  bf16x8 qh[2];
  {
    size_t qoff = ((size_t)(b * NN + qrow0 + w * 16 + m16)) * INNER + h * 64 + quad * 8;
#pragma unroll
    for (int ks = 0; ks < 2; ++ks)
      qh[ks] = *(const bf16x8*)(qhg + qoff + ks * 32);
  }

  // Staging: waves 0,1 -> K chunks 0-3/4-7; waves 2,3 -> V^T chunks 0-3/4-7.
  // Per chunk: 8 rows x 8 slots of 16B; dest linear, source slot = (lane&7)^(lane>>3)
  // so LDS (row, cc) holds logical chunk cc^(row&7).
  const int sr = lane >> 3;
  const int sc = (lane & 7) ^ sr;
  const int c0 = (w & 1) * 4;
  const u16* gp;
  u32* lp;
  size_t cstr, jstr;
  if (w < 2) {
    gp = khg + ((size_t)b * KVPAD + t0 * 64 + c0 * 8 + sr) * INNER + h * 64 + sc * 8;
    lp = (u32*)Kh_s + c0 * 256;
    cstr = (size_t)8 * INNER;
    jstr = (size_t)64 * INNER;
  } else {
    gp = vtg_h + ((size_t)b * INNER + h * 64 + c0 * 8 + sr) * KVPAD + t0 * 64 + sc * 8;
    lp = (u32*)Vh_s + c0 * 256;
    cstr = (size_t)8 * KVPAD;
    jstr = 64;
  }

  f32x4 O[4] = {{0.f,0.f,0.f,0.f},{0.f,0.f,0.f,0.f},{0.f,0.f,0.f,0.f},{0.f,0.f,0.f,0.f}};
  float lpart[4];
#pragma unroll
  for (int r = 0; r < 4; ++r) lpart[r] = 0.f;

  for (int tile = t0; tile < t1; ++tile) {
    const int j0 = tile * 64;
    __syncthreads();                       // prior tile fully consumed
#pragma unroll
    for (int c = 0; c < 4; ++c) gload16(gp + (size_t)c * cstr, lp + c * 256);
    gp += jstr;
    __syncthreads();                       // drain DMA (vmcnt(0) before barrier)

    // ---- QK^T (single-plane: 8 MFMA) ----
    f32x4 S[4];
    __builtin_amdgcn_s_setprio(1);
#pragma unroll
    for (int jt = 0; jt < 4; ++jt) {
      const int row = jt * 16 + m16;
      f32x4 acc = {0.f, 0.f, 0.f, 0.f};
#pragma unroll
      for (int ks = 0; ks < 2; ++ks) {
        const int cc = row * 64 + (((ks * 4 + quad) ^ (row & 7)) << 3);
        bf16x8 kh = *(const bf16x8*)&Kh_s[cc];
        acc = __builtin_amdgcn_mfma_f32_16x16x32_bf16(qh[ks], kh, acc, 0, 0, 0);
      }
      S[jt] = acc;
    }
    __builtin_amdgcn_s_setprio(0);

    // mask tail columns (only last tile straddles JTOT); exp2(-inf) = 0 exactly
    if (j0 + 64 > JTOT) {
#pragma unroll
      for (int jt = 0; jt < 4; ++jt) {
        int jc = j0 + jt * 16 + m16;
        if (jc >= JTOT)
#pragma unroll
          for (int r = 0; r < 4; ++r) S[jt][r] = -INFINITY;
      }
    }

    // ---- fixed-max softmax: p = 2^(S-8); accumulate per-lane l partials ----
    float pj[4][4];
#pragma unroll
    for (int jt = 0; jt < 4; ++jt)
#pragma unroll
      for (int r = 0; r < 4; ++r) {
        float pv = __builtin_amdgcn_exp2f(S[jt][r] - 8.f);
        pj[jt][r] = pv;
        lpart[r] += pv;
      }

    // ---- P -> LDS (single RNE bf16 plane; rows are wave-private: no barrier) ----
#pragma unroll
    for (int jt = 0; jt < 4; ++jt)
#pragma unroll
      for (int r = 0; r < 4; ++r) {
        int pq = (w * 16 + quad * 4 + r) * 72 + jt * 16 + m16;
        Ph_s[pq] = rnd_bf16(pj[jt][r]);
      }

    bf16x8 ph[2];
#pragma unroll
    for (int ks = 0; ks < 2; ++ks) {
      int po = (w * 16 + m16) * 72 + ks * 32 + quad * 8;
      ph[ks] = *(const bf16x8*)&Ph_s[po];
    }

    // ---- PV (single-plane: 8 MFMA) ----
    __builtin_amdgcn_s_setprio(1);
#pragma unroll
    for (int nt = 0; nt < 4; ++nt) {
      const int row = nt * 16 + m16;
#pragma unroll
      for (int ks = 0; ks < 2; ++ks) {
        const int cc = row * 64 + (((ks * 4 + quad) ^ (row & 7)) << 3);
        bf16x8 vh = *(const bf16x8*)&Vh_s[cc];
        O[nt] = __builtin_amdgcn_mfma_f32_16x16x32_bf16(ph[ks], vh, O[nt], 0, 0, 0);
      }
    }
    __builtin_amdgcn_s_setprio(0);
  }

  // l partial: reduce across the 16 j-columns per row; one writer lane per row
  float lres[4];
#pragma unroll
  for (int r = 0; r < 4; ++r) {
    float rs = lpart[r];
    rs += dpp_f<0xB1>(rs);     // quad_perm xor1
    rs += dpp_f<0x4E>(rs);     // quad_perm xor2
    rs += dpp_f<0x124>(rs);    // row_ror:4
    rs += dpp_f<0x128>(rs);    // row_ror:8
    lres[r] = rs;
  }
  if (m16 == 0) {
#pragma unroll
    for (int r = 0; r < 4; ++r) {
      size_t row = (size_t)b * NN + qrow0 + w * 16 + quad * 4 + r;
      lsum[((size_t)jh * MTOT + row) * HEADS + h] = lres[r];
    }
  }
  // un-normalized O partial (f32)
#pragma unroll
  for (int nt = 0; nt < 4; ++nt)
#pragma unroll
    for (int r = 0; r < 4; ++r) {
      size_t idx = ((size_t)jh * MTOT + b * NN + qrow0 + w * 16 + quad * 4 + r) * INNER +
                   h * 64 + nt * 16 + m16;
      Opart[idx] = O[nt][r];
    }
}

// ---------------- combine j-halves: ao = (O0+O1)/(l0+l1) -> split planes ----------------
__global__ __launch_bounds__(256) void combine_attn(
    const float* __restrict__ Opart, const float* __restrict__ lsum,
    u16* __restrict__ aoh, u16* __restrict__ aol) {
  int i = blockIdx.x * 256 + threadIdx.x;   // one float4 per thread
  const int total4 = MTOT * INNER / 4;
  if (i >= total4) return;
  int row = i / (INNER / 4);
  int c4 = (i % (INNER / 4)) * 4;
  int h = c4 >> 6;
  float4 o0 = ((const float4*)Opart)[i];
  float4 o1 = ((const float4*)(Opart + (size_t)MTOT * INNER))[i];
  float l = lsum[(size_t)row * HEADS + h] + lsum[((size_t)MTOT + row) * HEADS + h];
  float inv = 1.f / l;
  float v0 = (o0.x + o1.x) * inv;
  float v1 = (o0.y + o1.y) * inv;
  float v2 = (o0.z + o1.z) * inv;
  float v3 = (o0.w + o1.w) * inv;
  ushort4 hh, ll;
  split2(v0, hh.x, ll.x); split2(v1, hh.y, ll.y);
  split2(v2, hh.z, ll.z); split2(v3, hh.w, ll.w);
  ((ushort4*)aoh)[i] = hh;
  ((ushort4*)aol)[i] = ll;
}

// ---------------- launch ----------------
extern "C" void kernel_launch(void* const* d_in, const int* in_sizes, int n_in,
                              void* d_out, int out_size, void* d_ws, size_t ws_size,
                              hipStream_t stream) {
  const float* x        = (const float*)d_in[0];
  const float* context  = (const float*)d_in[1];
  const float* prompt   = (const float*)d_in[2];
  const float* w_prompt = (const float*)d_in[3];
  const float* w_img    = (const float*)d_in[4];
  const float* w_q      = (const float*)d_in[5];
  const float* w_k      = (const float*)d_in[6];
  const float* w_v      = (const float*)d_in[7];
  const float* w_out    = (const float*)d_in[8];
  const float* b_out    = (const float*)d_in[9];
  float* out = (float*)d_out;

  const int M = MTOT;             // 4096
  const int MJ = BB * JTOT;       // 4378

  u16* p = (u16*)d_ws;
  const size_t qN = (size_t)M * INNER;
  const size_t ctxN = (size_t)MJ * TCD;
  const size_t kN = (size_t)BB * KVPAD * INNER;  // K / V^T plane size
  u16* cth = p; p += ctxN;                          // ctx single RNE plane
  u16* aoh = p; p += qN;   u16* aol = p; p += qN;
  u16* xh  = p; p += (size_t)M * QD;                // x single RNE plane
  u16* prh = p; p += (size_t)NUM_PROMPT * PD;       // prompt single RNE plane
  u16* WtPh = p; p += (size_t)TCD * PD;
  u16* WtAh = p; p += (size_t)(TCD + INNER) * QD;
  u16* WtBh = p; p += (size_t)(2 * INNER) * TCD;
  u16* WtOh = p; p += (size_t)QD * INNER;          u16* WtOl = p; p += (size_t)QD * INNER;
  u16* qhp = p; p += qN;                           // q single RNE plane (exp2 domain)
  u16* khp = p; p += kN;                           // K single RNE plane [B][KVPAD][INNER]
  u16* vthp = p; p += kN;                          // V^T single RNE plane [B][INNER][KVPAD]
  float* Opart = (float*)p; p += 2 * qN * 2;       // 2 x [MTOT][INNER] f32 partials
  float* lsum  = (float*)p; p += (size_t)2 * MTOT * HEADS * 2;   // 2 x [MTOT][HEADS] f32

  // ---- pack inputs + text ctx rows + V^T pad zero-fill (one launch) ----
  const int n4x = M * QD / 4, n4p = NUM_PROMPT * PD / 4;
  const int n4c = BB * CTX_LEN * TCD / 4;
  const int n4z = BB * INNER * 8;   // 8192 zero chunks of 16B
  pack_planes4<<<(n4x + n4p + n4c + n4z + 255) / 256, 256, 0, stream>>>(
      x, xh, n4x, prompt, prh, n4p, context, cth, n4c, vthp, n4z);

  // ---- transpose+pack all 6 weights (one launch); lo plane only for w_out ----
  TP6 tp;
  const float* srcs[6] = {w_prompt, w_img, w_q, w_k, w_v, w_out};
  u16* dhs[6] = {WtPh, WtAh, WtAh + (size_t)TCD * QD, WtBh, WtBh + (size_t)INNER * TCD, WtOh};
  u16* dls[6] = {nullptr, nullptr, nullptr, nullptr, nullptr, WtOl};
  int Ks[6] = {PD, QD, QD, TCD, TCD, INNER};
  int Ns[6] = {TCD, TCD, INNER, INNER, INNER, QD};
  int acc_blk = 0;
  for (int i = 0; i < 6; ++i) {
    tp.src[i] = srcs[i]; tp.dh[i] = dhs[i]; tp.dl[i] = dls[i];
    tp.K[i] = Ks[i]; tp.N[i] = Ns[i];
    tp.blk0[i] = acc_blk;
    acc_blk += (Ns[i] / 32) * (Ks[i] / 32);
  }
  tp.blk0[6] = acc_blk;
  transpose_pack6<<<acc_blk, 256, 0, stream>>>(tp);

  // ---- x @ [w_img | w_q] (1-term) -> ctx plane (remap, RNE) + q plane (x SCALEL2, RNE);
  //      extra band: prompt @ w_prompt -> ctx rows 77..140 (both b) ----
  gemm_mfma<1><<<dim3((TCD + INNER) / 64, M / 128 + 1), 256, 0, stream>>>(
      xh, nullptr, WtAh, nullptr, cth, qhp, nullptr, nullptr,
      M, QD, TCD + INNER, prh, WtPh);
  // ---- ctx @ [w_k | w_v] (1-term) -> K plane + V^T plane ----
  gemm_mfma<2><<<dim3((2 * INNER) / 64, 2 * (KVPAD / 128)), 256, 0, stream>>>(
      cth, nullptr, WtBh, nullptr, khp, vthp, nullptr, nullptr,
      MJ, TCD, 2 * INNER, nullptr, nullptr);
  // ---- attention: j-split partials, then combine ----
  attn_mfma2<<<BB * HEADS * (NN / 64) * 2, 256, 0, stream>>>(
      qhp, khp, vthp, Opart, lsum);
  combine_attn<<<(M * INNER / 4 + 255) / 256, 256, 0, stream>>>(
      Opart, lsum, aoh, aol);
  // ---- out = ao @ w_out + b_out (3-term, full accuracy) ----
  gemm_mfma<3><<<dim3(QD / 64, M / 128), 256, 0, stream>>>(
      aoh, aol, WtOh, WtOl, nullptr, nullptr, out, b_out,
      M, INNER, QD, nullptr, nullptr);
}